// Round 1
// baseline (849.761 us; speedup 1.0000x reference)
//
#include <hip/hip_runtime.h>
#include <math.h>

#define HW 1024
#define EPSV 1e-5f

// ws layout (float offsets)
static const size_t WT_OFF = 0;          // 256 ch x 256 (243 used)      = 65536
static const size_t WT_DCN = 65536;      // [k][c][o] 9*256*128          = 294912
static const size_t WT_UP  = 360448;     // [t][c][o] 16*128*128         = 262144
static const size_t OFFB   = 622592;     // off final 16*27*1024         = 442368
static const size_t YB     = 1064960;    // y 16*128*1024                = 2097152
static const size_t ST1    = 3162112;    // scale/shift BN1              = 256
static const size_t ST2    = 3162368;    // scale/shift BN2              = 256
static const size_t PARTB  = 3162624;    // off_part (8*442368) then y_part (4*2097152), aliased
// total = 3162624 + 8388608 = 11551232 floats = 46.2 MB

// ---------------- prep: transpose weights for uniform scalar-load access ----------
__global__ __launch_bounds__(256) void prep_kernel(const float* __restrict__ w_off,
                                                   const float* __restrict__ w_dcn,
                                                   const float* __restrict__ w_up,
                                                   float* __restrict__ ws) {
  int i = blockIdx.x * 256 + threadIdx.x;
  if (i < 62208) {
    // src w_off[(j*256+c)*9+kk] -> dst [c][j*9+kk] stride 256
    int kk = i % 9; int c = (i / 9) & 255; int j = i / 2304;
    ws[WT_OFF + (size_t)c * 256 + j * 9 + kk] = w_off[i];
  } else if (i < 62208 + 294912) {
    int d = i - 62208;            // d = (k*256+c)*128+o
    int o = d & 127; int c = (d >> 7) & 255; int k = d >> 15;
    ws[WT_DCN + d] = w_dcn[((size_t)o * 256 + c) * 9 + k];
  } else if (i < 62208 + 294912 + 262144) {
    int d = i - (62208 + 294912); // d = (t*128+c)*128+o
    int o = d & 127; int c = (d >> 7) & 127; int t = d >> 14;
    ws[WT_UP + d] = w_up[((size_t)c * 128 + o) * 16 + t];
  }
}

// ---------------- offset conv: 256->27, 3x3, pad 1 (partial over 8 cin-splits) ----
__global__ __launch_bounds__(256) void offconv_kernel(const float* __restrict__ x,
                                                      const float* __restrict__ wt,
                                                      float* __restrict__ off_part) {
  int b = blockIdx.x >> 2, pg = blockIdx.x & 3;
  int cs = blockIdx.y;
  int tid = threadIdx.x;
  int p = pg * 256 + tid;
  int h = p >> 5, w = p & 31;
  float acc[27];
#pragma unroll
  for (int j = 0; j < 27; ++j) acc[j] = 0.f;

  int ofs[9]; float msk[9];
#pragma unroll
  for (int t = 0; t < 9; ++t) {
    int ky = t / 3, kx = t % 3;
    int yy = h + ky - 1, xx = w + kx - 1;
    bool v = (yy >= 0) && (yy < 32) && (xx >= 0) && (xx < 32);
    int yc = min(max(yy, 0), 31), xc = min(max(xx, 0), 31);
    ofs[t] = yc * 32 + xc;
    msk[t] = v ? 1.f : 0.f;
  }
  const float* xb = x + (size_t)(b * 256 + cs * 32) * HW;
  for (int c = 0; c < 32; ++c) {
    const float* xc = xb + (size_t)c * HW;
    float xv[9];
#pragma unroll
    for (int t = 0; t < 9; ++t) xv[t] = xc[ofs[t]] * msk[t];
    const float* wr = wt + (size_t)(cs * 32 + c) * 256;  // uniform -> s_load
#pragma unroll
    for (int j = 0; j < 27; ++j)
#pragma unroll
      for (int kk = 0; kk < 9; ++kk)
        acc[j] = fmaf(xv[kk], wr[j * 9 + kk], acc[j]);
  }
  float* op = off_part + (size_t)cs * 442368 + (size_t)b * 27 * HW + p;
#pragma unroll
  for (int j = 0; j < 27; ++j) op[(size_t)j * HW] = acc[j];
}

// ---------------- reduce offset partials + bias + sigmoid(mask channels) ----------
__global__ __launch_bounds__(256) void offreduce_kernel(const float* __restrict__ off_part,
                                                        const float* __restrict__ b_off,
                                                        float* __restrict__ off) {
  int i = blockIdx.x * 256 + threadIdx.x;
  if (i >= 442368) return;
  float s = 0.f;
#pragma unroll
  for (int cs = 0; cs < 8; ++cs) s += off_part[(size_t)cs * 442368 + i];
  int ch = (i >> 10) % 27;
  s += b_off[ch];
  if (ch >= 18) s = 1.f / (1.f + __expf(-s));
  off[i] = s;
}

// ---------------- deformable conv (partial over 2 oc-groups x 4 cin-splits) -------
__global__ __launch_bounds__(256) void deform_kernel(const float* __restrict__ x,
                                                     const float* __restrict__ off,
                                                     const float* __restrict__ wt,
                                                     float* __restrict__ y_part) {
  int b = blockIdx.x >> 2, pg = blockIdx.x & 3;
  int ocg = blockIdx.y, cs = blockIdx.z;
  int tid = threadIdx.x;
  int p = pg * 256 + tid; int h = p >> 5, w = p & 31;
  float acc[64];
#pragma unroll
  for (int j = 0; j < 64; ++j) acc[j] = 0.f;

  const float* offb = off + (size_t)b * 27 * HW + p;
  const float* xb = x + (size_t)(b * 256 + cs * 64) * HW;

  for (int k = 0; k < 9; ++k) {
    float dy = offb[(size_t)(2 * k) * HW];
    float dx = offb[(size_t)(2 * k + 1) * HW];
    float m  = offb[(size_t)(18 + k) * HW];
    float py = (float)(h + k / 3 - 1) + dy;
    float px = (float)(w + k % 3 - 1) + dx;
    float y0f = floorf(py), x0f = floorf(px);
    float wy = py - y0f, wx = px - x0f;
    int y0 = (int)y0f, x0 = (int)x0f;
    float cw[4] = {(1.f - wy) * (1.f - wx), (1.f - wy) * wx, wy * (1.f - wx), wy * wx};
    int idx[4]; float wgt[4];
#pragma unroll
    for (int t = 0; t < 4; ++t) {
      int yy = y0 + (t >> 1), xx = x0 + (t & 1);
      bool v = (yy >= 0) && (yy <= 31) && (xx >= 0) && (xx <= 31);
      int yc = min(max(yy, 0), 31), xc = min(max(xx, 0), 31);
      idx[t] = yc * 32 + xc;
      wgt[t] = v ? cw[t] * m : 0.f;
    }
    const float* wk = wt + ((size_t)k * 256 + cs * 64) * 128 + ocg * 64;
    for (int c = 0; c < 64; ++c) {
      const float* xc = xb + (size_t)c * HW;
      float s = fmaf(wgt[0], xc[idx[0]],
                fmaf(wgt[1], xc[idx[1]],
                fmaf(wgt[2], xc[idx[2]], wgt[3] * xc[idx[3]])));
      const float* wr = wk + (size_t)c * 128;  // uniform -> s_load_dwordx16
#pragma unroll
      for (int j = 0; j < 64; ++j) acc[j] = fmaf(s, wr[j], acc[j]);
    }
  }
  float* yp = y_part + (size_t)cs * 2097152 + ((size_t)b * 128 + ocg * 64) * HW + p;
#pragma unroll
  for (int j = 0; j < 64; ++j) yp[(size_t)j * HW] = acc[j];
}

// ---------------- reduce y partials + bias -----------------------------------------
__global__ __launch_bounds__(256) void yreduce_kernel(const float* __restrict__ y_part,
                                                      const float* __restrict__ b_dcn,
                                                      float* __restrict__ y) {
  int i4 = blockIdx.x * 256 + threadIdx.x;
  if (i4 >= 524288) return;
  size_t i = (size_t)i4 * 4;
  float4 s = {0.f, 0.f, 0.f, 0.f};
#pragma unroll
  for (int cs = 0; cs < 4; ++cs) {
    float4 v = *(const float4*)(y_part + (size_t)cs * 2097152 + i);
    s.x += v.x; s.y += v.y; s.z += v.z; s.w += v.w;
  }
  float bb = b_dcn[(i >> 10) & 127];
  s.x += bb; s.y += bb; s.z += bb; s.w += bb;
  *(float4*)(y + i) = s;
}

// ---------------- BN stats per channel -> scale/shift ------------------------------
__global__ __launch_bounds__(256) void stats_kernel(const float* __restrict__ src,
                                                    const float* __restrict__ g,
                                                    const float* __restrict__ bt,
                                                    float* __restrict__ stats, int hw) {
  int oc = blockIdx.x; int tid = threadIdx.x;
  float s = 0.f, sq = 0.f;
  for (int b = 0; b < 16; ++b) {
    const float* sb = src + ((size_t)b * 128 + oc) * hw;
    for (int p = tid; p < hw; p += 256) { float v = sb[p]; s += v; sq = fmaf(v, v, sq); }
  }
  __shared__ float ls[256], lq[256];
  ls[tid] = s; lq[tid] = sq; __syncthreads();
  for (int st = 128; st > 0; st >>= 1) {
    if (tid < st) { ls[tid] += ls[tid + st]; lq[tid] += lq[tid + st]; }
    __syncthreads();
  }
  if (tid == 0) {
    float n = 16.f * (float)hw;
    float mean = ls[0] / n;
    float var = lq[0] / n - mean * mean;
    float sc = g[oc] * rsqrtf(var + EPSV);
    stats[oc] = sc;
    stats[128 + oc] = fmaf(-mean, sc, bt[oc]);
  }
}

// ---------------- transposed conv 4x4 s2 p1, BN1+ReLU fused on input --------------
// parity-decomposed so kernel-tap indices are wave-uniform (scalar weight loads)
__global__ __launch_bounds__(256) void deconv_kernel(const float* __restrict__ y,
                                                     const float* __restrict__ stats,
                                                     const float* __restrict__ wt,
                                                     float* __restrict__ out) {
  int b = blockIdx.x >> 2, pg = blockIdx.x & 3;
  int par = blockIdx.y; int pu = par >> 1, pv = par & 1;
  int ocg = blockIdx.z;
  int tid = threadIdx.x;
  int uu = pg * 8 + (tid >> 5), vv = tid & 31;
  int u = 2 * uu + pu, v = 2 * vv + pv;
  int ky0 = 1 - pu, kx0 = 1 - pv;
  int i0 = uu + pu, i1 = uu + pu - 1;
  int j0 = vv + pv, j1 = vv + pv - 1;
  float my0 = (i0 <= 31) ? 1.f : 0.f, my1 = (i1 >= 0) ? 1.f : 0.f;
  float mx0 = (j0 <= 31) ? 1.f : 0.f, mx1 = (j1 >= 0) ? 1.f : 0.f;
  int i0c = min(i0, 31), i1c = max(i1, 0), j0c = min(j0, 31), j1c = max(j1, 0);
  int o00 = i0c * 32 + j0c, o01 = i0c * 32 + j1c, o10 = i1c * 32 + j0c, o11 = i1c * 32 + j1c;
  float m00 = my0 * mx0, m01 = my0 * mx1, m10 = my1 * mx0, m11 = my1 * mx1;

  const float* w00 = wt + (size_t)((ky0 * 4 + kx0) * 128) * 128 + ocg * 64;
  const float* w01 = wt + (size_t)((ky0 * 4 + kx0 + 2) * 128) * 128 + ocg * 64;
  const float* w10 = wt + (size_t)(((ky0 + 2) * 4 + kx0) * 128) * 128 + ocg * 64;
  const float* w11 = wt + (size_t)(((ky0 + 2) * 4 + kx0 + 2) * 128) * 128 + ocg * 64;

  float acc[64];
#pragma unroll
  for (int j = 0; j < 64; ++j) acc[j] = 0.f;

  const float* yb = y + (size_t)b * 128 * HW;
  for (int c = 0; c < 128; ++c) {
    const float* yc = yb + (size_t)c * HW;
    float sc = stats[c], sh = stats[128 + c];
    float v00 = fmaxf(fmaf(yc[o00], sc, sh), 0.f) * m00;
    float v01 = fmaxf(fmaf(yc[o01], sc, sh), 0.f) * m01;
    float v10 = fmaxf(fmaf(yc[o10], sc, sh), 0.f) * m10;
    float v11 = fmaxf(fmaf(yc[o11], sc, sh), 0.f) * m11;
    const float* p00 = w00 + (size_t)c * 128;
    const float* p01 = w01 + (size_t)c * 128;
    const float* p10 = w10 + (size_t)c * 128;
    const float* p11 = w11 + (size_t)c * 128;
#pragma unroll
    for (int j = 0; j < 64; ++j)
      acc[j] = fmaf(v00, p00[j],
               fmaf(v01, p01[j],
               fmaf(v10, p10[j],
               fmaf(v11, p11[j], acc[j]))));
  }
  float* ob = out + ((size_t)b * 128 + ocg * 64) * 4096 + u * 64 + v;
#pragma unroll
  for (int j = 0; j < 64; ++j) ob[(size_t)j * 4096] = acc[j];
}

// ---------------- final BN+ReLU in place on d_out ----------------------------------
__global__ __launch_bounds__(256) void bnrelu_out_kernel(float* __restrict__ out,
                                                         const float* __restrict__ stats) {
  int i4 = blockIdx.x * 256 + threadIdx.x;
  if (i4 >= 2097152) return;
  size_t i = (size_t)i4 * 4;
  int oc = (int)((i >> 12) & 127);
  float sc = stats[oc], sh = stats[128 + oc];
  float4 v = *(float4*)(out + i);
  v.x = fmaxf(fmaf(v.x, sc, sh), 0.f);
  v.y = fmaxf(fmaf(v.y, sc, sh), 0.f);
  v.z = fmaxf(fmaf(v.z, sc, sh), 0.f);
  v.w = fmaxf(fmaf(v.w, sc, sh), 0.f);
  *(float4*)(out + i) = v;
}

extern "C" void kernel_launch(void* const* d_in, const int* in_sizes, int n_in,
                              void* d_out, int out_size, void* d_ws, size_t ws_size,
                              hipStream_t stream) {
  const float* x     = (const float*)d_in[0];
  const float* w_off = (const float*)d_in[1];
  const float* b_off = (const float*)d_in[2];
  const float* w_dcn = (const float*)d_in[3];
  const float* b_dcn = (const float*)d_in[4];
  const float* g1    = (const float*)d_in[5];
  const float* bt1   = (const float*)d_in[6];
  const float* w_up  = (const float*)d_in[7];
  const float* g2    = (const float*)d_in[8];
  const float* bt2   = (const float*)d_in[9];
  float* ws  = (float*)d_ws;
  float* out = (float*)d_out;

  prep_kernel<<<2419, 256, 0, stream>>>(w_off, w_dcn, w_up, ws);
  offconv_kernel<<<dim3(64, 8), 256, 0, stream>>>(x, ws + WT_OFF, ws + PARTB);
  offreduce_kernel<<<1728, 256, 0, stream>>>(ws + PARTB, b_off, ws + OFFB);
  deform_kernel<<<dim3(64, 2, 4), 256, 0, stream>>>(x, ws + OFFB, ws + WT_DCN, ws + PARTB);
  yreduce_kernel<<<2048, 256, 0, stream>>>(ws + PARTB, b_dcn, ws + YB);
  stats_kernel<<<128, 256, 0, stream>>>(ws + YB, g1, bt1, ws + ST1, 1024);
  deconv_kernel<<<dim3(64, 4, 2), 256, 0, stream>>>(ws + YB, ws + ST1, ws + WT_UP, out);
  stats_kernel<<<128, 256, 0, stream>>>(out, g2, bt2, ws + ST2, 4096);
  bnrelu_out_kernel<<<8192, 256, 0, stream>>>(out, ws + ST2);
}

// Round 2
// 466.971 us; speedup vs baseline: 1.8197x; 1.8197x over previous
//
#include <hip/hip_runtime.h>
#include <math.h>

#define HW 1024
#define EPSV 1e-5f

typedef unsigned int uint;
typedef unsigned short ushort;
typedef __attribute__((ext_vector_type(8))) short short8;
typedef __attribute__((ext_vector_type(4))) float floatx4;

// ---------------- ws layout (float offsets) ----------------------------------------
// lifetimes: step numbers in comments
static const size_t WT_OFF = 0;        // 65536   (live 1-2)
static const size_t WT_DCN = 65536;    // 294912  (live 1-4)
static const size_t YBN_F  = 0;        // 1048576 floats = 2097152 bf16 (live 6-7, overwrites WT_*)
static const size_t OFFB   = 1048576;  // 442368  (live 3-4)
static const size_t STP    = 1048576;  // 131072  (live 8-9, aliases OFFB)
static const size_t ST1    = 1490944;  // 256     (live 5-6)
static const size_t ST2    = 1491200;  // 256     (live 9-10)
static const size_t BP     = 1491456;  // 131072 floats = 262144 bf16 (live 1-7)
static const size_t BIG    = 1622528;  // 8388608: off_part(2-3) / y_part(4-6) / O fp32(7-10)
// total = 10011136 floats = 40.0 MB (< 46.2 MB proven in round 1)

__device__ inline ushort f2bf(float f) {
  uint u = __builtin_bit_cast(uint, f);
  uint r = (u + 0x7FFFu + ((u >> 16) & 1u)) >> 16;
  return (ushort)r;
}

// ---------------- 1. prep: transpose weights --------------------------------------
__global__ __launch_bounds__(256) void prep_kernel(const float* __restrict__ w_off,
                                                   const float* __restrict__ w_dcn,
                                                   const float* __restrict__ w_up,
                                                   float* __restrict__ ws) {
  int i = blockIdx.x * 256 + threadIdx.x;
  if (i < 62208) {
    // w_off[(j*256+c)*9+kk] -> [c][j*9+kk] stride 256
    int kk = i % 9; int c = (i / 9) & 255; int j = i / 2304;
    ws[WT_OFF + (size_t)c * 256 + j * 9 + kk] = w_off[i];
  } else if (i < 62208 + 294912) {
    int d = i - 62208;            // d = (k*256+c)*128+o
    int o = d & 127; int c = (d >> 7) & 255; int k = d >> 15;
    ws[WT_DCN + d] = w_dcn[((size_t)o * 256 + c) * 9 + k];
  } else if (i < 62208 + 294912 + 262144) {
    // Bp[par][o][k = (ty*2+tx)*128 + c] bf16 = w_up[c][o][ky0+2ty][kx0+2tx]
    int d = i - (62208 + 294912);
    int par = d >> 16; int rem = d & 65535;
    int o = rem >> 9; int k = rem & 511;
    int t4 = k >> 7; int c = k & 127;
    int ty = t4 >> 1, tx = t4 & 1;
    int pu = par >> 1, pv = par & 1;
    int ky = (1 - pu) + 2 * ty, kx = (1 - pv) + 2 * tx;
    float v = w_up[((size_t)c * 128 + o) * 16 + ky * 4 + kx];
    ((ushort*)(ws + BP))[d] = f2bf(v);
  }
}

// ---------------- 2. offset conv: 256->27 (partial over 8 cin-splits) -------------
__global__ __launch_bounds__(256) void offconv_kernel(const float* __restrict__ x,
                                                      const float* __restrict__ wt,
                                                      float* __restrict__ off_part) {
  int b = blockIdx.x >> 2, pg = blockIdx.x & 3;
  int cs = blockIdx.y;
  int tid = threadIdx.x;
  int p = pg * 256 + tid;
  int h = p >> 5, w = p & 31;
  float acc[27];
#pragma unroll
  for (int j = 0; j < 27; ++j) acc[j] = 0.f;

  int ofs[9]; float msk[9];
#pragma unroll
  for (int t = 0; t < 9; ++t) {
    int ky = t / 3, kx = t % 3;
    int yy = h + ky - 1, xx = w + kx - 1;
    bool v = (yy >= 0) && (yy < 32) && (xx >= 0) && (xx < 32);
    int yc = min(max(yy, 0), 31), xc = min(max(xx, 0), 31);
    ofs[t] = yc * 32 + xc;
    msk[t] = v ? 1.f : 0.f;
  }
  const float* xb = x + (size_t)(b * 256 + cs * 32) * HW;
  for (int c = 0; c < 32; ++c) {
    const float* xc = xb + (size_t)c * HW;
    float xv[9];
#pragma unroll
    for (int t = 0; t < 9; ++t) xv[t] = xc[ofs[t]] * msk[t];
    const float* wr = wt + (size_t)(cs * 32 + c) * 256;
#pragma unroll
    for (int j = 0; j < 27; ++j)
#pragma unroll
      for (int kk = 0; kk < 9; ++kk)
        acc[j] = fmaf(xv[kk], wr[j * 9 + kk], acc[j]);
  }
  float* op = off_part + (size_t)cs * 442368 + (size_t)b * 27 * HW + p;
#pragma unroll
  for (int j = 0; j < 27; ++j) op[(size_t)j * HW] = acc[j];
}

// ---------------- 3. reduce offsets + bias + sigmoid ------------------------------
__global__ __launch_bounds__(256) void offreduce_kernel(const float* __restrict__ off_part,
                                                        const float* __restrict__ b_off,
                                                        float* __restrict__ off) {
  int i = blockIdx.x * 256 + threadIdx.x;
  if (i >= 442368) return;
  float s = 0.f;
#pragma unroll
  for (int cs = 0; cs < 8; ++cs) s += off_part[(size_t)cs * 442368 + i];
  int ch = (i >> 10) % 27;
  s += b_off[ch];
  if (ch >= 18) s = 1.f / (1.f + __expf(-s));
  off[i] = s;
}

// ---------------- 4. deformable conv (partial 2 ocg x 4 cs) -----------------------
__global__ __launch_bounds__(256) void deform_kernel(const float* __restrict__ x,
                                                     const float* __restrict__ off,
                                                     const float* __restrict__ wt,
                                                     float* __restrict__ y_part) {
  int b = blockIdx.x >> 2, pg = blockIdx.x & 3;
  int ocg = blockIdx.y, cs = blockIdx.z;
  int tid = threadIdx.x;
  int p = pg * 256 + tid; int h = p >> 5, w = p & 31;
  float acc[64];
#pragma unroll
  for (int j = 0; j < 64; ++j) acc[j] = 0.f;

  const float* offb = off + (size_t)b * 27 * HW + p;
  const float* xb = x + (size_t)(b * 256 + cs * 64) * HW;

  for (int k = 0; k < 9; ++k) {
    float dy = offb[(size_t)(2 * k) * HW];
    float dx = offb[(size_t)(2 * k + 1) * HW];
    float m  = offb[(size_t)(18 + k) * HW];
    float py = (float)(h + k / 3 - 1) + dy;
    float px = (float)(w + k % 3 - 1) + dx;
    float y0f = floorf(py), x0f = floorf(px);
    float wy = py - y0f, wx = px - x0f;
    int y0 = (int)y0f, x0 = (int)x0f;
    float cw[4] = {(1.f - wy) * (1.f - wx), (1.f - wy) * wx, wy * (1.f - wx), wy * wx};
    int idx[4]; float wgt[4];
#pragma unroll
    for (int t = 0; t < 4; ++t) {
      int yy = y0 + (t >> 1), xx = x0 + (t & 1);
      bool v = (yy >= 0) && (yy <= 31) && (xx >= 0) && (xx <= 31);
      int yc = min(max(yy, 0), 31), xc = min(max(xx, 0), 31);
      idx[t] = yc * 32 + xc;
      wgt[t] = v ? cw[t] * m : 0.f;
    }
    const float* wk = wt + ((size_t)k * 256 + cs * 64) * 128 + ocg * 64;
    for (int c = 0; c < 64; ++c) {
      const float* xc = xb + (size_t)c * HW;
      float s = fmaf(wgt[0], xc[idx[0]],
                fmaf(wgt[1], xc[idx[1]],
                fmaf(wgt[2], xc[idx[2]], wgt[3] * xc[idx[3]])));
      const float* wr = wk + (size_t)c * 128;
#pragma unroll
      for (int j = 0; j < 64; ++j) acc[j] = fmaf(s, wr[j], acc[j]);
    }
  }
  float* yp = y_part + (size_t)cs * 2097152 + ((size_t)b * 128 + ocg * 64) * HW + p;
#pragma unroll
  for (int j = 0; j < 64; ++j) yp[(size_t)j * HW] = acc[j];
}

// ---------------- 5. BN1 stats from y partials (incl bias) ------------------------
__global__ __launch_bounds__(256) void stats1_kernel(const float* __restrict__ y_part,
                                                     const float* __restrict__ b_dcn,
                                                     const float* __restrict__ g,
                                                     const float* __restrict__ bt,
                                                     float* __restrict__ st) {
  int oc = blockIdx.x; int tid = threadIdx.x;
  float bias = b_dcn[oc];
  float s = 0.f, sq = 0.f;
  for (int b = 0; b < 16; ++b) {
    size_t base = ((size_t)b * 128 + oc) * HW;
    for (int p = tid; p < HW; p += 256) {
      float v = y_part[base + p] + y_part[2097152 + base + p]
              + y_part[4194304 + base + p] + y_part[6291456 + base + p] + bias;
      s += v; sq = fmaf(v, v, sq);
    }
  }
  __shared__ float ls[256], lq[256];
  ls[tid] = s; lq[tid] = sq; __syncthreads();
  for (int stp = 128; stp > 0; stp >>= 1) {
    if (tid < stp) { ls[tid] += ls[tid + stp]; lq[tid] += lq[tid + stp]; }
    __syncthreads();
  }
  if (tid == 0) {
    float n = 16.f * 1024.f;
    float mean = ls[0] / n;
    float var = lq[0] / n - mean * mean;
    float sc = g[oc] * rsqrtf(var + EPSV);
    st[oc] = sc;
    st[128 + oc] = fmaf(-mean, sc, bt[oc]);
  }
}

// ---------------- 6. ybn: reduce partials + bias + BN + ReLU + transpose to bf16 --
// out: ybn[b][pix][c]  (c contiguous, bf16)
__global__ __launch_bounds__(256) void ybn_kernel(const float* __restrict__ y_part,
                                                  const float* __restrict__ b_dcn,
                                                  const float* __restrict__ st,
                                                  ushort* __restrict__ ybn) {
  __shared__ float tile[128 * 65];
  int b = blockIdx.x >> 4, pg = blockIdx.x & 15;  // 64-pixel group
  int tid = threadIdx.x;
#pragma unroll 4
  for (int it = 0; it < 32; ++it) {
    int idx = it * 256 + tid;
    int c = idx >> 6, prel = idx & 63;
    size_t base = ((size_t)b * 128 + c) * HW + pg * 64 + prel;
    float v = y_part[base] + y_part[2097152 + base]
            + y_part[4194304 + base] + y_part[6291456 + base] + b_dcn[c];
    float r = fmaxf(fmaf(v, st[c], st[128 + c]), 0.f);
    tile[c * 65 + prel] = r;
  }
  __syncthreads();
#pragma unroll 4
  for (int it = 0; it < 32; ++it) {
    int idx = it * 256 + tid;
    int prel = idx >> 7, c = idx & 127;
    ybn[((size_t)b * 1024 + pg * 64 + prel) * 128 + c] = f2bf(tile[c * 65 + prel]);
  }
}

// ---------------- 7. deconv as 4 parity GEMMs, bf16 MFMA --------------------------
// per block: par, b, 128-pixel tile; M=128, N=128, K=512 (c x 4 taps)
__global__ __launch_bounds__(256) void deconv_mfma_kernel(const ushort* __restrict__ ybn,
                                                          const ushort* __restrict__ bp,
                                                          float* __restrict__ O) {
  __shared__ ushort As[128 * 72];
  __shared__ ushort Bs[128 * 72];
  int blk = blockIdx.x;
  int ptile = blk & 7, par = (blk >> 3) & 3, b = blk >> 5;
  int pu = par >> 1, pv = par & 1;
  int tid = threadIdx.x;
  int wid = tid >> 6, lane = tid & 63, lr = lane & 15, quad = lane >> 4;
  int m_w = (wid & 1) * 64, n_w = (wid >> 1) * 64;
  int P0 = ptile * 128;
  int sm = tid >> 1, shalf = tid & 1;
  int pix = P0 + sm, uu = pix >> 5, vv = pix & 31;

  floatx4 acc[4][4];
#pragma unroll
  for (int mi = 0; mi < 4; ++mi)
#pragma unroll
    for (int ni = 0; ni < 4; ++ni) acc[mi][ni] = (floatx4)0.f;

  for (int kk = 0; kk < 8; ++kk) {
    int t = kk >> 1, chalf = (kk & 1) * 64;
    int ty = t >> 1, tx = t & 1;
    int i = uu + pu - ty, j = vv + pv - tx;
    bool valid = (i >= 0) && (i <= 31) && (j >= 0) && (j <= 31);
    int pos = min(max(i, 0), 31) * 32 + min(max(j, 0), 31);
    const float4* ga = (const float4*)(ybn + ((size_t)(b * 1024 + pos) * 128 + chalf + shalf * 32));
    const float4* gb = (const float4*)(bp + ((size_t)(par * 128 + sm) * 512 + kk * 64 + shalf * 32));
    float4 a0 = ga[0], a1 = ga[1], a2 = ga[2], a3 = ga[3];
    float4 b0 = gb[0], b1 = gb[1], b2 = gb[2], b3 = gb[3];
    if (!valid) { a0 = a1 = a2 = a3 = make_float4(0.f, 0.f, 0.f, 0.f); }
    if (kk) __syncthreads();
    float4* qa = (float4*)(As + sm * 72 + shalf * 32);
    qa[0] = a0; qa[1] = a1; qa[2] = a2; qa[3] = a3;
    float4* qb = (float4*)(Bs + sm * 72 + shalf * 32);
    qb[0] = b0; qb[1] = b1; qb[2] = b2; qb[3] = b3;
    __syncthreads();
#pragma unroll
    for (int k2 = 0; k2 < 64; k2 += 32) {
      short8 af[4], bfr[4];
#pragma unroll
      for (int mi = 0; mi < 4; ++mi)
        af[mi] = *(const short8*)(As + (m_w + mi * 16 + lr) * 72 + k2 + quad * 8);
#pragma unroll
      for (int ni = 0; ni < 4; ++ni)
        bfr[ni] = *(const short8*)(Bs + (n_w + ni * 16 + lr) * 72 + k2 + quad * 8);
#pragma unroll
      for (int mi = 0; mi < 4; ++mi)
#pragma unroll
        for (int ni = 0; ni < 4; ++ni)
          acc[mi][ni] = __builtin_amdgcn_mfma_f32_16x16x32_bf16(af[mi], bfr[ni], acc[mi][ni], 0, 0, 0);
    }
  }
  // epilogue: O[b][par][pix][oc] fp32
  size_t obase = (size_t)(b * 4 + par) * 1024 * 128;
#pragma unroll
  for (int mi = 0; mi < 4; ++mi) {
#pragma unroll
    for (int r = 0; r < 4; ++r) {
      int m = m_w + mi * 16 + quad * 4 + r;
      float* orow = O + obase + (size_t)(P0 + m) * 128;
#pragma unroll
      for (int ni = 0; ni < 4; ++ni)
        orow[n_w + ni * 16 + lr] = acc[mi][ni][r];
    }
  }
}

// ---------------- 8. BN2 stats partials -------------------------------------------
__global__ __launch_bounds__(256) void stats2_part_kernel(const float* __restrict__ O,
                                                          float* __restrict__ stp) {
  int blk = blockIdx.x; int tid = threadIdx.x;
  int oc = tid & 127, rh = tid >> 7;
  size_t base = (size_t)blk * 128 * 128;
  float s = 0.f, sq = 0.f;
  for (int r = rh; r < 128; r += 2) {
    float v = O[base + (size_t)r * 128 + oc];
    s += v; sq = fmaf(v, v, sq);
  }
  __shared__ float ls[256], lq[256];
  ls[tid] = s; lq[tid] = sq; __syncthreads();
  if (tid < 128) {
    stp[(size_t)blk * 128 + tid] = ls[tid] + ls[tid + 128];
    stp[65536 + (size_t)blk * 128 + tid] = lq[tid] + lq[tid + 128];
  }
}

// ---------------- 9. BN2 stats final ----------------------------------------------
__global__ __launch_bounds__(256) void stats2_final_kernel(const float* __restrict__ stp,
                                                           const float* __restrict__ g,
                                                           const float* __restrict__ bt,
                                                           float* __restrict__ st) {
  int tid = threadIdx.x;
  if (tid >= 128) return;
  float s = 0.f, sq = 0.f;
  for (int i = 0; i < 512; ++i) {
    s += stp[(size_t)i * 128 + tid];
    sq += stp[65536 + (size_t)i * 128 + tid];
  }
  float n = 65536.f;
  float mean = s / n;
  float var = sq / n - mean * mean;
  float sc = g[tid] * rsqrtf(var + EPSV);
  st[tid] = sc;
  st[128 + tid] = fmaf(-mean, sc, bt[tid]);
}

// ---------------- 10. BN2+ReLU + transpose to NCHW out ----------------------------
__global__ __launch_bounds__(256) void bnout_kernel(const float* __restrict__ O,
                                                    const float* __restrict__ st,
                                                    float* __restrict__ out) {
  __shared__ float tile[128 * 33];
  int blk = blockIdx.x;
  int uu = blk & 31, par = (blk >> 5) & 3, b = blk >> 7;
  int pu = par >> 1, pv = par & 1;
  int tid = threadIdx.x;
#pragma unroll 4
  for (int it = 0; it < 16; ++it) {
    int idx = it * 256 + tid;
    int vv = idx >> 7, oc = idx & 127;
    float v = O[((size_t)(b * 4 + par) * 1024 + uu * 32 + vv) * 128 + oc];
    tile[oc * 33 + vv] = fmaxf(fmaf(v, st[oc], st[128 + oc]), 0.f);
  }
  __syncthreads();
#pragma unroll 4
  for (int it = 0; it < 16; ++it) {
    int idx = it * 256 + tid;
    int oc = idx >> 5, vv = idx & 31;
    out[((size_t)b * 128 + oc) * 4096 + (2 * uu + pu) * 64 + 2 * vv + pv] = tile[oc * 33 + vv];
  }
}

extern "C" void kernel_launch(void* const* d_in, const int* in_sizes, int n_in,
                              void* d_out, int out_size, void* d_ws, size_t ws_size,
                              hipStream_t stream) {
  const float* x     = (const float*)d_in[0];
  const float* w_off = (const float*)d_in[1];
  const float* b_off = (const float*)d_in[2];
  const float* w_dcn = (const float*)d_in[3];
  const float* b_dcn = (const float*)d_in[4];
  const float* g1    = (const float*)d_in[5];
  const float* bt1   = (const float*)d_in[6];
  const float* w_up  = (const float*)d_in[7];
  const float* g2    = (const float*)d_in[8];
  const float* bt2   = (const float*)d_in[9];
  float* ws  = (float*)d_ws;
  float* out = (float*)d_out;

  prep_kernel<<<2419, 256, 0, stream>>>(w_off, w_dcn, w_up, ws);
  offconv_kernel<<<dim3(64, 8), 256, 0, stream>>>(x, ws + WT_OFF, ws + BIG);
  offreduce_kernel<<<1728, 256, 0, stream>>>(ws + BIG, b_off, ws + OFFB);
  deform_kernel<<<dim3(64, 2, 4), 256, 0, stream>>>(x, ws + OFFB, ws + WT_DCN, ws + BIG);
  stats1_kernel<<<128, 256, 0, stream>>>(ws + BIG, b_dcn, g1, bt1, ws + ST1);
  ybn_kernel<<<256, 256, 0, stream>>>(ws + BIG, b_dcn, ws + ST1, (ushort*)(ws + YBN_F));
  deconv_mfma_kernel<<<512, 256, 0, stream>>>((const ushort*)(ws + YBN_F),
                                              (const ushort*)(ws + BP), ws + BIG);
  stats2_part_kernel<<<512, 256, 0, stream>>>(ws + BIG, ws + STP);
  stats2_final_kernel<<<1, 256, 0, stream>>>(ws + STP, g2, bt2, ws + ST2);
  bnout_kernel<<<2048, 256, 0, stream>>>(ws + BIG, ws + ST2, out);
}

// Round 3
// 306.400 us; speedup vs baseline: 2.7734x; 1.5241x over previous
//
#include <hip/hip_runtime.h>
#include <hip/hip_fp16.h>
#include <math.h>

#define HW 1024
#define EPSV 1e-5f

typedef unsigned int uint;
typedef unsigned short ushort;
typedef __attribute__((ext_vector_type(8))) short short8;
typedef __attribute__((ext_vector_type(8))) _Float16 half8;
typedef __attribute__((ext_vector_type(4))) float floatx4;

// ---------------- ws layout (float offsets) ----------------------------------------
static const size_t WT_OFF = 0;        // 65536   fp32 wt for offconv       (1->3)
static const size_t BD     = 65536;    // 147456  fp16 Bd[oc][tap*256+c]    (1->5)
static const size_t BP     = 212992;   // 131072  bf16 Bp[par][oc][k]       (1->9)
static const size_t XT     = 344064;   // 2097152 fp16 xT[b][p][c]          (2->5); YBN bf16 aliases (8->9)
static const size_t OFFB   = 2441216;  // 442368  offsets                   (4->5)
static const size_t ST1    = 2883584;  // 256
static const size_t ST2    = 2883840;  // 256
static const size_t STP    = 2884096;  // 131072  stats partials (reused)
static const size_t BIG    = 3015168;  // 8388608 off_part(3-4)/y_part(5-8)/O(9-12)
// total = 11403776 floats = 45.6 MB (< 46.2 MB proven in round 1)

__device__ inline ushort f2bf(float f) {
  uint u = __builtin_bit_cast(uint, f);
  uint r = (u + 0x7FFFu + ((u >> 16) & 1u)) >> 16;
  return (ushort)r;
}

// ---------------- 1. prep: weight transposes ---------------------------------------
__global__ __launch_bounds__(256) void prep_kernel(const float* __restrict__ w_off,
                                                   const float* __restrict__ w_dcn,
                                                   const float* __restrict__ w_up,
                                                   float* __restrict__ ws) {
  int i = blockIdx.x * 256 + threadIdx.x;
  if (i < 62208) {
    int kk = i % 9; int c = (i / 9) & 255; int j = i / 2304;
    ws[WT_OFF + (size_t)c * 256 + j * 9 + kk] = w_off[i];
  } else if (i < 62208 + 294912) {
    int d = i - 62208;            // d = oc*2304 + tap*256 + c
    int oc = d / 2304; int k = d % 2304;
    int tap = k >> 8; int c = k & 255;
    ((__half*)(ws + BD))[d] = __float2half(w_dcn[((size_t)oc * 256 + c) * 9 + tap]);
  } else if (i < 62208 + 294912 + 262144) {
    int d = i - (62208 + 294912);
    int par = d >> 16; int rem = d & 65535;
    int o = rem >> 9; int k = rem & 511;
    int t4 = k >> 7; int c = k & 127;
    int ty = t4 >> 1, tx = t4 & 1;
    int pu = par >> 1, pv = par & 1;
    int ky = (1 - pu) + 2 * ty, kx = (1 - pv) + 2 * tx;
    float v = w_up[((size_t)c * 128 + o) * 16 + ky * 4 + kx];
    ((ushort*)(ws + BP))[d] = f2bf(v);
  }
}

// ---------------- 2. xT: x[b][c][p] fp32 -> xT[b][p][c] fp16 -----------------------
__global__ __launch_bounds__(256) void xt_kernel(const float* __restrict__ x,
                                                 uint* __restrict__ xtu) {
  __shared__ float tile[64 * 65];
  int blk = blockIdx.x;
  int b = blk >> 6, pt = (blk >> 2) & 15, cc = blk & 3;
  int p0 = pt * 64, c0 = cc * 64;
  int tid = threadIdx.x;
  int pp = tid & 63, ci = tid >> 6;
#pragma unroll
  for (int it = 0; it < 16; ++it) {
    int c = it * 4 + ci;
    tile[c * 65 + pp] = x[((size_t)(b * 256 + c0 + c)) * HW + p0 + pp];
  }
  __syncthreads();
  int cp = tid & 31, pp2 = tid >> 5;
#pragma unroll
  for (int it = 0; it < 8; ++it) {
    int p = it * 8 + pp2;
    __half2 h = __floats2half2_rn(tile[(2 * cp) * 65 + p], tile[(2 * cp + 1) * 65 + p]);
    xtu[(size_t)(b * 1024 + p0 + p) * 128 + cc * 32 + cp] = __builtin_bit_cast(uint, h);
  }
}

// ---------------- 3. offset conv: 256->27 (8 cin-splits) ---------------------------
__global__ __launch_bounds__(256) void offconv_kernel(const float* __restrict__ x,
                                                      const float* __restrict__ wt,
                                                      float* __restrict__ off_part) {
  int b = blockIdx.x >> 2, pg = blockIdx.x & 3;
  int cs = blockIdx.y;
  int tid = threadIdx.x;
  int p = pg * 256 + tid;
  int h = p >> 5, w = p & 31;
  float acc[27];
#pragma unroll
  for (int j = 0; j < 27; ++j) acc[j] = 0.f;

  int ofs[9]; float msk[9];
#pragma unroll
  for (int t = 0; t < 9; ++t) {
    int ky = t / 3, kx = t % 3;
    int yy = h + ky - 1, xx = w + kx - 1;
    bool v = (yy >= 0) && (yy < 32) && (xx >= 0) && (xx < 32);
    int yc = min(max(yy, 0), 31), xc = min(max(xx, 0), 31);
    ofs[t] = yc * 32 + xc;
    msk[t] = v ? 1.f : 0.f;
  }
  const float* xb = x + (size_t)(b * 256 + cs * 32) * HW;
  for (int c = 0; c < 32; ++c) {
    const float* xc = xb + (size_t)c * HW;
    float xv[9];
#pragma unroll
    for (int t = 0; t < 9; ++t) xv[t] = xc[ofs[t]] * msk[t];
    const float* wr = wt + (size_t)(cs * 32 + c) * 256;
#pragma unroll
    for (int j = 0; j < 27; ++j)
#pragma unroll
      for (int kk = 0; kk < 9; ++kk)
        acc[j] = fmaf(xv[kk], wr[j * 9 + kk], acc[j]);
  }
  float* op = off_part + (size_t)cs * 442368 + (size_t)b * 27 * HW + p;
#pragma unroll
  for (int j = 0; j < 27; ++j) op[(size_t)j * HW] = acc[j];
}

// ---------------- 4. reduce offsets + bias + sigmoid -------------------------------
__global__ __launch_bounds__(256) void offreduce_kernel(const float* __restrict__ off_part,
                                                        const float* __restrict__ b_off,
                                                        float* __restrict__ off) {
  int i = blockIdx.x * 256 + threadIdx.x;
  if (i >= 442368) return;
  float s = 0.f;
#pragma unroll
  for (int cs = 0; cs < 8; ++cs) s += off_part[(size_t)cs * 442368 + i];
  int ch = (i >> 10) % 27;
  s += b_off[ch];
  if (ch >= 18) s = 1.f / (1.f + __expf(-s));
  off[i] = s;
}

// ---------------- 5. deformable conv via fused gather + f16 MFMA -------------------
// block: (b, ptile of 128 pixels, cs quarter of 64 cin). K = 9 taps x 64 c.
// y_part[cs][b*1024+pix][oc] fp32
__global__ __launch_bounds__(256) void deform_mfma_kernel(const __half* __restrict__ xt,
                                                          const float* __restrict__ off,
                                                          const __half* __restrict__ bd,
                                                          float* __restrict__ y_part) {
  __shared__ short As[128 * 72];
  __shared__ short Bs[128 * 72];
  int blk = blockIdx.x;
  int ptile = blk & 7, cs = (blk >> 3) & 3, b = blk >> 5;
  int tid = threadIdx.x;
  int wid = tid >> 6, lane = tid & 63, lr = lane & 15, quad = lane >> 4;
  int m_w = (wid & 1) * 64, n_w = (wid >> 1) * 64;
  int P0 = ptile * 128;
  int pix_l = tid >> 1, chalf = (tid & 1) * 32;
  int pix = P0 + pix_l;
  int h = pix >> 5, w = pix & 31;
  const float* offb = off + (size_t)b * 27 * HW + pix;
  const __half* xb = xt + (size_t)b * 1024 * 256 + cs * 64 + chalf;
  int ocb = tid >> 1, seg = tid & 1;
  const __half* bdr = bd + (size_t)ocb * 2304 + cs * 64 + seg * 32;

  floatx4 acc[4][4];
#pragma unroll
  for (int mi = 0; mi < 4; ++mi)
#pragma unroll
    for (int ni = 0; ni < 4; ++ni) acc[mi][ni] = (floatx4)0.f;

  for (int tap = 0; tap < 9; ++tap) {
    float dy = offb[(size_t)(2 * tap) * HW];
    float dx = offb[(size_t)(2 * tap + 1) * HW];
    float mm = offb[(size_t)(18 + tap) * HW];
    float py = (float)(h + tap / 3 - 1) + dy;
    float px = (float)(w + tap % 3 - 1) + dx;
    float y0f = floorf(py), x0f = floorf(px);
    float wy = py - y0f, wx = px - x0f;
    int y0 = (int)y0f, x0 = (int)x0f;
    float cw[4] = {(1.f - wy) * (1.f - wx), (1.f - wy) * wx, wy * (1.f - wx), wy * wx};
    uint4 q[4][4];
    __half2 w2[4];
#pragma unroll
    for (int t = 0; t < 4; ++t) {
      int yy = y0 + (t >> 1), xx = x0 + (t & 1);
      bool v = (yy >= 0) && (yy <= 31) && (xx >= 0) && (xx <= 31);
      int yc = min(max(yy, 0), 31), xc = min(max(xx, 0), 31);
      const uint4* xr = (const uint4*)(xb + (size_t)(yc * 32 + xc) * 256);
      q[t][0] = xr[0]; q[t][1] = xr[1]; q[t][2] = xr[2]; q[t][3] = xr[3];
      w2[t] = __float2half2_rn(v ? cw[t] * mm : 0.f);
    }
    const float4* gb = (const float4*)(bdr + tap * 256);
    float4 b0 = gb[0], b1 = gb[1], b2 = gb[2], b3 = gb[3];

    __half2 hacc[16];
#pragma unroll
    for (int j = 0; j < 16; ++j) hacc[j] = __float2half2_rn(0.f);
#pragma unroll
    for (int t = 0; t < 4; ++t) {
      uint qa[16] = {q[t][0].x, q[t][0].y, q[t][0].z, q[t][0].w,
                     q[t][1].x, q[t][1].y, q[t][1].z, q[t][1].w,
                     q[t][2].x, q[t][2].y, q[t][2].z, q[t][2].w,
                     q[t][3].x, q[t][3].y, q[t][3].z, q[t][3].w};
#pragma unroll
      for (int j = 0; j < 16; ++j)
        hacc[j] = __hfma2(w2[t], __builtin_bit_cast(__half2, qa[j]), hacc[j]);
    }
    if (tap) __syncthreads();
    // write As: 32 halves at row pix_l, col chalf
#pragma unroll
    for (int g = 0; g < 4; ++g) {
      float4 f;
      f.x = __builtin_bit_cast(float, hacc[4 * g + 0]);
      f.y = __builtin_bit_cast(float, hacc[4 * g + 1]);
      f.z = __builtin_bit_cast(float, hacc[4 * g + 2]);
      f.w = __builtin_bit_cast(float, hacc[4 * g + 3]);
      *(float4*)(As + pix_l * 72 + chalf + g * 8) = f;
    }
    *(float4*)(Bs + ocb * 72 + seg * 32 + 0)  = b0;
    *(float4*)(Bs + ocb * 72 + seg * 32 + 8)  = b1;
    *(float4*)(Bs + ocb * 72 + seg * 32 + 16) = b2;
    *(float4*)(Bs + ocb * 72 + seg * 32 + 24) = b3;
    __syncthreads();
#pragma unroll
    for (int k2 = 0; k2 < 2; ++k2) {
      half8 af[4], bf[4];
#pragma unroll
      for (int mi = 0; mi < 4; ++mi)
        af[mi] = *(const half8*)(As + (m_w + mi * 16 + lr) * 72 + k2 * 32 + quad * 8);
#pragma unroll
      for (int ni = 0; ni < 4; ++ni)
        bf[ni] = *(const half8*)(Bs + (n_w + ni * 16 + lr) * 72 + k2 * 32 + quad * 8);
#pragma unroll
      for (int mi = 0; mi < 4; ++mi)
#pragma unroll
        for (int ni = 0; ni < 4; ++ni)
          acc[mi][ni] = __builtin_amdgcn_mfma_f32_16x16x32_f16(af[mi], bf[ni], acc[mi][ni], 0, 0, 0);
    }
  }
  float* yp = y_part + (size_t)cs * 2097152 + ((size_t)(b * 1024 + P0)) * 128;
#pragma unroll
  for (int mi = 0; mi < 4; ++mi) {
#pragma unroll
    for (int r = 0; r < 4; ++r) {
      int m = m_w + mi * 16 + quad * 4 + r;
      float* orow = yp + (size_t)m * 128;
#pragma unroll
      for (int ni = 0; ni < 4; ++ni)
        orow[n_w + ni * 16 + lr] = acc[mi][ni][r];
    }
  }
}

// ---------------- 6. BN1 stats partials over [pix][oc] -----------------------------
__global__ __launch_bounds__(256) void stats1_part_kernel(const float* __restrict__ P,
                                                          const float* __restrict__ b_dcn,
                                                          float* __restrict__ stp) {
  int blk = blockIdx.x; int tid = threadIdx.x;
  int oc = tid & 127, rh = tid >> 7;
  float bias = b_dcn[oc];
  float s = 0.f, sq = 0.f;
  for (int r = rh; r < 128; r += 2) {
    size_t idx = ((size_t)blk * 128 + r) * 128 + oc;
    float v = P[idx] + P[2097152 + idx] + P[4194304 + idx] + P[6291456 + idx] + bias;
    s += v; sq = fmaf(v, v, sq);
  }
  __shared__ float ls[256], lq[256];
  ls[tid] = s; lq[tid] = sq; __syncthreads();
  if (tid < 128) {
    stp[(size_t)blk * 128 + tid] = ls[tid] + ls[tid + 128];
    stp[16384 + (size_t)blk * 128 + tid] = lq[tid] + lq[tid + 128];
  }
}

__global__ __launch_bounds__(256) void stats1_final_kernel(const float* __restrict__ stp,
                                                           const float* __restrict__ g,
                                                           const float* __restrict__ bt,
                                                           float* __restrict__ st) {
  int tid = threadIdx.x;
  if (tid >= 128) return;
  float s = 0.f, sq = 0.f;
  for (int i = 0; i < 128; ++i) {
    s += stp[(size_t)i * 128 + tid];
    sq += stp[16384 + (size_t)i * 128 + tid];
  }
  float n = 16384.f;
  float mean = s / n;
  float var = sq / n - mean * mean;
  float sc = g[tid] * rsqrtf(var + EPSV);
  st[tid] = sc;
  st[128 + tid] = fmaf(-mean, sc, bt[tid]);
}

// ---------------- 7. ybn: reduce + bias + BN + ReLU -> bf16 [pix][c] ---------------
__global__ __launch_bounds__(256) void ybn_kernel(const float* __restrict__ P,
                                                  const float* __restrict__ b_dcn,
                                                  const float* __restrict__ st,
                                                  ushort* __restrict__ ybn) {
  int i4 = blockIdx.x * 256 + threadIdx.x;
  size_t i = (size_t)i4 * 4;
  int oc = (int)(i & 127);
  float4 v = *(const float4*)(P + i);
  float4 v1 = *(const float4*)(P + 2097152 + i);
  float4 v2 = *(const float4*)(P + 4194304 + i);
  float4 v3 = *(const float4*)(P + 6291456 + i);
  ushort r[4];
  float vv[4] = {v.x + v1.x + v2.x + v3.x, v.y + v1.y + v2.y + v3.y,
                 v.z + v1.z + v2.z + v3.z, v.w + v1.w + v2.w + v3.w};
#pragma unroll
  for (int j = 0; j < 4; ++j) {
    float t = vv[j] + b_dcn[oc + j];
    r[j] = f2bf(fmaxf(fmaf(t, st[oc + j], st[128 + oc + j]), 0.f));
  }
  uint2 pk;
  pk.x = (uint)r[0] | ((uint)r[1] << 16);
  pk.y = (uint)r[2] | ((uint)r[3] << 16);
  *(uint2*)(ybn + i) = pk;
}

// ---------------- 8. deconv as 4 parity GEMMs, bf16 MFMA ---------------------------
__global__ __launch_bounds__(256) void deconv_mfma_kernel(const ushort* __restrict__ ybn,
                                                          const ushort* __restrict__ bp,
                                                          float* __restrict__ O) {
  __shared__ ushort As[128 * 72];
  __shared__ ushort Bs[128 * 72];
  int blk = blockIdx.x;
  int ptile = blk & 7, par = (blk >> 3) & 3, b = blk >> 5;
  int pu = par >> 1, pv = par & 1;
  int tid = threadIdx.x;
  int wid = tid >> 6, lane = tid & 63, lr = lane & 15, quad = lane >> 4;
  int m_w = (wid & 1) * 64, n_w = (wid >> 1) * 64;
  int P0 = ptile * 128;
  int sm = tid >> 1, shalf = tid & 1;
  int pix = P0 + sm, uu = pix >> 5, vv = pix & 31;

  floatx4 acc[4][4];
#pragma unroll
  for (int mi = 0; mi < 4; ++mi)
#pragma unroll
    for (int ni = 0; ni < 4; ++ni) acc[mi][ni] = (floatx4)0.f;

  for (int kk = 0; kk < 8; ++kk) {
    int t = kk >> 1, chalf = (kk & 1) * 64;
    int ty = t >> 1, tx = t & 1;
    int i = uu + pu - ty, j = vv + pv - tx;
    bool valid = (i >= 0) && (i <= 31) && (j >= 0) && (j <= 31);
    int pos = min(max(i, 0), 31) * 32 + min(max(j, 0), 31);
    const float4* ga = (const float4*)(ybn + ((size_t)(b * 1024 + pos) * 128 + chalf + shalf * 32));
    const float4* gb = (const float4*)(bp + ((size_t)(par * 128 + sm) * 512 + kk * 64 + shalf * 32));
    float4 a0 = ga[0], a1 = ga[1], a2 = ga[2], a3 = ga[3];
    float4 b0 = gb[0], b1 = gb[1], b2 = gb[2], b3 = gb[3];
    if (!valid) { a0 = a1 = a2 = a3 = make_float4(0.f, 0.f, 0.f, 0.f); }
    if (kk) __syncthreads();
    float4* qa = (float4*)(As + sm * 72 + shalf * 32);
    qa[0] = a0; qa[1] = a1; qa[2] = a2; qa[3] = a3;
    float4* qb = (float4*)(Bs + sm * 72 + shalf * 32);
    qb[0] = b0; qb[1] = b1; qb[2] = b2; qb[3] = b3;
    __syncthreads();
#pragma unroll
    for (int k2 = 0; k2 < 64; k2 += 32) {
      short8 af[4], bfr[4];
#pragma unroll
      for (int mi = 0; mi < 4; ++mi)
        af[mi] = *(const short8*)(As + (m_w + mi * 16 + lr) * 72 + k2 + quad * 8);
#pragma unroll
      for (int ni = 0; ni < 4; ++ni)
        bfr[ni] = *(const short8*)(Bs + (n_w + ni * 16 + lr) * 72 + k2 + quad * 8);
#pragma unroll
      for (int mi = 0; mi < 4; ++mi)
#pragma unroll
        for (int ni = 0; ni < 4; ++ni)
          acc[mi][ni] = __builtin_amdgcn_mfma_f32_16x16x32_bf16(af[mi], bfr[ni], acc[mi][ni], 0, 0, 0);
    }
  }
  size_t obase = (size_t)(b * 4 + par) * 1024 * 128;
#pragma unroll
  for (int mi = 0; mi < 4; ++mi) {
#pragma unroll
    for (int r = 0; r < 4; ++r) {
      int m = m_w + mi * 16 + quad * 4 + r;
      float* orow = O + obase + (size_t)(P0 + m) * 128;
#pragma unroll
      for (int ni = 0; ni < 4; ++ni)
        orow[n_w + ni * 16 + lr] = acc[mi][ni][r];
    }
  }
}

// ---------------- 9. BN2 stats ----------------------------------------------------
__global__ __launch_bounds__(256) void stats2_part_kernel(const float* __restrict__ O,
                                                          float* __restrict__ stp) {
  int blk = blockIdx.x; int tid = threadIdx.x;
  int oc = tid & 127, rh = tid >> 7;
  size_t base = (size_t)blk * 128 * 128;
  float s = 0.f, sq = 0.f;
  for (int r = rh; r < 128; r += 2) {
    float v = O[base + (size_t)r * 128 + oc];
    s += v; sq = fmaf(v, v, sq);
  }
  __shared__ float ls[256], lq[256];
  ls[tid] = s; lq[tid] = sq; __syncthreads();
  if (tid < 128) {
    stp[(size_t)blk * 128 + tid] = ls[tid] + ls[tid + 128];
    stp[65536 + (size_t)blk * 128 + tid] = lq[tid] + lq[tid + 128];
  }
}

__global__ __launch_bounds__(256) void stats2_final_kernel(const float* __restrict__ stp,
                                                           const float* __restrict__ g,
                                                           const float* __restrict__ bt,
                                                           float* __restrict__ st) {
  int tid = threadIdx.x;
  if (tid >= 128) return;
  float s = 0.f, sq = 0.f;
  for (int i = 0; i < 512; ++i) {
    s += stp[(size_t)i * 128 + tid];
    sq += stp[65536 + (size_t)i * 128 + tid];
  }
  float n = 65536.f;
  float mean = s / n;
  float var = sq / n - mean * mean;
  float sc = g[tid] * rsqrtf(var + EPSV);
  st[tid] = sc;
  st[128 + tid] = fmaf(-mean, sc, bt[tid]);
}

// ---------------- 10. BN2+ReLU + transpose to NCHW out -----------------------------
__global__ __launch_bounds__(256) void bnout_kernel(const float* __restrict__ O,
                                                    const float* __restrict__ st,
                                                    float* __restrict__ out) {
  __shared__ float tile[128 * 33];
  int blk = blockIdx.x;
  int uu = blk & 31, par = (blk >> 5) & 3, b = blk >> 7;
  int pu = par >> 1, pv = par & 1;
  int tid = threadIdx.x;
#pragma unroll 4
  for (int it = 0; it < 16; ++it) {
    int idx = it * 256 + tid;
    int vv = idx >> 7, oc = idx & 127;
    float v = O[((size_t)(b * 4 + par) * 1024 + uu * 32 + vv) * 128 + oc];
    tile[oc * 33 + vv] = fmaxf(fmaf(v, st[oc], st[128 + oc]), 0.f);
  }
  __syncthreads();
#pragma unroll 4
  for (int it = 0; it < 16; ++it) {
    int idx = it * 256 + tid;
    int oc = idx >> 5, vv = idx & 31;
    out[((size_t)b * 128 + oc) * 4096 + (2 * uu + pu) * 64 + 2 * vv + pv] = tile[oc * 33 + vv];
  }
}

extern "C" void kernel_launch(void* const* d_in, const int* in_sizes, int n_in,
                              void* d_out, int out_size, void* d_ws, size_t ws_size,
                              hipStream_t stream) {
  const float* x     = (const float*)d_in[0];
  const float* w_off = (const float*)d_in[1];
  const float* b_off = (const float*)d_in[2];
  const float* w_dcn = (const float*)d_in[3];
  const float* b_dcn = (const float*)d_in[4];
  const float* g1    = (const float*)d_in[5];
  const float* bt1   = (const float*)d_in[6];
  const float* w_up  = (const float*)d_in[7];
  const float* g2    = (const float*)d_in[8];
  const float* bt2   = (const float*)d_in[9];
  float* ws  = (float*)d_ws;
  float* out = (float*)d_out;

  prep_kernel<<<2419, 256, 0, stream>>>(w_off, w_dcn, w_up, ws);
  xt_kernel<<<1024, 256, 0, stream>>>(x, (uint*)(ws + XT));
  offconv_kernel<<<dim3(64, 8), 256, 0, stream>>>(x, ws + WT_OFF, ws + BIG);
  offreduce_kernel<<<1728, 256, 0, stream>>>(ws + BIG, b_off, ws + OFFB);
  deform_mfma_kernel<<<512, 256, 0, stream>>>((const __half*)(ws + XT), ws + OFFB,
                                              (const __half*)(ws + BD), ws + BIG);
  stats1_part_kernel<<<128, 256, 0, stream>>>(ws + BIG, b_dcn, ws + STP);
  stats1_final_kernel<<<1, 256, 0, stream>>>(ws + STP, g1, bt1, ws + ST1);
  ybn_kernel<<<2048, 256, 0, stream>>>(ws + BIG, b_dcn, ws + ST1, (ushort*)(ws + XT));
  deconv_mfma_kernel<<<512, 256, 0, stream>>>((const ushort*)(ws + XT),
                                              (const ushort*)(ws + BP), ws + BIG);
  stats2_part_kernel<<<512, 256, 0, stream>>>(ws + BIG, ws + STP);
  stats2_final_kernel<<<1, 256, 0, stream>>>(ws + STP, g2, bt2, ws + ST2);
  bnout_kernel<<<2048, 256, 0, stream>>>(ws + BIG, ws + ST2, out);
}

// Round 4
// 250.053 us; speedup vs baseline: 3.3983x; 1.2253x over previous
//
#include <hip/hip_runtime.h>
#include <hip/hip_fp16.h>
#include <math.h>

#define HW 1024
#define EPSV 1e-5f

typedef unsigned int uint;
typedef unsigned short ushort;
typedef __attribute__((ext_vector_type(8))) short short8;
typedef __attribute__((ext_vector_type(8))) _Float16 half8;
typedef __attribute__((ext_vector_type(4))) float floatx4;

// ---------------- ws layout (float offsets) ----------------------------------------
static const size_t BOFF = 0;        // 36864   fp16 Boff[tap][n32][c256]   (1->3)
static const size_t BD   = 36864;    // 147456  fp16 Bd[oc][tap*256+c]      (1->5)
static const size_t BP   = 184320;   // 131072  bf16 Bp[par][oc][k]         (1->9)
static const size_t XT   = 315392;   // 2097152 fp16 xT[b][p][c] (2->5); YBN bf16 aliases (8->9)
static const size_t OFFB = 2412544;  // 524288  off [b][pix][32] fp32       (4->5)
static const size_t ST1  = 2936832;  // 256
static const size_t ST2  = 2937088;  // 256
static const size_t STP  = 2937344;  // 131072  stats partials (reused)
static const size_t BIG  = 3068416;  // 8388608 opart(3-4)/y_part(5-8)/O(9-12)
// total = 11457024 floats = 45.8 MB (< 46.2 MB proven in round 1)

__device__ inline ushort f2bf(float f) {
  uint u = __builtin_bit_cast(uint, f);
  uint r = (u + 0x7FFFu + ((u >> 16) & 1u)) >> 16;
  return (ushort)r;
}

// ---------------- 1. prep: weight transposes ---------------------------------------
__global__ __launch_bounds__(256) void prep_kernel(const float* __restrict__ w_off,
                                                   const float* __restrict__ w_dcn,
                                                   const float* __restrict__ w_up,
                                                   float* __restrict__ ws) {
  int i = blockIdx.x * 256 + threadIdx.x;
  if (i < 73728) {
    // Boff[tap][n][c], zero-padded n>=27
    int c = i & 255; int n = (i >> 8) & 31; int tap = i >> 13;
    float v = (n < 27) ? w_off[((size_t)n * 256 + c) * 9 + tap] : 0.f;
    ((__half*)(ws + BOFF))[i] = __float2half(v);
  } else if (i < 73728 + 294912) {
    int d = i - 73728;            // d = oc*2304 + tap*256 + c
    int oc = d / 2304; int k = d % 2304;
    int tap = k >> 8; int c = k & 255;
    ((__half*)(ws + BD))[d] = __float2half(w_dcn[((size_t)oc * 256 + c) * 9 + tap]);
  } else if (i < 73728 + 294912 + 262144) {
    int d = i - (73728 + 294912);
    int par = d >> 16; int rem = d & 65535;
    int o = rem >> 9; int k = rem & 511;
    int t4 = k >> 7; int c = k & 127;
    int ty = t4 >> 1, tx = t4 & 1;
    int pu = par >> 1, pv = par & 1;
    int ky = (1 - pu) + 2 * ty, kx = (1 - pv) + 2 * tx;
    float v = w_up[((size_t)c * 128 + o) * 16 + ky * 4 + kx];
    ((ushort*)(ws + BP))[d] = f2bf(v);
  }
}

// ---------------- 2. xT: x[b][c][p] fp32 -> xT[b][p][c] fp16 -----------------------
__global__ __launch_bounds__(256) void xt_kernel(const float* __restrict__ x,
                                                 uint* __restrict__ xtu) {
  __shared__ float tile[64 * 65];
  int blk = blockIdx.x;
  int b = blk >> 6, pt = (blk >> 2) & 15, cc = blk & 3;
  int p0 = pt * 64, c0 = cc * 64;
  int tid = threadIdx.x;
  int pp = tid & 63, ci = tid >> 6;
#pragma unroll
  for (int it = 0; it < 16; ++it) {
    int c = it * 4 + ci;
    tile[c * 65 + pp] = x[((size_t)(b * 256 + c0 + c)) * HW + p0 + pp];
  }
  __syncthreads();
  int cp = tid & 31, pp2 = tid >> 5;
#pragma unroll
  for (int it = 0; it < 8; ++it) {
    int p = it * 8 + pp2;
    __half2 h = __floats2half2_rn(tile[(2 * cp) * 65 + p], tile[(2 * cp + 1) * 65 + p]);
    xtu[(size_t)(b * 1024 + p0 + p) * 128 + cc * 32 + cp] = __builtin_bit_cast(uint, h);
  }
}

// ---------------- 3. offset conv via shifted-gather + f16 MFMA ---------------------
// block: (b, cs half of 128 cin, ptile of 128 pixels). K = 9 taps x 128 c. N=32 (27 used)
// opart[cs][b*1024+pix][32] fp32
__global__ __launch_bounds__(256) void offconv_mfma_kernel(const __half* __restrict__ xt,
                                                           const __half* __restrict__ boff,
                                                           float* __restrict__ opart) {
  __shared__ short As[128 * 132];
  __shared__ short Bs[32 * 132];
  int blk = blockIdx.x;
  int ptile = blk & 7, cs = (blk >> 3) & 1, b = blk >> 4;
  int tid = threadIdx.x;
  int wid = tid >> 6, lane = tid & 63, lr = lane & 15, quad = lane >> 4;
  int P0 = ptile * 128;
  int m_w = wid * 32;
  int srow = tid >> 1, shalf = tid & 1;
  int pix = P0 + srow; int h = pix >> 5, w = pix & 31;
  const __half* xb = xt + (size_t)(b * 1024) * 256 + cs * 128 + shalf * 64;
  int brow = tid >> 3, bseg = tid & 7;

  floatx4 acc[2][2];
#pragma unroll
  for (int mi = 0; mi < 2; ++mi)
#pragma unroll
    for (int ni = 0; ni < 2; ++ni) acc[mi][ni] = (floatx4)0.f;

  for (int tap = 0; tap < 9; ++tap) {
    int ty = tap / 3, tx = tap % 3;
    int yy = h + ty - 1, xx = w + tx - 1;
    bool valid = (yy >= 0) && (yy < 32) && (xx >= 0) && (xx < 32);
    int pos = min(max(yy, 0), 31) * 32 + min(max(xx, 0), 31);
    const float4* ga = (const float4*)(xb + (size_t)pos * 256);
    float4 a[8];
#pragma unroll
    for (int i = 0; i < 8; ++i) a[i] = ga[i];
    if (!valid) {
#pragma unroll
      for (int i = 0; i < 8; ++i) a[i] = make_float4(0.f, 0.f, 0.f, 0.f);
    }
    const float4* gb = (const float4*)(boff + ((size_t)(tap * 32 + brow)) * 256 + cs * 128 + bseg * 16);
    float4 b0 = gb[0], b1 = gb[1];
    if (tap) __syncthreads();
    float4* qa = (float4*)(As + srow * 132 + shalf * 64);
#pragma unroll
    for (int i = 0; i < 8; ++i) qa[i] = a[i];
    float4* qb = (float4*)(Bs + brow * 132 + bseg * 16);
    qb[0] = b0; qb[1] = b1;
    __syncthreads();
#pragma unroll
    for (int k2 = 0; k2 < 4; ++k2) {
      half8 af[2], bf[2];
#pragma unroll
      for (int mi = 0; mi < 2; ++mi)
        af[mi] = *(const half8*)(As + (m_w + mi * 16 + lr) * 132 + k2 * 32 + quad * 8);
#pragma unroll
      for (int ni = 0; ni < 2; ++ni)
        bf[ni] = *(const half8*)(Bs + (ni * 16 + lr) * 132 + k2 * 32 + quad * 8);
#pragma unroll
      for (int mi = 0; mi < 2; ++mi)
#pragma unroll
        for (int ni = 0; ni < 2; ++ni)
          acc[mi][ni] = __builtin_amdgcn_mfma_f32_16x16x32_f16(af[mi], bf[ni], acc[mi][ni], 0, 0, 0);
    }
  }
  float* op = opart + (size_t)cs * 524288 + ((size_t)(b * 1024 + P0)) * 32;
#pragma unroll
  for (int mi = 0; mi < 2; ++mi) {
#pragma unroll
    for (int r = 0; r < 4; ++r) {
      int m = m_w + mi * 16 + quad * 4 + r;
      float* orow = op + (size_t)m * 32;
#pragma unroll
      for (int ni = 0; ni < 2; ++ni)
        orow[ni * 16 + lr] = acc[mi][ni][r];
    }
  }
}

// ---------------- 4. reduce offsets + bias + sigmoid, [b][pix][32] -----------------
__global__ __launch_bounds__(256) void offreduce_kernel(const float* __restrict__ opart,
                                                        const float* __restrict__ b_off,
                                                        float* __restrict__ off) {
  int i4 = blockIdx.x * 256 + threadIdx.x;  // 131072 threads
  size_t i = (size_t)i4 * 4;
  float4 v0 = *(const float4*)(opart + i);
  float4 v1 = *(const float4*)(opart + 524288 + i);
  float r[4] = {v0.x + v1.x, v0.y + v1.y, v0.z + v1.z, v0.w + v1.w};
#pragma unroll
  for (int j = 0; j < 4; ++j) {
    int ch = (int)((i + j) & 31);
    float s = r[j] + (ch < 27 ? b_off[ch] : 0.f);
    if (ch >= 18 && ch < 27) s = 1.f / (1.f + __expf(-s));
    r[j] = s;
  }
  *(float4*)(off + i) = make_float4(r[0], r[1], r[2], r[3]);
}

// ---------------- 5. deformable conv via fused gather + f16 MFMA -------------------
__global__ __launch_bounds__(256) void deform_mfma_kernel(const __half* __restrict__ xt,
                                                          const float* __restrict__ off,
                                                          const __half* __restrict__ bd,
                                                          float* __restrict__ y_part) {
  __shared__ short As[128 * 72];
  __shared__ short Bs[128 * 72];
  int blk = blockIdx.x;
  int ptile = blk & 7, cs = (blk >> 3) & 3, b = blk >> 5;
  int tid = threadIdx.x;
  int wid = tid >> 6, lane = tid & 63, lr = lane & 15, quad = lane >> 4;
  int m_w = (wid & 1) * 64, n_w = (wid >> 1) * 64;
  int P0 = ptile * 128;
  int pix_l = tid >> 1, chalf = (tid & 1) * 32;
  int pix = P0 + pix_l;
  int h = pix >> 5, w = pix & 31;
  const float* offb = off + (size_t)(b * 1024 + pix) * 32;
  const __half* xb = xt + (size_t)b * 1024 * 256 + cs * 64 + chalf;
  int ocb = tid >> 1, seg = tid & 1;
  const __half* bdr = bd + (size_t)ocb * 2304 + cs * 64 + seg * 32;

  floatx4 acc[4][4];
#pragma unroll
  for (int mi = 0; mi < 4; ++mi)
#pragma unroll
    for (int ni = 0; ni < 4; ++ni) acc[mi][ni] = (floatx4)0.f;

  for (int tap = 0; tap < 9; ++tap) {
    float dy = offb[2 * tap];
    float dx = offb[2 * tap + 1];
    float mm = offb[18 + tap];
    float py = (float)(h + tap / 3 - 1) + dy;
    float px = (float)(w + tap % 3 - 1) + dx;
    float y0f = floorf(py), x0f = floorf(px);
    float wy = py - y0f, wx = px - x0f;
    int y0 = (int)y0f, x0 = (int)x0f;
    float cw[4] = {(1.f - wy) * (1.f - wx), (1.f - wy) * wx, wy * (1.f - wx), wy * wx};
    uint4 q[4][4];
    __half2 w2[4];
#pragma unroll
    for (int t = 0; t < 4; ++t) {
      int yy = y0 + (t >> 1), xx = x0 + (t & 1);
      bool v = (yy >= 0) && (yy <= 31) && (xx >= 0) && (xx <= 31);
      int yc = min(max(yy, 0), 31), xc = min(max(xx, 0), 31);
      const uint4* xr = (const uint4*)(xb + (size_t)(yc * 32 + xc) * 256);
      q[t][0] = xr[0]; q[t][1] = xr[1]; q[t][2] = xr[2]; q[t][3] = xr[3];
      w2[t] = __float2half2_rn(v ? cw[t] * mm : 0.f);
    }
    const float4* gb = (const float4*)(bdr + tap * 256);
    float4 b0 = gb[0], b1 = gb[1], b2 = gb[2], b3 = gb[3];

    __half2 hacc[16];
#pragma unroll
    for (int j = 0; j < 16; ++j) hacc[j] = __float2half2_rn(0.f);
#pragma unroll
    for (int t = 0; t < 4; ++t) {
      uint qa[16] = {q[t][0].x, q[t][0].y, q[t][0].z, q[t][0].w,
                     q[t][1].x, q[t][1].y, q[t][1].z, q[t][1].w,
                     q[t][2].x, q[t][2].y, q[t][2].z, q[t][2].w,
                     q[t][3].x, q[t][3].y, q[t][3].z, q[t][3].w};
#pragma unroll
      for (int j = 0; j < 16; ++j)
        hacc[j] = __hfma2(w2[t], __builtin_bit_cast(__half2, qa[j]), hacc[j]);
    }
    if (tap) __syncthreads();
#pragma unroll
    for (int g = 0; g < 4; ++g) {
      float4 f;
      f.x = __builtin_bit_cast(float, hacc[4 * g + 0]);
      f.y = __builtin_bit_cast(float, hacc[4 * g + 1]);
      f.z = __builtin_bit_cast(float, hacc[4 * g + 2]);
      f.w = __builtin_bit_cast(float, hacc[4 * g + 3]);
      *(float4*)(As + pix_l * 72 + chalf + g * 8) = f;
    }
    *(float4*)(Bs + ocb * 72 + seg * 32 + 0)  = b0;
    *(float4*)(Bs + ocb * 72 + seg * 32 + 8)  = b1;
    *(float4*)(Bs + ocb * 72 + seg * 32 + 16) = b2;
    *(float4*)(Bs + ocb * 72 + seg * 32 + 24) = b3;
    __syncthreads();
#pragma unroll
    for (int k2 = 0; k2 < 2; ++k2) {
      half8 af[4], bf[4];
#pragma unroll
      for (int mi = 0; mi < 4; ++mi)
        af[mi] = *(const half8*)(As + (m_w + mi * 16 + lr) * 72 + k2 * 32 + quad * 8);
#pragma unroll
      for (int ni = 0; ni < 4; ++ni)
        bf[ni] = *(const half8*)(Bs + (n_w + ni * 16 + lr) * 72 + k2 * 32 + quad * 8);
#pragma unroll
      for (int mi = 0; mi < 4; ++mi)
#pragma unroll
        for (int ni = 0; ni < 4; ++ni)
          acc[mi][ni] = __builtin_amdgcn_mfma_f32_16x16x32_f16(af[mi], bf[ni], acc[mi][ni], 0, 0, 0);
    }
  }
  float* yp = y_part + (size_t)cs * 2097152 + ((size_t)(b * 1024 + P0)) * 128;
#pragma unroll
  for (int mi = 0; mi < 4; ++mi) {
#pragma unroll
    for (int r = 0; r < 4; ++r) {
      int m = m_w + mi * 16 + quad * 4 + r;
      float* orow = yp + (size_t)m * 128;
#pragma unroll
      for (int ni = 0; ni < 4; ++ni)
        orow[n_w + ni * 16 + lr] = acc[mi][ni][r];
    }
  }
}

// ---------------- 6. BN1 stats partials over [pix][oc] -----------------------------
__global__ __launch_bounds__(256) void stats1_part_kernel(const float* __restrict__ P,
                                                          const float* __restrict__ b_dcn,
                                                          float* __restrict__ stp) {
  int blk = blockIdx.x; int tid = threadIdx.x;
  int oc = tid & 127, rh = tid >> 7;
  float bias = b_dcn[oc];
  float s = 0.f, sq = 0.f;
  for (int r = rh; r < 128; r += 2) {
    size_t idx = ((size_t)blk * 128 + r) * 128 + oc;
    float v = P[idx] + P[2097152 + idx] + P[4194304 + idx] + P[6291456 + idx] + bias;
    s += v; sq = fmaf(v, v, sq);
  }
  __shared__ float ls[256], lq[256];
  ls[tid] = s; lq[tid] = sq; __syncthreads();
  if (tid < 128) {
    stp[(size_t)blk * 128 + tid] = ls[tid] + ls[tid + 128];
    stp[16384 + (size_t)blk * 128 + tid] = lq[tid] + lq[tid + 128];
  }
}

__global__ __launch_bounds__(256) void stats1_final_kernel(const float* __restrict__ stp,
                                                           const float* __restrict__ g,
                                                           const float* __restrict__ bt,
                                                           float* __restrict__ st) {
  int tid = threadIdx.x;
  if (tid >= 128) return;
  float s = 0.f, sq = 0.f;
  for (int i = 0; i < 128; ++i) {
    s += stp[(size_t)i * 128 + tid];
    sq += stp[16384 + (size_t)i * 128 + tid];
  }
  float n = 16384.f;
  float mean = s / n;
  float var = sq / n - mean * mean;
  float sc = g[tid] * rsqrtf(var + EPSV);
  st[tid] = sc;
  st[128 + tid] = fmaf(-mean, sc, bt[tid]);
}

// ---------------- 7. ybn: reduce + bias + BN + ReLU -> bf16 [pix][c] ---------------
__global__ __launch_bounds__(256) void ybn_kernel(const float* __restrict__ P,
                                                  const float* __restrict__ b_dcn,
                                                  const float* __restrict__ st,
                                                  ushort* __restrict__ ybn) {
  int i4 = blockIdx.x * 256 + threadIdx.x;
  size_t i = (size_t)i4 * 4;
  int oc = (int)(i & 127);
  float4 v = *(const float4*)(P + i);
  float4 v1 = *(const float4*)(P + 2097152 + i);
  float4 v2 = *(const float4*)(P + 4194304 + i);
  float4 v3 = *(const float4*)(P + 6291456 + i);
  ushort r[4];
  float vv[4] = {v.x + v1.x + v2.x + v3.x, v.y + v1.y + v2.y + v3.y,
                 v.z + v1.z + v2.z + v3.z, v.w + v1.w + v2.w + v3.w};
#pragma unroll
  for (int j = 0; j < 4; ++j) {
    float t = vv[j] + b_dcn[oc + j];
    r[j] = f2bf(fmaxf(fmaf(t, st[oc + j], st[128 + oc + j]), 0.f));
  }
  uint2 pk;
  pk.x = (uint)r[0] | ((uint)r[1] << 16);
  pk.y = (uint)r[2] | ((uint)r[3] << 16);
  *(uint2*)(ybn + i) = pk;
}

// ---------------- 8. deconv as 4 parity GEMMs, bf16 MFMA ---------------------------
__global__ __launch_bounds__(256) void deconv_mfma_kernel(const ushort* __restrict__ ybn,
                                                          const ushort* __restrict__ bp,
                                                          float* __restrict__ O) {
  __shared__ ushort As[128 * 72];
  __shared__ ushort Bs[128 * 72];
  int blk = blockIdx.x;
  int ptile = blk & 7, par = (blk >> 3) & 3, b = blk >> 5;
  int pu = par >> 1, pv = par & 1;
  int tid = threadIdx.x;
  int wid = tid >> 6, lane = tid & 63, lr = lane & 15, quad = lane >> 4;
  int m_w = (wid & 1) * 64, n_w = (wid >> 1) * 64;
  int P0 = ptile * 128;
  int sm = tid >> 1, shalf = tid & 1;
  int pix = P0 + sm, uu = pix >> 5, vv = pix & 31;

  floatx4 acc[4][4];
#pragma unroll
  for (int mi = 0; mi < 4; ++mi)
#pragma unroll
    for (int ni = 0; ni < 4; ++ni) acc[mi][ni] = (floatx4)0.f;

  for (int kk = 0; kk < 8; ++kk) {
    int t = kk >> 1, chalf = (kk & 1) * 64;
    int ty = t >> 1, tx = t & 1;
    int i = uu + pu - ty, j = vv + pv - tx;
    bool valid = (i >= 0) && (i <= 31) && (j >= 0) && (j <= 31);
    int pos = min(max(i, 0), 31) * 32 + min(max(j, 0), 31);
    const float4* ga = (const float4*)(ybn + ((size_t)(b * 1024 + pos) * 128 + chalf + shalf * 32));
    const float4* gb = (const float4*)(bp + ((size_t)(par * 128 + sm) * 512 + kk * 64 + shalf * 32));
    float4 a0 = ga[0], a1 = ga[1], a2 = ga[2], a3 = ga[3];
    float4 b0 = gb[0], b1 = gb[1], b2 = gb[2], b3 = gb[3];
    if (!valid) { a0 = a1 = a2 = a3 = make_float4(0.f, 0.f, 0.f, 0.f); }
    if (kk) __syncthreads();
    float4* qa = (float4*)(As + sm * 72 + shalf * 32);
    qa[0] = a0; qa[1] = a1; qa[2] = a2; qa[3] = a3;
    float4* qb = (float4*)(Bs + sm * 72 + shalf * 32);
    qb[0] = b0; qb[1] = b1; qb[2] = b2; qb[3] = b3;
    __syncthreads();
#pragma unroll
    for (int k2 = 0; k2 < 64; k2 += 32) {
      short8 af[4], bfr[4];
#pragma unroll
      for (int mi = 0; mi < 4; ++mi)
        af[mi] = *(const short8*)(As + (m_w + mi * 16 + lr) * 72 + k2 + quad * 8);
#pragma unroll
      for (int ni = 0; ni < 4; ++ni)
        bfr[ni] = *(const short8*)(Bs + (n_w + ni * 16 + lr) * 72 + k2 + quad * 8);
#pragma unroll
      for (int mi = 0; mi < 4; ++mi)
#pragma unroll
        for (int ni = 0; ni < 4; ++ni)
          acc[mi][ni] = __builtin_amdgcn_mfma_f32_16x16x32_bf16(af[mi], bfr[ni], acc[mi][ni], 0, 0, 0);
    }
  }
  size_t obase = (size_t)(b * 4 + par) * 1024 * 128;
#pragma unroll
  for (int mi = 0; mi < 4; ++mi) {
#pragma unroll
    for (int r = 0; r < 4; ++r) {
      int m = m_w + mi * 16 + quad * 4 + r;
      float* orow = O + obase + (size_t)(P0 + m) * 128;
#pragma unroll
      for (int ni = 0; ni < 4; ++ni)
        orow[n_w + ni * 16 + lr] = acc[mi][ni][r];
    }
  }
}

// ---------------- 9. BN2 stats ----------------------------------------------------
__global__ __launch_bounds__(256) void stats2_part_kernel(const float* __restrict__ O,
                                                          float* __restrict__ stp) {
  int blk = blockIdx.x; int tid = threadIdx.x;
  int oc = tid & 127, rh = tid >> 7;
  size_t base = (size_t)blk * 128 * 128;
  float s = 0.f, sq = 0.f;
  for (int r = rh; r < 128; r += 2) {
    float v = O[base + (size_t)r * 128 + oc];
    s += v; sq = fmaf(v, v, sq);
  }
  __shared__ float ls[256], lq[256];
  ls[tid] = s; lq[tid] = sq; __syncthreads();
  if (tid < 128) {
    stp[(size_t)blk * 128 + tid] = ls[tid] + ls[tid + 128];
    stp[65536 + (size_t)blk * 128 + tid] = lq[tid] + lq[tid + 128];
  }
}

__global__ __launch_bounds__(256) void stats2_final_kernel(const float* __restrict__ stp,
                                                           const float* __restrict__ g,
                                                           const float* __restrict__ bt,
                                                           float* __restrict__ st) {
  int tid = threadIdx.x;
  if (tid >= 128) return;
  float s = 0.f, sq = 0.f;
  for (int i = 0; i < 512; ++i) {
    s += stp[(size_t)i * 128 + tid];
    sq += stp[65536 + (size_t)i * 128 + tid];
  }
  float n = 65536.f;
  float mean = s / n;
  float var = sq / n - mean * mean;
  float sc = g[tid] * rsqrtf(var + EPSV);
  st[tid] = sc;
  st[128 + tid] = fmaf(-mean, sc, bt[tid]);
}

// ---------------- 10. BN2+ReLU + transpose to NCHW out -----------------------------
__global__ __launch_bounds__(256) void bnout_kernel(const float* __restrict__ O,
                                                    const float* __restrict__ st,
                                                    float* __restrict__ out) {
  __shared__ float tile[128 * 33];
  int blk = blockIdx.x;
  int uu = blk & 31, par = (blk >> 5) & 3, b = blk >> 7;
  int pu = par >> 1, pv = par & 1;
  int tid = threadIdx.x;
#pragma unroll 4
  for (int it = 0; it < 16; ++it) {
    int idx = it * 256 + tid;
    int vv = idx >> 7, oc = idx & 127;
    float v = O[((size_t)(b * 4 + par) * 1024 + uu * 32 + vv) * 128 + oc];
    tile[oc * 33 + vv] = fmaxf(fmaf(v, st[oc], st[128 + oc]), 0.f);
  }
  __syncthreads();
#pragma unroll 4
  for (int it = 0; it < 16; ++it) {
    int idx = it * 256 + tid;
    int oc = idx >> 5, vv = idx & 31;
    out[((size_t)b * 128 + oc) * 4096 + (2 * uu + pu) * 64 + 2 * vv + pv] = tile[oc * 33 + vv];
  }
}

extern "C" void kernel_launch(void* const* d_in, const int* in_sizes, int n_in,
                              void* d_out, int out_size, void* d_ws, size_t ws_size,
                              hipStream_t stream) {
  const float* x     = (const float*)d_in[0];
  const float* w_off = (const float*)d_in[1];
  const float* b_off = (const float*)d_in[2];
  const float* w_dcn = (const float*)d_in[3];
  const float* b_dcn = (const float*)d_in[4];
  const float* g1    = (const float*)d_in[5];
  const float* bt1   = (const float*)d_in[6];
  const float* w_up  = (const float*)d_in[7];
  const float* g2    = (const float*)d_in[8];
  const float* bt2   = (const float*)d_in[9];
  float* ws  = (float*)d_ws;
  float* out = (float*)d_out;

  prep_kernel<<<2464, 256, 0, stream>>>(w_off, w_dcn, w_up, ws);
  xt_kernel<<<1024, 256, 0, stream>>>(x, (uint*)(ws + XT));
  offconv_mfma_kernel<<<256, 256, 0, stream>>>((const __half*)(ws + XT),
                                               (const __half*)(ws + BOFF), ws + BIG);
  offreduce_kernel<<<512, 256, 0, stream>>>(ws + BIG, b_off, ws + OFFB);
  deform_mfma_kernel<<<512, 256, 0, stream>>>((const __half*)(ws + XT), ws + OFFB,
                                              (const __half*)(ws + BD), ws + BIG);
  stats1_part_kernel<<<128, 256, 0, stream>>>(ws + BIG, b_dcn, ws + STP);
  stats1_final_kernel<<<1, 256, 0, stream>>>(ws + STP, g1, bt1, ws + ST1);
  ybn_kernel<<<2048, 256, 0, stream>>>(ws + BIG, b_dcn, ws + ST1, (ushort*)(ws + XT));
  deconv_mfma_kernel<<<512, 256, 0, stream>>>((const ushort*)(ws + XT),
                                              (const ushort*)(ws + BP), ws + BIG);
  stats2_part_kernel<<<512, 256, 0, stream>>>(ws + BIG, ws + STP);
  stats2_final_kernel<<<1, 256, 0, stream>>>(ws + STP, g2, bt2, ws + ST2);
  bnout_kernel<<<2048, 256, 0, stream>>>(ws + BIG, ws + ST2, out);
}

// Round 5
// 221.125 us; speedup vs baseline: 3.8429x; 1.1308x over previous
//
#include <hip/hip_runtime.h>
#include <hip/hip_fp16.h>
#include <math.h>

#define HW 1024
#define EPSV 1e-5f

typedef unsigned int uint;
typedef unsigned short ushort;
typedef __attribute__((ext_vector_type(8))) short short8;
typedef __attribute__((ext_vector_type(8))) _Float16 half8;
typedef __attribute__((ext_vector_type(4))) float floatx4;

// ---------------- ws layout (float offsets), no aliasing (ws is 268 MB) ------------
static const size_t BOFF = 0;         // 36864   fp16 Boff[tap][n32][c256]
static const size_t BD   = 36864;     // 147456  fp16 Bd[oc][tap*256+c]
static const size_t BP   = 184320;    // 131072  bf16 Bp[par][oc][k]
static const size_t XT   = 315392;    // 2097152 fp16 xT[b][p][c]
static const size_t OFFB = 2412544;   // 524288  off [b][pix][32] fp32
static const size_t ST1  = 2936832;   // 256 BN1 sum/sq accumulators (atomic)
static const size_t ST2  = 2937088;   // 256 BN2 sum/sq accumulators (atomic)
static const size_t YP   = 2937344;   // 8388608 y_part[4][pix][oc]
static const size_t YSUM = 11325952;  // 2097152 ysum[pix][oc] fp32 (bias applied)
static const size_t OB   = 13423104;  // 8388608 O[b][par][pix][oc] fp32
// total = 21811712 floats = 87.2 MB (ws fill shows 268 MB available)

__device__ inline ushort f2bf(float f) {
  uint u = __builtin_bit_cast(uint, f);
  uint r = (u + 0x7FFFu + ((u >> 16) & 1u)) >> 16;
  return (ushort)r;
}

// ---------------- 1. prep + xT + zero accumulators ---------------------------------
__global__ __launch_bounds__(256) void prep_xt_kernel(const float* __restrict__ x,
                                                      const float* __restrict__ w_off,
                                                      const float* __restrict__ w_dcn,
                                                      const float* __restrict__ w_up,
                                                      float* __restrict__ ws) {
  __shared__ float tile[64 * 65];
  int blk = blockIdx.x;
  int tid = threadIdx.x;
  if (blk < 1024) {
    // xT: x[b][c][p] fp32 -> xT[b][p][c] fp16
    int b = blk >> 6, pt = (blk >> 2) & 15, cc = blk & 3;
    int p0 = pt * 64, c0 = cc * 64;
    int pp = tid & 63, ci = tid >> 6;
#pragma unroll
    for (int it = 0; it < 16; ++it) {
      int c = it * 4 + ci;
      tile[c * 65 + pp] = x[((size_t)(b * 256 + c0 + c)) * HW + p0 + pp];
    }
    __syncthreads();
    int cp = tid & 31, pp2 = tid >> 5;
    uint* xtu = (uint*)(ws + XT);
#pragma unroll
    for (int it = 0; it < 8; ++it) {
      int p = it * 8 + pp2;
      __half2 h = __floats2half2_rn(tile[(2 * cp) * 65 + p], tile[(2 * cp + 1) * 65 + p]);
      xtu[(size_t)(b * 1024 + p0 + p) * 128 + cc * 32 + cp] = __builtin_bit_cast(uint, h);
    }
  } else if (blk < 3488) {
    int i = (blk - 1024) * 256 + tid;
    if (i < 73728) {
      // Boff[tap][n][c], zero-padded n>=27
      int c = i & 255; int n = (i >> 8) & 31; int tap = i >> 13;
      float v = (n < 27) ? w_off[((size_t)n * 256 + c) * 9 + tap] : 0.f;
      ((__half*)(ws + BOFF))[i] = __float2half(v);
    } else if (i < 73728 + 294912) {
      int d = i - 73728;            // d = oc*2304 + tap*256 + c
      int oc = d / 2304; int k = d % 2304;
      int tap = k >> 8; int c = k & 255;
      ((__half*)(ws + BD))[d] = __float2half(w_dcn[((size_t)oc * 256 + c) * 9 + tap]);
    } else if (i < 73728 + 294912 + 262144) {
      int d = i - (73728 + 294912);
      int par = d >> 16; int rem = d & 65535;
      int o = rem >> 9; int k = rem & 511;
      int t4 = k >> 7; int c = k & 127;
      int ty = t4 >> 1, tx = t4 & 1;
      int pu = par >> 1, pv = par & 1;
      int ky = (1 - pu) + 2 * ty, kx = (1 - pv) + 2 * tx;
      float v = w_up[((size_t)c * 128 + o) * 16 + ky * 4 + kx];
      ((ushort*)(ws + BP))[d] = f2bf(v);
    }
  } else {
    if (tid < 512) ws[ST1 + tid] = 0.f;  // ST1(256)+ST2(256) contiguous
  }
}

// ---------------- 2. offset conv full-K + bias + sigmoid ---------------------------
// 512 blocks: b(16) x 32-pixel tile(32). M=32, N=32, K=2304 (18 stages of tap x chalf)
__global__ __launch_bounds__(256) void offconv_mfma_kernel(const __half* __restrict__ xt,
                                                           const __half* __restrict__ boff,
                                                           const float* __restrict__ b_off,
                                                           float* __restrict__ off) {
  __shared__ short As[32 * 132];
  __shared__ short Bs[32 * 132];
  int blk = blockIdx.x;
  int pt = blk & 31, b = blk >> 5;
  int P0 = pt * 32;
  int tid = threadIdx.x;
  int wid = tid >> 6, lane = tid & 63, lr = lane & 15, quad = lane >> 4;
  int m_w = (wid & 1) * 16, n_w = (wid >> 1) * 16;
  int arow = tid >> 3, aseg = tid & 7;  // 32 rows x 16 halves
  int pix = P0 + arow; int h = pix >> 5, w = pix & 31;

  floatx4 acc = (floatx4)0.f;

  for (int s = 0; s < 18; ++s) {
    int tap = s >> 1, ch = (s & 1) * 128;
    int ty = tap / 3, tx = tap % 3;
    int yy = h + ty - 1, xx = w + tx - 1;
    bool valid = (yy >= 0) && (yy < 32) && (xx >= 0) && (xx < 32);
    int pos = min(max(yy, 0), 31) * 32 + min(max(xx, 0), 31);
    const float4* ga = (const float4*)(xt + ((size_t)(b * 1024 + pos)) * 256 + ch + aseg * 16);
    float4 a0 = ga[0], a1 = ga[1];
    if (!valid) { a0 = make_float4(0.f, 0.f, 0.f, 0.f); a1 = a0; }
    const float4* gb = (const float4*)(boff + ((size_t)(tap * 32 + arow)) * 256 + ch + aseg * 16);
    float4 b0 = gb[0], b1 = gb[1];
    if (s) __syncthreads();
    float4* qa = (float4*)(As + arow * 132 + aseg * 16);
    qa[0] = a0; qa[1] = a1;
    float4* qb = (float4*)(Bs + arow * 132 + aseg * 16);
    qb[0] = b0; qb[1] = b1;
    __syncthreads();
#pragma unroll
    for (int k2 = 0; k2 < 4; ++k2) {
      half8 af = *(const half8*)(As + (m_w + lr) * 132 + k2 * 32 + quad * 8);
      half8 bf = *(const half8*)(Bs + (n_w + lr) * 132 + k2 * 32 + quad * 8);
      acc = __builtin_amdgcn_mfma_f32_16x16x32_f16(af, bf, acc, 0, 0, 0);
    }
  }
  int n = n_w + lr;
  float bias = (n < 27) ? b_off[n] : 0.f;
  bool sig = (n >= 18) && (n < 27);
#pragma unroll
  for (int r = 0; r < 4; ++r) {
    int m = m_w + quad * 4 + r;
    float v = acc[r] + bias;
    if (sig) v = 1.f / (1.f + __expf(-v));
    off[((size_t)(b * 1024 + P0 + m)) * 32 + n] = v;
  }
}

// ---------------- 3. deformable conv via fused gather + f16 MFMA -------------------
__global__ __launch_bounds__(256) void deform_mfma_kernel(const __half* __restrict__ xt,
                                                          const float* __restrict__ off,
                                                          const __half* __restrict__ bd,
                                                          float* __restrict__ y_part) {
  __shared__ short As[128 * 72];
  __shared__ short Bs[128 * 72];
  int blk = blockIdx.x;
  int ptile = blk & 7, cs = (blk >> 3) & 3, b = blk >> 5;
  int tid = threadIdx.x;
  int wid = tid >> 6, lane = tid & 63, lr = lane & 15, quad = lane >> 4;
  int m_w = (wid & 1) * 64, n_w = (wid >> 1) * 64;
  int P0 = ptile * 128;
  int pix_l = tid >> 1, chalf = (tid & 1) * 32;
  int pix = P0 + pix_l;
  int h = pix >> 5, w = pix & 31;
  const float* offb = off + (size_t)(b * 1024 + pix) * 32;
  const __half* xb = xt + (size_t)b * 1024 * 256 + cs * 64 + chalf;
  int ocb = tid >> 1, seg = tid & 1;
  const __half* bdr = bd + (size_t)ocb * 2304 + cs * 64 + seg * 32;

  floatx4 acc[4][4];
#pragma unroll
  for (int mi = 0; mi < 4; ++mi)
#pragma unroll
    for (int ni = 0; ni < 4; ++ni) acc[mi][ni] = (floatx4)0.f;

  for (int tap = 0; tap < 9; ++tap) {
    float dy = offb[2 * tap];
    float dx = offb[2 * tap + 1];
    float mm = offb[18 + tap];
    float py = (float)(h + tap / 3 - 1) + dy;
    float px = (float)(w + tap % 3 - 1) + dx;
    float y0f = floorf(py), x0f = floorf(px);
    float wy = py - y0f, wx = px - x0f;
    int y0 = (int)y0f, x0 = (int)x0f;
    float cw[4] = {(1.f - wy) * (1.f - wx), (1.f - wy) * wx, wy * (1.f - wx), wy * wx};
    uint4 q[4][4];
    __half2 w2[4];
#pragma unroll
    for (int t = 0; t < 4; ++t) {
      int yy = y0 + (t >> 1), xx = x0 + (t & 1);
      bool v = (yy >= 0) && (yy <= 31) && (xx >= 0) && (xx <= 31);
      int yc = min(max(yy, 0), 31), xc = min(max(xx, 0), 31);
      const uint4* xr = (const uint4*)(xb + (size_t)(yc * 32 + xc) * 256);
      q[t][0] = xr[0]; q[t][1] = xr[1]; q[t][2] = xr[2]; q[t][3] = xr[3];
      w2[t] = __float2half2_rn(v ? cw[t] * mm : 0.f);
    }
    const float4* gb = (const float4*)(bdr + tap * 256);
    float4 b0 = gb[0], b1 = gb[1], b2 = gb[2], b3 = gb[3];

    __half2 hacc[16];
#pragma unroll
    for (int j = 0; j < 16; ++j) hacc[j] = __float2half2_rn(0.f);
#pragma unroll
    for (int t = 0; t < 4; ++t) {
      uint qa[16] = {q[t][0].x, q[t][0].y, q[t][0].z, q[t][0].w,
                     q[t][1].x, q[t][1].y, q[t][1].z, q[t][1].w,
                     q[t][2].x, q[t][2].y, q[t][2].z, q[t][2].w,
                     q[t][3].x, q[t][3].y, q[t][3].z, q[t][3].w};
#pragma unroll
      for (int j = 0; j < 16; ++j)
        hacc[j] = __hfma2(w2[t], __builtin_bit_cast(__half2, qa[j]), hacc[j]);
    }
    if (tap) __syncthreads();
#pragma unroll
    for (int g = 0; g < 4; ++g) {
      float4 f;
      f.x = __builtin_bit_cast(float, hacc[4 * g + 0]);
      f.y = __builtin_bit_cast(float, hacc[4 * g + 1]);
      f.z = __builtin_bit_cast(float, hacc[4 * g + 2]);
      f.w = __builtin_bit_cast(float, hacc[4 * g + 3]);
      *(float4*)(As + pix_l * 72 + chalf + g * 8) = f;
    }
    *(float4*)(Bs + ocb * 72 + seg * 32 + 0)  = b0;
    *(float4*)(Bs + ocb * 72 + seg * 32 + 8)  = b1;
    *(float4*)(Bs + ocb * 72 + seg * 32 + 16) = b2;
    *(float4*)(Bs + ocb * 72 + seg * 32 + 24) = b3;
    __syncthreads();
#pragma unroll
    for (int k2 = 0; k2 < 2; ++k2) {
      half8 af[4], bf[4];
#pragma unroll
      for (int mi = 0; mi < 4; ++mi)
        af[mi] = *(const half8*)(As + (m_w + mi * 16 + lr) * 72 + k2 * 32 + quad * 8);
#pragma unroll
      for (int ni = 0; ni < 4; ++ni)
        bf[ni] = *(const half8*)(Bs + (n_w + ni * 16 + lr) * 72 + k2 * 32 + quad * 8);
#pragma unroll
      for (int mi = 0; mi < 4; ++mi)
#pragma unroll
        for (int ni = 0; ni < 4; ++ni)
          acc[mi][ni] = __builtin_amdgcn_mfma_f32_16x16x32_f16(af[mi], bf[ni], acc[mi][ni], 0, 0, 0);
    }
  }
  float* yp = y_part + (size_t)cs * 2097152 + ((size_t)(b * 1024 + P0)) * 128;
#pragma unroll
  for (int mi = 0; mi < 4; ++mi) {
#pragma unroll
    for (int r = 0; r < 4; ++r) {
      int m = m_w + mi * 16 + quad * 4 + r;
      float* orow = yp + (size_t)m * 128;
#pragma unroll
      for (int ni = 0; ni < 4; ++ni)
        orow[n_w + ni * 16 + lr] = acc[mi][ni][r];
    }
  }
}

// ---------------- 4. yred: 4-partial sum + bias -> ysum; BN1 sum/sq atomics --------
__global__ __launch_bounds__(256) void yred_kernel(const float* __restrict__ yp,
                                                   const float* __restrict__ b_dcn,
                                                   float* __restrict__ ysum,
                                                   float* __restrict__ st1) {
  int blk = blockIdx.x; int tid = threadIdx.x;
  int oc = tid & 127, rh = tid >> 7;
  float bias = b_dcn[oc];
  float s = 0.f, sq = 0.f;
  for (int r = rh; r < 128; r += 2) {
    size_t idx = ((size_t)(blk * 128 + r)) * 128 + oc;
    float v = yp[idx] + yp[2097152 + idx] + yp[4194304 + idx] + yp[6291456 + idx] + bias;
    ysum[idx] = v;
    s += v; sq = fmaf(v, v, sq);
  }
  __shared__ float ls[256], lq[256];
  ls[tid] = s; lq[tid] = sq; __syncthreads();
  if (tid < 128) {
    atomicAdd(&st1[tid], ls[tid] + ls[tid + 128]);
    atomicAdd(&st1[128 + tid], lq[tid] + lq[tid + 128]);
  }
}

// ---------------- 5. deconv: BN1+ReLU inline, 4 parity GEMMs, BN2 stats atomics ----
__global__ __launch_bounds__(256) void deconv_mfma_kernel(const float* __restrict__ ysum,
                                                          const float* __restrict__ st1,
                                                          const float* __restrict__ g1,
                                                          const float* __restrict__ bt1,
                                                          const ushort* __restrict__ bp,
                                                          float* __restrict__ O,
                                                          float* __restrict__ st2) {
  __shared__ ushort As[128 * 72];
  __shared__ ushort Bs[128 * 72];
  __shared__ float scs[128], shs[128];
  int blk = blockIdx.x;
  int ptile = blk & 7, par = (blk >> 3) & 3, b = blk >> 5;
  int pu = par >> 1, pv = par & 1;
  int tid = threadIdx.x;
  int wid = tid >> 6, lane = tid & 63, lr = lane & 15, quad = lane >> 4;
  int m_w = (wid & 1) * 64, n_w = (wid >> 1) * 64;
  int P0 = ptile * 128;
  int sm = tid >> 1, shalf = tid & 1;
  int pix = P0 + sm, uu = pix >> 5, vv = pix & 31;

  if (tid < 128) {
    float s = st1[tid], sq = st1[128 + tid];
    float mean = s / 16384.f;
    float var = sq / 16384.f - mean * mean;
    float sc = g1[tid] * rsqrtf(var + EPSV);
    scs[tid] = sc;
    shs[tid] = fmaf(-mean, sc, bt1[tid]);
  }
  __syncthreads();

  floatx4 acc[4][4];
#pragma unroll
  for (int mi = 0; mi < 4; ++mi)
#pragma unroll
    for (int ni = 0; ni < 4; ++ni) acc[mi][ni] = (floatx4)0.f;

  for (int kk = 0; kk < 8; ++kk) {
    int t = kk >> 1, chalf = (kk & 1) * 64;
    int ty = t >> 1, tx = t & 1;
    int i = uu + pu - ty, j = vv + pv - tx;
    bool valid = (i >= 0) && (i <= 31) && (j >= 0) && (j <= 31);
    int pos = min(max(i, 0), 31) * 32 + min(max(j, 0), 31);
    int c0 = chalf + shalf * 32;
    const float4* ga = (const float4*)(ysum + ((size_t)(b * 1024 + pos)) * 128 + c0);
    float4 fq[8];
#pragma unroll
    for (int i2 = 0; i2 < 8; ++i2) fq[i2] = ga[i2];
    const float4* gb = (const float4*)(bp + ((size_t)(par * 128 + sm) * 512 + kk * 64 + shalf * 32));
    float4 b0 = gb[0], b1 = gb[1], b2 = gb[2], b3 = gb[3];
    // BN1+ReLU+bf16 pack (round-half-up via +0x8000, v_perm packs 2 per op)
    const float* fv = (const float*)fq;
    uint pk[16];
#pragma unroll
    for (int j2 = 0; j2 < 16; ++j2) {
      float v0 = fmaxf(fmaf(fv[2 * j2],     scs[c0 + 2 * j2],     shs[c0 + 2 * j2]), 0.f);
      float v1 = fmaxf(fmaf(fv[2 * j2 + 1], scs[c0 + 2 * j2 + 1], shs[c0 + 2 * j2 + 1]), 0.f);
      uint u0 = __builtin_bit_cast(uint, v0) + 0x8000u;
      uint u1 = __builtin_bit_cast(uint, v1) + 0x8000u;
      pk[j2] = __builtin_amdgcn_perm(u1, u0, 0x07060302u);
    }
    if (!valid) {
#pragma unroll
      for (int j2 = 0; j2 < 16; ++j2) pk[j2] = 0u;
    }
    if (kk) __syncthreads();
    uint4* qa = (uint4*)(As + sm * 72 + shalf * 32);
    qa[0] = make_uint4(pk[0], pk[1], pk[2], pk[3]);
    qa[1] = make_uint4(pk[4], pk[5], pk[6], pk[7]);
    qa[2] = make_uint4(pk[8], pk[9], pk[10], pk[11]);
    qa[3] = make_uint4(pk[12], pk[13], pk[14], pk[15]);
    float4* qb = (float4*)(Bs + sm * 72 + shalf * 32);
    qb[0] = b0; qb[1] = b1; qb[2] = b2; qb[3] = b3;
    __syncthreads();
#pragma unroll
    for (int k2 = 0; k2 < 64; k2 += 32) {
      short8 af[4], bfr[4];
#pragma unroll
      for (int mi = 0; mi < 4; ++mi)
        af[mi] = *(const short8*)(As + (m_w + mi * 16 + lr) * 72 + k2 + quad * 8);
#pragma unroll
      for (int ni = 0; ni < 4; ++ni)
        bfr[ni] = *(const short8*)(Bs + (n_w + ni * 16 + lr) * 72 + k2 + quad * 8);
#pragma unroll
      for (int mi = 0; mi < 4; ++mi)
#pragma unroll
        for (int ni = 0; ni < 4; ++ni)
          acc[mi][ni] = __builtin_amdgcn_mfma_f32_16x16x32_bf16(af[mi], bfr[ni], acc[mi][ni], 0, 0, 0);
    }
  }
  size_t obase = (size_t)(b * 4 + par) * 1024 * 128;
#pragma unroll
  for (int mi = 0; mi < 4; ++mi) {
#pragma unroll
    for (int r = 0; r < 4; ++r) {
      int m = m_w + mi * 16 + quad * 4 + r;
      float* orow = O + obase + (size_t)(P0 + m) * 128;
#pragma unroll
      for (int ni = 0; ni < 4; ++ni)
        orow[n_w + ni * 16 + lr] = acc[mi][ni][r];
    }
  }
  // BN2 stats: per-oc sum/sq over this block's 128 pixels, quad-reduced, atomics
  float sn[4], qn[4];
#pragma unroll
  for (int ni = 0; ni < 4; ++ni) {
    float s = 0.f, q = 0.f;
#pragma unroll
    for (int mi = 0; mi < 4; ++mi)
#pragma unroll
      for (int r = 0; r < 4; ++r) {
        float v = acc[mi][ni][r];
        s += v; q = fmaf(v, v, q);
      }
    sn[ni] = s; qn[ni] = q;
  }
#pragma unroll
  for (int ni = 0; ni < 4; ++ni) {
    sn[ni] += __shfl_xor(sn[ni], 16);
    sn[ni] += __shfl_xor(sn[ni], 32);
    qn[ni] += __shfl_xor(qn[ni], 16);
    qn[ni] += __shfl_xor(qn[ni], 32);
  }
  if (lane < 16) {
#pragma unroll
    for (int ni = 0; ni < 4; ++ni) {
      atomicAdd(&st2[n_w + ni * 16 + lr], sn[ni]);
      atomicAdd(&st2[128 + n_w + ni * 16 + lr], qn[ni]);
    }
  }
}

// ---------------- 6. bnout: BN2 scale/shift inline + transpose to NCHW -------------
__global__ __launch_bounds__(256) void bnout_kernel(const float* __restrict__ O,
                                                    const float* __restrict__ st2,
                                                    const float* __restrict__ g2,
                                                    const float* __restrict__ bt2,
                                                    float* __restrict__ out) {
  __shared__ float tile[128 * 33];
  __shared__ float scs[128], shs[128];
  int blk = blockIdx.x;
  int uu = blk & 31, par = (blk >> 5) & 3, b = blk >> 7;
  int pu = par >> 1, pv = par & 1;
  int tid = threadIdx.x;
  if (tid < 128) {
    float s = st2[tid], sq = st2[128 + tid];
    float mean = s / 65536.f;
    float var = sq / 65536.f - mean * mean;
    float sc = g2[tid] * rsqrtf(var + EPSV);
    scs[tid] = sc;
    shs[tid] = fmaf(-mean, sc, bt2[tid]);
  }
  __syncthreads();
#pragma unroll 4
  for (int it = 0; it < 16; ++it) {
    int idx = it * 256 + tid;
    int vv = idx >> 7, oc = idx & 127;
    float v = O[((size_t)(b * 4 + par) * 1024 + uu * 32 + vv) * 128 + oc];
    tile[oc * 33 + vv] = fmaxf(fmaf(v, scs[oc], shs[oc]), 0.f);
  }
  __syncthreads();
#pragma unroll 4
  for (int it = 0; it < 16; ++it) {
    int idx = it * 256 + tid;
    int oc = idx >> 5, vv = idx & 31;
    out[((size_t)b * 128 + oc) * 4096 + (2 * uu + pu) * 64 + 2 * vv + pv] = tile[oc * 33 + vv];
  }
}

extern "C" void kernel_launch(void* const* d_in, const int* in_sizes, int n_in,
                              void* d_out, int out_size, void* d_ws, size_t ws_size,
                              hipStream_t stream) {
  const float* x     = (const float*)d_in[0];
  const float* w_off = (const float*)d_in[1];
  const float* b_off = (const float*)d_in[2];
  const float* w_dcn = (const float*)d_in[3];
  const float* b_dcn = (const float*)d_in[4];
  const float* g1    = (const float*)d_in[5];
  const float* bt1   = (const float*)d_in[6];
  const float* w_up  = (const float*)d_in[7];
  const float* g2    = (const float*)d_in[8];
  const float* bt2   = (const float*)d_in[9];
  float* ws  = (float*)d_ws;
  float* out = (float*)d_out;

  prep_xt_kernel<<<3489, 256, 0, stream>>>(x, w_off, w_dcn, w_up, ws);
  offconv_mfma_kernel<<<512, 256, 0, stream>>>((const __half*)(ws + XT),
                                               (const __half*)(ws + BOFF), b_off, ws + OFFB);
  deform_mfma_kernel<<<512, 256, 0, stream>>>((const __half*)(ws + XT), ws + OFFB,
                                              (const __half*)(ws + BD), ws + YP);
  yred_kernel<<<128, 256, 0, stream>>>(ws + YP, b_dcn, ws + YSUM, ws + ST1);
  deconv_mfma_kernel<<<512, 256, 0, stream>>>(ws + YSUM, ws + ST1, g1, bt1,
                                              (const ushort*)(ws + BP), ws + OB, ws + ST2);
  bnout_kernel<<<2048, 256, 0, stream>>>(ws + OB, ws + ST2, g2, bt2, out);
}

// Round 6
// 217.295 us; speedup vs baseline: 3.9106x; 1.0176x over previous
//
#include <hip/hip_runtime.h>
#include <hip/hip_fp16.h>
#include <math.h>

#define HW 1024
#define EPSV 1e-5f

typedef unsigned int uint;
typedef unsigned short ushort;
typedef __attribute__((ext_vector_type(8))) short short8;
typedef __attribute__((ext_vector_type(8))) _Float16 half8;
typedef __attribute__((ext_vector_type(4))) float floatx4;

// ---------------- ws layout (float offsets), no aliasing ---------------------------
static const size_t BOFF = 0;         // 36864   fp16 Boff[tap][n32][c256]
static const size_t BD   = 36864;     // 147456  fp16 Bd[oc][tap*256+c]
static const size_t BP   = 184320;    // 131072  bf16 Bp[par][oc][k]
static const size_t XT   = 315392;    // 2097152 fp16 xT[b][p][c]
static const size_t OFFB = 2412544;   // 524288  off [b][pix][32] fp32
static const size_t ST1  = 2936832;   // 1024: BN1 sum/sq, 4 striped copies of 256
static const size_t ST2  = 2937856;   // 2048: BN2 sum/sq, 8 striped copies of 256
static const size_t YP   = 2939904;   // 8388608 y_part[4][pix][oc]
static const size_t YSUM = 11328512;  // 2097152 ysum[pix][oc] fp32 (bias applied)
static const size_t OB   = 13425664;  // 8388608 O[b][par][pix][oc] fp32
// total = 21814272 floats = 87.3 MB

__device__ inline ushort f2bf(float f) {
  uint u = __builtin_bit_cast(uint, f);
  uint r = (u + 0x7FFFu + ((u >> 16) & 1u)) >> 16;
  return (ushort)r;
}

// ---------------- 1. prep + xT + zero striped accumulators -------------------------
__global__ __launch_bounds__(256) void prep_xt_kernel(const float* __restrict__ x,
                                                      const float* __restrict__ w_off,
                                                      const float* __restrict__ w_dcn,
                                                      const float* __restrict__ w_up,
                                                      float* __restrict__ ws) {
  __shared__ float tile[64 * 65];
  int blk = blockIdx.x;
  int tid = threadIdx.x;
  if (blk < 1024) {
    // xT: x[b][c][p] fp32 -> xT[b][p][c] fp16
    int b = blk >> 6, pt = (blk >> 2) & 15, cc = blk & 3;
    int p0 = pt * 64, c0 = cc * 64;
    int pp = tid & 63, ci = tid >> 6;
#pragma unroll
    for (int it = 0; it < 16; ++it) {
      int c = it * 4 + ci;
      tile[c * 65 + pp] = x[((size_t)(b * 256 + c0 + c)) * HW + p0 + pp];
    }
    __syncthreads();
    int cp = tid & 31, pp2 = tid >> 5;
    uint* xtu = (uint*)(ws + XT);
#pragma unroll
    for (int it = 0; it < 8; ++it) {
      int p = it * 8 + pp2;
      __half2 h = __floats2half2_rn(tile[(2 * cp) * 65 + p], tile[(2 * cp + 1) * 65 + p]);
      xtu[(size_t)(b * 1024 + p0 + p) * 128 + cc * 32 + cp] = __builtin_bit_cast(uint, h);
    }
  } else if (blk < 3488) {
    int i = (blk - 1024) * 256 + tid;
    if (i < 73728) {
      // Boff[tap][n][c], zero-padded n>=27
      int c = i & 255; int n = (i >> 8) & 31; int tap = i >> 13;
      float v = (n < 27) ? w_off[((size_t)n * 256 + c) * 9 + tap] : 0.f;
      ((__half*)(ws + BOFF))[i] = __float2half(v);
    } else if (i < 73728 + 294912) {
      int d = i - 73728;            // d = oc*2304 + tap*256 + c
      int oc = d / 2304; int k = d % 2304;
      int tap = k >> 8; int c = k & 255;
      ((__half*)(ws + BD))[d] = __float2half(w_dcn[((size_t)oc * 256 + c) * 9 + tap]);
    } else if (i < 73728 + 294912 + 262144) {
      int d = i - (73728 + 294912);
      int par = d >> 16; int rem = d & 65535;
      int o = rem >> 9; int k = rem & 511;
      int t4 = k >> 7; int c = k & 127;
      int ty = t4 >> 1, tx = t4 & 1;
      int pu = par >> 1, pv = par & 1;
      int ky = (1 - pu) + 2 * ty, kx = (1 - pv) + 2 * tx;
      float v = w_up[((size_t)c * 128 + o) * 16 + ky * 4 + kx];
      ((ushort*)(ws + BP))[d] = f2bf(v);
    }
  } else {
    int i = (blk - 3488) * 256 + tid;
    if (i < 3072) ws[ST1 + i] = 0.f;  // ST1(1024)+ST2(2048) contiguous
  }
}

// ---------------- 2. offset conv full-K + bias + sigmoid ---------------------------
__global__ __launch_bounds__(256) void offconv_mfma_kernel(const __half* __restrict__ xt,
                                                           const __half* __restrict__ boff,
                                                           const float* __restrict__ b_off,
                                                           float* __restrict__ off) {
  __shared__ short As[32 * 132];
  __shared__ short Bs[32 * 132];
  int blk = blockIdx.x;
  int pt = blk & 31, b = blk >> 5;
  int P0 = pt * 32;
  int tid = threadIdx.x;
  int wid = tid >> 6, lane = tid & 63, lr = lane & 15, quad = lane >> 4;
  int m_w = (wid & 1) * 16, n_w = (wid >> 1) * 16;
  int arow = tid >> 3, aseg = tid & 7;  // 32 rows x 16 halves
  int pix = P0 + arow; int h = pix >> 5, w = pix & 31;

  floatx4 acc = (floatx4)0.f;

  for (int s = 0; s < 18; ++s) {
    int tap = s >> 1, ch = (s & 1) * 128;
    int ty = tap / 3, tx = tap % 3;
    int yy = h + ty - 1, xx = w + tx - 1;
    bool valid = (yy >= 0) && (yy < 32) && (xx >= 0) && (xx < 32);
    int pos = min(max(yy, 0), 31) * 32 + min(max(xx, 0), 31);
    const float4* ga = (const float4*)(xt + ((size_t)(b * 1024 + pos)) * 256 + ch + aseg * 16);
    float4 a0 = ga[0], a1 = ga[1];
    if (!valid) { a0 = make_float4(0.f, 0.f, 0.f, 0.f); a1 = a0; }
    const float4* gb = (const float4*)(boff + ((size_t)(tap * 32 + arow)) * 256 + ch + aseg * 16);
    float4 b0 = gb[0], b1 = gb[1];
    if (s) __syncthreads();
    float4* qa = (float4*)(As + arow * 132 + aseg * 16);
    qa[0] = a0; qa[1] = a1;
    float4* qb = (float4*)(Bs + arow * 132 + aseg * 16);
    qb[0] = b0; qb[1] = b1;
    __syncthreads();
#pragma unroll
    for (int k2 = 0; k2 < 4; ++k2) {
      half8 af = *(const half8*)(As + (m_w + lr) * 132 + k2 * 32 + quad * 8);
      half8 bf = *(const half8*)(Bs + (n_w + lr) * 132 + k2 * 32 + quad * 8);
      acc = __builtin_amdgcn_mfma_f32_16x16x32_f16(af, bf, acc, 0, 0, 0);
    }
  }
  int n = n_w + lr;
  float bias = (n < 27) ? b_off[n] : 0.f;
  bool sig = (n >= 18) && (n < 27);
#pragma unroll
  for (int r = 0; r < 4; ++r) {
    int m = m_w + quad * 4 + r;
    float v = acc[r] + bias;
    if (sig) v = 1.f / (1.f + __expf(-v));
    off[((size_t)(b * 1024 + P0 + m)) * 32 + n] = v;
  }
}

// ---------------- 3. deformable conv via fused gather + f16 MFMA -------------------
__global__ __launch_bounds__(256) void deform_mfma_kernel(const __half* __restrict__ xt,
                                                          const float* __restrict__ off,
                                                          const __half* __restrict__ bd,
                                                          float* __restrict__ y_part) {
  __shared__ short As[128 * 72];
  __shared__ short Bs[128 * 72];
  int blk = blockIdx.x;
  int ptile = blk & 7, cs = (blk >> 3) & 3, b = blk >> 5;
  int tid = threadIdx.x;
  int wid = tid >> 6, lane = tid & 63, lr = lane & 15, quad = lane >> 4;
  int m_w = (wid & 1) * 64, n_w = (wid >> 1) * 64;
  int P0 = ptile * 128;
  int pix_l = tid >> 1, chalf = (tid & 1) * 32;
  int pix = P0 + pix_l;
  int h = pix >> 5, w = pix & 31;
  const float* offb = off + (size_t)(b * 1024 + pix) * 32;
  const __half* xb = xt + (size_t)b * 1024 * 256 + cs * 64 + chalf;
  int ocb = tid >> 1, seg = tid & 1;
  const __half* bdr = bd + (size_t)ocb * 2304 + cs * 64 + seg * 32;

  floatx4 acc[4][4];
#pragma unroll
  for (int mi = 0; mi < 4; ++mi)
#pragma unroll
    for (int ni = 0; ni < 4; ++ni) acc[mi][ni] = (floatx4)0.f;

  for (int tap = 0; tap < 9; ++tap) {
    float dy = offb[2 * tap];
    float dx = offb[2 * tap + 1];
    float mm = offb[18 + tap];
    float py = (float)(h + tap / 3 - 1) + dy;
    float px = (float)(w + tap % 3 - 1) + dx;
    float y0f = floorf(py), x0f = floorf(px);
    float wy = py - y0f, wx = px - x0f;
    int y0 = (int)y0f, x0 = (int)x0f;
    float cw[4] = {(1.f - wy) * (1.f - wx), (1.f - wy) * wx, wy * (1.f - wx), wy * wx};
    uint4 q[4][4];
    __half2 w2[4];
#pragma unroll
    for (int t = 0; t < 4; ++t) {
      int yy = y0 + (t >> 1), xx = x0 + (t & 1);
      bool v = (yy >= 0) && (yy <= 31) && (xx >= 0) && (xx <= 31);
      int yc = min(max(yy, 0), 31), xc = min(max(xx, 0), 31);
      const uint4* xr = (const uint4*)(xb + (size_t)(yc * 32 + xc) * 256);
      q[t][0] = xr[0]; q[t][1] = xr[1]; q[t][2] = xr[2]; q[t][3] = xr[3];
      w2[t] = __float2half2_rn(v ? cw[t] * mm : 0.f);
    }
    const float4* gb = (const float4*)(bdr + tap * 256);
    float4 b0 = gb[0], b1 = gb[1], b2 = gb[2], b3 = gb[3];

    __half2 hacc[16];
#pragma unroll
    for (int j = 0; j < 16; ++j) hacc[j] = __float2half2_rn(0.f);
#pragma unroll
    for (int t = 0; t < 4; ++t) {
      uint qa[16] = {q[t][0].x, q[t][0].y, q[t][0].z, q[t][0].w,
                     q[t][1].x, q[t][1].y, q[t][1].z, q[t][1].w,
                     q[t][2].x, q[t][2].y, q[t][2].z, q[t][2].w,
                     q[t][3].x, q[t][3].y, q[t][3].z, q[t][3].w};
#pragma unroll
      for (int j = 0; j < 16; ++j)
        hacc[j] = __hfma2(w2[t], __builtin_bit_cast(__half2, qa[j]), hacc[j]);
    }
    if (tap) __syncthreads();
#pragma unroll
    for (int g = 0; g < 4; ++g) {
      float4 f;
      f.x = __builtin_bit_cast(float, hacc[4 * g + 0]);
      f.y = __builtin_bit_cast(float, hacc[4 * g + 1]);
      f.z = __builtin_bit_cast(float, hacc[4 * g + 2]);
      f.w = __builtin_bit_cast(float, hacc[4 * g + 3]);
      *(float4*)(As + pix_l * 72 + chalf + g * 8) = f;
    }
    *(float4*)(Bs + ocb * 72 + seg * 32 + 0)  = b0;
    *(float4*)(Bs + ocb * 72 + seg * 32 + 8)  = b1;
    *(float4*)(Bs + ocb * 72 + seg * 32 + 16) = b2;
    *(float4*)(Bs + ocb * 72 + seg * 32 + 24) = b3;
    __syncthreads();
#pragma unroll
    for (int k2 = 0; k2 < 2; ++k2) {
      half8 af[4], bf[4];
#pragma unroll
      for (int mi = 0; mi < 4; ++mi)
        af[mi] = *(const half8*)(As + (m_w + mi * 16 + lr) * 72 + k2 * 32 + quad * 8);
#pragma unroll
      for (int ni = 0; ni < 4; ++ni)
        bf[ni] = *(const half8*)(Bs + (n_w + ni * 16 + lr) * 72 + k2 * 32 + quad * 8);
#pragma unroll
      for (int mi = 0; mi < 4; ++mi)
#pragma unroll
        for (int ni = 0; ni < 4; ++ni)
          acc[mi][ni] = __builtin_amdgcn_mfma_f32_16x16x32_f16(af[mi], bf[ni], acc[mi][ni], 0, 0, 0);
    }
  }
  float* yp = y_part + (size_t)cs * 2097152 + ((size_t)(b * 1024 + P0)) * 128;
#pragma unroll
  for (int mi = 0; mi < 4; ++mi) {
#pragma unroll
    for (int r = 0; r < 4; ++r) {
      int m = m_w + mi * 16 + quad * 4 + r;
      float* orow = yp + (size_t)m * 128;
#pragma unroll
      for (int ni = 0; ni < 4; ++ni)
        orow[n_w + ni * 16 + lr] = acc[mi][ni][r];
    }
  }
}

// ---------------- 4. yred: 4-partial sum + bias -> ysum; striped BN1 atomics -------
__global__ __launch_bounds__(256) void yred_kernel(const float* __restrict__ yp,
                                                   const float* __restrict__ b_dcn,
                                                   float* __restrict__ ysum,
                                                   float* __restrict__ st1) {
  int blk = blockIdx.x; int tid = threadIdx.x;
  int oc = tid & 127, rh = tid >> 7;
  float bias = b_dcn[oc];
  float s = 0.f, sq = 0.f;
  for (int r = rh; r < 128; r += 2) {
    size_t idx = ((size_t)(blk * 128 + r)) * 128 + oc;
    float v = yp[idx] + yp[2097152 + idx] + yp[4194304 + idx] + yp[6291456 + idx] + bias;
    ysum[idx] = v;
    s += v; sq = fmaf(v, v, sq);
  }
  __shared__ float ls[256], lq[256];
  ls[tid] = s; lq[tid] = sq; __syncthreads();
  if (tid < 128) {
    float* dst = st1 + (blk & 3) * 256;
    atomicAdd(&dst[tid], ls[tid] + ls[tid + 128]);
    atomicAdd(&dst[128 + tid], lq[tid] + lq[tid + 128]);
  }
}

// ---------------- 5. deconv: BN1+ReLU inline, prefetch-pipelined, striped stats ----
__device__ __forceinline__ void dc_load_stage(int kk, int uu, int vv, int pu, int pv,
                                              int b, int par, int sm, int shalf,
                                              const float* __restrict__ ysum,
                                              const ushort* __restrict__ bp,
                                              float4* fq, float4* bq) {
  int t = kk >> 1, chalf = (kk & 1) * 64;
  int ty = t >> 1, tx = t & 1;
  int i = uu + pu - ty, j = vv + pv - tx;
  int pos = min(max(i, 0), 31) * 32 + min(max(j, 0), 31);
  const float4* ga = (const float4*)(ysum + ((size_t)(b * 1024 + pos)) * 128 + chalf + shalf * 32);
#pragma unroll
  for (int q = 0; q < 8; ++q) fq[q] = ga[q];
  const float4* gb = (const float4*)(bp + ((size_t)(par * 128 + sm) * 512 + kk * 64 + shalf * 32));
#pragma unroll
  for (int q = 0; q < 4; ++q) bq[q] = gb[q];
}

__global__ __launch_bounds__(256) void deconv_mfma_kernel(const float* __restrict__ ysum,
                                                          const float* __restrict__ st1,
                                                          const float* __restrict__ g1,
                                                          const float* __restrict__ bt1,
                                                          const ushort* __restrict__ bp,
                                                          float* __restrict__ O,
                                                          float* __restrict__ st2) {
  __shared__ ushort As[128 * 72];
  __shared__ ushort Bs[128 * 72];
  __shared__ float scs[128], shs[128];
  int blk = blockIdx.x;
  int ptile = blk & 7, par = (blk >> 3) & 3, b = blk >> 5;
  int pu = par >> 1, pv = par & 1;
  int tid = threadIdx.x;
  int wid = tid >> 6, lane = tid & 63, lr = lane & 15, quad = lane >> 4;
  int m_w = (wid & 1) * 64, n_w = (wid >> 1) * 64;
  int P0 = ptile * 128;
  int sm = tid >> 1, shalf = tid & 1;
  int pix = P0 + sm, uu = pix >> 5, vv = pix & 31;

  if (tid < 128) {
    float s  = st1[tid] + st1[256 + tid] + st1[512 + tid] + st1[768 + tid];
    float sq = st1[128 + tid] + st1[384 + tid] + st1[640 + tid] + st1[896 + tid];
    float mean = s / 16384.f;
    float var = sq / 16384.f - mean * mean;
    float sc = g1[tid] * rsqrtf(var + EPSV);
    scs[tid] = sc;
    shs[tid] = fmaf(-mean, sc, bt1[tid]);
  }
  __syncthreads();

  floatx4 acc[4][4];
#pragma unroll
  for (int mi = 0; mi < 4; ++mi)
#pragma unroll
    for (int ni = 0; ni < 4; ++ni) acc[mi][ni] = (floatx4)0.f;

  float4 fq[8], bq[4];
  dc_load_stage(0, uu, vv, pu, pv, b, par, sm, shalf, ysum, bp, fq, bq);

#pragma unroll
  for (int kk = 0; kk < 8; ++kk) {
    int t = kk >> 1, chalf = (kk & 1) * 64;
    int ty = t >> 1, tx = t & 1;
    int i = uu + pu - ty, j = vv + pv - tx;
    bool valid = (i >= 0) && (i <= 31) && (j >= 0) && (j <= 31);
    int c0 = chalf + shalf * 32;
    // BN1+ReLU+bf16 pack (round-half-up via +0x8000, v_perm packs 2 per op)
    const float* fv = (const float*)fq;
    uint pk[16];
#pragma unroll
    for (int j2 = 0; j2 < 16; ++j2) {
      float v0 = fmaxf(fmaf(fv[2 * j2],     scs[c0 + 2 * j2],     shs[c0 + 2 * j2]), 0.f);
      float v1 = fmaxf(fmaf(fv[2 * j2 + 1], scs[c0 + 2 * j2 + 1], shs[c0 + 2 * j2 + 1]), 0.f);
      uint u0 = __builtin_bit_cast(uint, v0) + 0x8000u;
      uint u1 = __builtin_bit_cast(uint, v1) + 0x8000u;
      pk[j2] = __builtin_amdgcn_perm(u1, u0, 0x07060302u);
    }
    if (!valid) {
#pragma unroll
      for (int j2 = 0; j2 < 16; ++j2) pk[j2] = 0u;
    }
    if (kk) __syncthreads();
    uint4* qa = (uint4*)(As + sm * 72 + shalf * 32);
    qa[0] = make_uint4(pk[0], pk[1], pk[2], pk[3]);
    qa[1] = make_uint4(pk[4], pk[5], pk[6], pk[7]);
    qa[2] = make_uint4(pk[8], pk[9], pk[10], pk[11]);
    qa[3] = make_uint4(pk[12], pk[13], pk[14], pk[15]);
    float4* qb = (float4*)(Bs + sm * 72 + shalf * 32);
    qb[0] = bq[0]; qb[1] = bq[1]; qb[2] = bq[2]; qb[3] = bq[3];
    __syncthreads();
    // prefetch next stage while MFMA consumes LDS
    if (kk < 7)
      dc_load_stage(kk + 1, uu, vv, pu, pv, b, par, sm, shalf, ysum, bp, fq, bq);
#pragma unroll
    for (int k2 = 0; k2 < 64; k2 += 32) {
      short8 af[4], bfr[4];
#pragma unroll
      for (int mi = 0; mi < 4; ++mi)
        af[mi] = *(const short8*)(As + (m_w + mi * 16 + lr) * 72 + k2 + quad * 8);
#pragma unroll
      for (int ni = 0; ni < 4; ++ni)
        bfr[ni] = *(const short8*)(Bs + (n_w + ni * 16 + lr) * 72 + k2 + quad * 8);
#pragma unroll
      for (int mi = 0; mi < 4; ++mi)
#pragma unroll
        for (int ni = 0; ni < 4; ++ni)
          acc[mi][ni] = __builtin_amdgcn_mfma_f32_16x16x32_bf16(af[mi], bfr[ni], acc[mi][ni], 0, 0, 0);
    }
  }
  size_t obase = (size_t)(b * 4 + par) * 1024 * 128;
#pragma unroll
  for (int mi = 0; mi < 4; ++mi) {
#pragma unroll
    for (int r = 0; r < 4; ++r) {
      int m = m_w + mi * 16 + quad * 4 + r;
      float* orow = O + obase + (size_t)(P0 + m) * 128;
#pragma unroll
      for (int ni = 0; ni < 4; ++ni)
        orow[n_w + ni * 16 + lr] = acc[mi][ni][r];
    }
  }
  // BN2 stats: quad shuffle-reduce -> LDS block-reduce -> striped atomics
  float sn[4], qn[4];
#pragma unroll
  for (int ni = 0; ni < 4; ++ni) {
    float s = 0.f, q = 0.f;
#pragma unroll
    for (int mi = 0; mi < 4; ++mi)
#pragma unroll
      for (int r = 0; r < 4; ++r) {
        float v = acc[mi][ni][r];
        s += v; q = fmaf(v, v, q);
      }
    sn[ni] = s; qn[ni] = q;
  }
#pragma unroll
  for (int ni = 0; ni < 4; ++ni) {
    sn[ni] += __shfl_xor(sn[ni], 16);
    sn[ni] += __shfl_xor(sn[ni], 32);
    qn[ni] += __shfl_xor(qn[ni], 16);
    qn[ni] += __shfl_xor(qn[ni], 32);
  }
  __syncthreads();
  float* red = (float*)As;  // 512 floats scratch
  if (lane < 16) {
#pragma unroll
    for (int ni = 0; ni < 4; ++ni) {
      red[wid * 64 + ni * 16 + lr] = sn[ni];
      red[256 + wid * 64 + ni * 16 + lr] = qn[ni];
    }
  }
  __syncthreads();
  if (tid < 128) {
    int sg = tid >> 6, l = tid & 63;
    float s = red[(sg * 2) * 64 + l] + red[(sg * 2 + 1) * 64 + l];
    float q = red[256 + (sg * 2) * 64 + l] + red[256 + (sg * 2 + 1) * 64 + l];
    float* dst = st2 + (blk & 7) * 256;
    atomicAdd(&dst[tid], s);
    atomicAdd(&dst[128 + tid], q);
  }
}

// ---------------- 6. bnout: BN2 from striped stats + transpose to NCHW -------------
__global__ __launch_bounds__(256) void bnout_kernel(const float* __restrict__ O,
                                                    const float* __restrict__ st2,
                                                    const float* __restrict__ g2,
                                                    const float* __restrict__ bt2,
                                                    float* __restrict__ out) {
  __shared__ float tile[128 * 33];
  __shared__ float scs[128], shs[128];
  int blk = blockIdx.x;
  int uu = blk & 31, par = (blk >> 5) & 3, b = blk >> 7;
  int pu = par >> 1, pv = par & 1;
  int tid = threadIdx.x;
  if (tid < 128) {
    float s = 0.f, sq = 0.f;
#pragma unroll
    for (int c = 0; c < 8; ++c) {
      s += st2[c * 256 + tid];
      sq += st2[c * 256 + 128 + tid];
    }
    float mean = s / 65536.f;
    float var = sq / 65536.f - mean * mean;
    float sc = g2[tid] * rsqrtf(var + EPSV);
    scs[tid] = sc;
    shs[tid] = fmaf(-mean, sc, bt2[tid]);
  }
  __syncthreads();
#pragma unroll 4
  for (int it = 0; it < 16; ++it) {
    int idx = it * 256 + tid;
    int vv = idx >> 7, oc = idx & 127;
    float v = O[((size_t)(b * 4 + par) * 1024 + uu * 32 + vv) * 128 + oc];
    tile[oc * 33 + vv] = fmaxf(fmaf(v, scs[oc], shs[oc]), 0.f);
  }
  __syncthreads();
#pragma unroll 4
  for (int it = 0; it < 16; ++it) {
    int idx = it * 256 + tid;
    int oc = idx >> 5, vv = idx & 31;
    out[((size_t)b * 128 + oc) * 4096 + (2 * uu + pu) * 64 + 2 * vv + pv] = tile[oc * 33 + vv];
  }
}

extern "C" void kernel_launch(void* const* d_in, const int* in_sizes, int n_in,
                              void* d_out, int out_size, void* d_ws, size_t ws_size,
                              hipStream_t stream) {
  const float* x     = (const float*)d_in[0];
  const float* w_off = (const float*)d_in[1];
  const float* b_off = (const float*)d_in[2];
  const float* w_dcn = (const float*)d_in[3];
  const float* b_dcn = (const float*)d_in[4];
  const float* g1    = (const float*)d_in[5];
  const float* bt1   = (const float*)d_in[6];
  const float* w_up  = (const float*)d_in[7];
  const float* g2    = (const float*)d_in[8];
  const float* bt2   = (const float*)d_in[9];
  float* ws  = (float*)d_ws;
  float* out = (float*)d_out;

  prep_xt_kernel<<<3500, 256, 0, stream>>>(x, w_off, w_dcn, w_up, ws);
  offconv_mfma_kernel<<<512, 256, 0, stream>>>((const __half*)(ws + XT),
                                               (const __half*)(ws + BOFF), b_off, ws + OFFB);
  deform_mfma_kernel<<<512, 256, 0, stream>>>((const __half*)(ws + XT), ws + OFFB,
                                              (const __half*)(ws + BD), ws + YP);
  yred_kernel<<<128, 256, 0, stream>>>(ws + YP, b_dcn, ws + YSUM, ws + ST1);
  deconv_mfma_kernel<<<512, 256, 0, stream>>>(ws + YSUM, ws + ST1, g1, bt1,
                                              (const ushort*)(ws + BP), ws + OB, ws + ST2);
  bnout_kernel<<<2048, 256, 0, stream>>>(ws + OB, ws + ST2, g2, bt2, out);
}

// Round 7
// 213.340 us; speedup vs baseline: 3.9831x; 1.0185x over previous
//
#include <hip/hip_runtime.h>
#include <hip/hip_fp16.h>
#include <math.h>

#define HW 1024
#define EPSV 1e-5f

typedef unsigned int uint;
typedef unsigned short ushort;
typedef __attribute__((ext_vector_type(8))) short short8;
typedef __attribute__((ext_vector_type(8))) _Float16 half8;
typedef __attribute__((ext_vector_type(4))) float floatx4;

// ---------------- ws layout (float offsets), no aliasing ---------------------------
static const size_t BOFF = 0;         // 36864   fp16 Boff[tap][n32][c256]
static const size_t BD   = 36864;     // 147456  fp16 Bd[oc][tap*256+c]
static const size_t BQ   = 184320;    // 131072  bf16 Bq[par][kstep][quad][n][8] (frag order)
static const size_t XT   = 315392;    // 2097152 fp16 xT[b][p][c]
static const size_t OFFB = 2412544;   // 524288  off [b][pix][32] fp32
static const size_t ST1  = 2936832;   // 1024: BN1 sum/sq, 4 striped copies of 256
static const size_t ST2  = 2937856;   // 4096: BN2 sum/sq, 16 striped copies of 256
static const size_t YP   = 2941952;   // 8388608 y_part[4][pix][oc]
static const size_t YSUM = 11330560;  // 2097152 ysum[pix][oc] fp32 (bias applied)
static const size_t YBN  = 13427712;  // 1048576 floats = 2M bf16 ybn[pix][oc]
static const size_t OB   = 14476288;  // 8388608 O[b][par][pix][oc] fp32
// total = 22864896 floats = 91.5 MB

__device__ inline ushort f2bf(float f) {
  uint u = __builtin_bit_cast(uint, f);
  uint r = (u + 0x7FFFu + ((u >> 16) & 1u)) >> 16;
  return (ushort)r;
}

// ---------------- 1. prep + xT + zero striped accumulators -------------------------
__global__ __launch_bounds__(256) void prep_xt_kernel(const float* __restrict__ x,
                                                      const float* __restrict__ w_off,
                                                      const float* __restrict__ w_dcn,
                                                      const float* __restrict__ w_up,
                                                      float* __restrict__ ws) {
  __shared__ float tile[64 * 65];
  int blk = blockIdx.x;
  int tid = threadIdx.x;
  if (blk < 1024) {
    // xT: x[b][c][p] fp32 -> xT[b][p][c] fp16
    int b = blk >> 6, pt = (blk >> 2) & 15, cc = blk & 3;
    int p0 = pt * 64, c0 = cc * 64;
    int pp = tid & 63, ci = tid >> 6;
#pragma unroll
    for (int it = 0; it < 16; ++it) {
      int c = it * 4 + ci;
      tile[c * 65 + pp] = x[((size_t)(b * 256 + c0 + c)) * HW + p0 + pp];
    }
    __syncthreads();
    int cp = tid & 31, pp2 = tid >> 5;
    uint* xtu = (uint*)(ws + XT);
#pragma unroll
    for (int it = 0; it < 8; ++it) {
      int p = it * 8 + pp2;
      __half2 h = __floats2half2_rn(tile[(2 * cp) * 65 + p], tile[(2 * cp + 1) * 65 + p]);
      xtu[(size_t)(b * 1024 + p0 + p) * 128 + cc * 32 + cp] = __builtin_bit_cast(uint, h);
    }
  } else if (blk < 3488) {
    int i = (blk - 1024) * 256 + tid;
    if (i < 73728) {
      // Boff[tap][n][c], zero-padded n>=27
      int c = i & 255; int n = (i >> 8) & 31; int tap = i >> 13;
      float v = (n < 27) ? w_off[((size_t)n * 256 + c) * 9 + tap] : 0.f;
      ((__half*)(ws + BOFF))[i] = __float2half(v);
    } else if (i < 73728 + 294912) {
      int d = i - 73728;            // d = oc*2304 + tap*256 + c
      int oc = d / 2304; int k = d % 2304;
      int tap = k >> 8; int c = k & 255;
      ((__half*)(ws + BD))[d] = __float2half(w_dcn[((size_t)oc * 256 + c) * 9 + tap]);
    } else if (i < 73728 + 294912 + 262144) {
      // Bq[par][kstep][quad][n][8] bf16, fragment-ordered for direct global reads
      int d = i - (73728 + 294912);
      int j = d & 7; int n = (d >> 3) & 127; int quad = (d >> 10) & 3;
      int kstep = (d >> 12) & 15; int par = d >> 16;
      int k = kstep * 32 + quad * 8 + j;
      int t4 = k >> 7; int c = k & 127;
      int ty = t4 >> 1, tx = t4 & 1;
      int pu = par >> 1, pv = par & 1;
      int ky = (1 - pu) + 2 * ty, kx = (1 - pv) + 2 * tx;
      float v = w_up[((size_t)c * 128 + n) * 16 + ky * 4 + kx];
      ((ushort*)(ws + BQ))[d] = f2bf(v);
    }
  } else {
    int i = (blk - 3488) * 256 + tid;
    if (i < 5120) ws[ST1 + i] = 0.f;  // ST1(1024)+ST2(4096) contiguous
  }
}

// ---------------- 2. offset conv full-K + bias + sigmoid ---------------------------
__global__ __launch_bounds__(256) void offconv_mfma_kernel(const __half* __restrict__ xt,
                                                           const __half* __restrict__ boff,
                                                           const float* __restrict__ b_off,
                                                           float* __restrict__ off) {
  __shared__ short As[32 * 132];
  __shared__ short Bs[32 * 132];
  int blk = blockIdx.x;
  int pt = blk & 31, b = blk >> 5;
  int P0 = pt * 32;
  int tid = threadIdx.x;
  int wid = tid >> 6, lane = tid & 63, lr = lane & 15, quad = lane >> 4;
  int m_w = (wid & 1) * 16, n_w = (wid >> 1) * 16;
  int arow = tid >> 3, aseg = tid & 7;  // 32 rows x 16 halves
  int pix = P0 + arow; int h = pix >> 5, w = pix & 31;

  floatx4 acc = (floatx4)0.f;

  for (int s = 0; s < 18; ++s) {
    int tap = s >> 1, ch = (s & 1) * 128;
    int ty = tap / 3, tx = tap % 3;
    int yy = h + ty - 1, xx = w + tx - 1;
    bool valid = (yy >= 0) && (yy < 32) && (xx >= 0) && (xx < 32);
    int pos = min(max(yy, 0), 31) * 32 + min(max(xx, 0), 31);
    const float4* ga = (const float4*)(xt + ((size_t)(b * 1024 + pos)) * 256 + ch + aseg * 16);
    float4 a0 = ga[0], a1 = ga[1];
    if (!valid) { a0 = make_float4(0.f, 0.f, 0.f, 0.f); a1 = a0; }
    const float4* gb = (const float4*)(boff + ((size_t)(tap * 32 + arow)) * 256 + ch + aseg * 16);
    float4 b0 = gb[0], b1 = gb[1];
    if (s) __syncthreads();
    float4* qa = (float4*)(As + arow * 132 + aseg * 16);
    qa[0] = a0; qa[1] = a1;
    float4* qb = (float4*)(Bs + arow * 132 + aseg * 16);
    qb[0] = b0; qb[1] = b1;
    __syncthreads();
#pragma unroll
    for (int k2 = 0; k2 < 4; ++k2) {
      half8 af = *(const half8*)(As + (m_w + lr) * 132 + k2 * 32 + quad * 8);
      half8 bf = *(const half8*)(Bs + (n_w + lr) * 132 + k2 * 32 + quad * 8);
      acc = __builtin_amdgcn_mfma_f32_16x16x32_f16(af, bf, acc, 0, 0, 0);
    }
  }
  int n = n_w + lr;
  float bias = (n < 27) ? b_off[n] : 0.f;
  bool sig = (n >= 18) && (n < 27);
#pragma unroll
  for (int r = 0; r < 4; ++r) {
    int m = m_w + quad * 4 + r;
    float v = acc[r] + bias;
    if (sig) v = 1.f / (1.f + __expf(-v));
    off[((size_t)(b * 1024 + P0 + m)) * 32 + n] = v;
  }
}

// ---------------- 3. deformable conv via fused gather + f16 MFMA -------------------
__global__ __launch_bounds__(256) void deform_mfma_kernel(const __half* __restrict__ xt,
                                                          const float* __restrict__ off,
                                                          const __half* __restrict__ bd,
                                                          float* __restrict__ y_part) {
  __shared__ short As[128 * 72];
  __shared__ short Bs[128 * 72];
  int blk = blockIdx.x;
  int ptile = blk & 7, cs = (blk >> 3) & 3, b = blk >> 5;
  int tid = threadIdx.x;
  int wid = tid >> 6, lane = tid & 63, lr = lane & 15, quad = lane >> 4;
  int m_w = (wid & 1) * 64, n_w = (wid >> 1) * 64;
  int P0 = ptile * 128;
  int pix_l = tid >> 1, chalf = (tid & 1) * 32;
  int pix = P0 + pix_l;
  int h = pix >> 5, w = pix & 31;
  const float* offb = off + (size_t)(b * 1024 + pix) * 32;
  const __half* xb = xt + (size_t)b * 1024 * 256 + cs * 64 + chalf;
  int ocb = tid >> 1, seg = tid & 1;
  const __half* bdr = bd + (size_t)ocb * 2304 + cs * 64 + seg * 32;

  floatx4 acc[4][4];
#pragma unroll
  for (int mi = 0; mi < 4; ++mi)
#pragma unroll
    for (int ni = 0; ni < 4; ++ni) acc[mi][ni] = (floatx4)0.f;

  for (int tap = 0; tap < 9; ++tap) {
    float dy = offb[2 * tap];
    float dx = offb[2 * tap + 1];
    float mm = offb[18 + tap];
    float py = (float)(h + tap / 3 - 1) + dy;
    float px = (float)(w + tap % 3 - 1) + dx;
    float y0f = floorf(py), x0f = floorf(px);
    float wy = py - y0f, wx = px - x0f;
    int y0 = (int)y0f, x0 = (int)x0f;
    float cw[4] = {(1.f - wy) * (1.f - wx), (1.f - wy) * wx, wy * (1.f - wx), wy * wx};
    uint4 q[4][4];
    __half2 w2[4];
#pragma unroll
    for (int t = 0; t < 4; ++t) {
      int yy = y0 + (t >> 1), xx = x0 + (t & 1);
      bool v = (yy >= 0) && (yy <= 31) && (xx >= 0) && (xx <= 31);
      int yc = min(max(yy, 0), 31), xc = min(max(xx, 0), 31);
      const uint4* xr = (const uint4*)(xb + (size_t)(yc * 32 + xc) * 256);
      q[t][0] = xr[0]; q[t][1] = xr[1]; q[t][2] = xr[2]; q[t][3] = xr[3];
      w2[t] = __float2half2_rn(v ? cw[t] * mm : 0.f);
    }
    const float4* gb = (const float4*)(bdr + tap * 256);
    float4 b0 = gb[0], b1 = gb[1], b2 = gb[2], b3 = gb[3];

    __half2 hacc[16];
#pragma unroll
    for (int j = 0; j < 16; ++j) hacc[j] = __float2half2_rn(0.f);
#pragma unroll
    for (int t = 0; t < 4; ++t) {
      uint qa[16] = {q[t][0].x, q[t][0].y, q[t][0].z, q[t][0].w,
                     q[t][1].x, q[t][1].y, q[t][1].z, q[t][1].w,
                     q[t][2].x, q[t][2].y, q[t][2].z, q[t][2].w,
                     q[t][3].x, q[t][3].y, q[t][3].z, q[t][3].w};
#pragma unroll
      for (int j = 0; j < 16; ++j)
        hacc[j] = __hfma2(w2[t], __builtin_bit_cast(__half2, qa[j]), hacc[j]);
    }
    if (tap) __syncthreads();
#pragma unroll
    for (int g = 0; g < 4; ++g) {
      float4 f;
      f.x = __builtin_bit_cast(float, hacc[4 * g + 0]);
      f.y = __builtin_bit_cast(float, hacc[4 * g + 1]);
      f.z = __builtin_bit_cast(float, hacc[4 * g + 2]);
      f.w = __builtin_bit_cast(float, hacc[4 * g + 3]);
      *(float4*)(As + pix_l * 72 + chalf + g * 8) = f;
    }
    *(float4*)(Bs + ocb * 72 + seg * 32 + 0)  = b0;
    *(float4*)(Bs + ocb * 72 + seg * 32 + 8)  = b1;
    *(float4*)(Bs + ocb * 72 + seg * 32 + 16) = b2;
    *(float4*)(Bs + ocb * 72 + seg * 32 + 24) = b3;
    __syncthreads();
#pragma unroll
    for (int k2 = 0; k2 < 2; ++k2) {
      half8 af[4], bf[4];
#pragma unroll
      for (int mi = 0; mi < 4; ++mi)
        af[mi] = *(const half8*)(As + (m_w + mi * 16 + lr) * 72 + k2 * 32 + quad * 8);
#pragma unroll
      for (int ni = 0; ni < 4; ++ni)
        bf[ni] = *(const half8*)(Bs + (n_w + ni * 16 + lr) * 72 + k2 * 32 + quad * 8);
#pragma unroll
      for (int mi = 0; mi < 4; ++mi)
#pragma unroll
        for (int ni = 0; ni < 4; ++ni)
          acc[mi][ni] = __builtin_amdgcn_mfma_f32_16x16x32_f16(af[mi], bf[ni], acc[mi][ni], 0, 0, 0);
    }
  }
  float* yp = y_part + (size_t)cs * 2097152 + ((size_t)(b * 1024 + P0)) * 128;
#pragma unroll
  for (int mi = 0; mi < 4; ++mi) {
#pragma unroll
    for (int r = 0; r < 4; ++r) {
      int m = m_w + mi * 16 + quad * 4 + r;
      float* orow = yp + (size_t)m * 128;
#pragma unroll
      for (int ni = 0; ni < 4; ++ni)
        orow[n_w + ni * 16 + lr] = acc[mi][ni][r];
    }
  }
}

// ---------------- 4. yred: 4-partial sum + bias -> ysum; striped BN1 atomics -------
__global__ __launch_bounds__(256) void yred_kernel(const float* __restrict__ yp,
                                                   const float* __restrict__ b_dcn,
                                                   float* __restrict__ ysum,
                                                   float* __restrict__ st1) {
  int blk = blockIdx.x; int tid = threadIdx.x;
  int oc = tid & 127, rh = tid >> 7;
  float bias = b_dcn[oc];
  float s = 0.f, sq = 0.f;
  for (int r = rh; r < 128; r += 2) {
    size_t idx = ((size_t)(blk * 128 + r)) * 128 + oc;
    float v = yp[idx] + yp[2097152 + idx] + yp[4194304 + idx] + yp[6291456 + idx] + bias;
    ysum[idx] = v;
    s += v; sq = fmaf(v, v, sq);
  }
  __shared__ float ls[256], lq[256];
  ls[tid] = s; lq[tid] = sq; __syncthreads();
  if (tid < 128) {
    float* dst = st1 + (blk & 3) * 256;
    atomicAdd(&dst[tid], ls[tid] + ls[tid + 128]);
    atomicAdd(&dst[128 + tid], lq[tid] + lq[tid + 128]);
  }
}

// ---------------- 5. ybn: BN1+ReLU -> bf16 [pix][c] --------------------------------
__global__ __launch_bounds__(256) void ybn_kernel(const float* __restrict__ ysum,
                                                  const float* __restrict__ st1,
                                                  const float* __restrict__ g1,
                                                  const float* __restrict__ bt1,
                                                  ushort* __restrict__ ybn) {
  __shared__ float scs[128], shs[128];
  int tid = threadIdx.x;
  if (tid < 128) {
    float s  = st1[tid] + st1[256 + tid] + st1[512 + tid] + st1[768 + tid];
    float sq = st1[128 + tid] + st1[384 + tid] + st1[640 + tid] + st1[896 + tid];
    float mean = s / 16384.f;
    float var = sq / 16384.f - mean * mean;
    float sc = g1[tid] * rsqrtf(var + EPSV);
    scs[tid] = sc;
    shs[tid] = fmaf(-mean, sc, bt1[tid]);
  }
  __syncthreads();
  int i4 = blockIdx.x * 256 + tid;
  size_t i = (size_t)i4 * 4;
  int oc = (int)(i & 127);
  float4 v = *(const float4*)(ysum + i);
  ushort r[4];
  r[0] = f2bf(fmaxf(fmaf(v.x, scs[oc], shs[oc]), 0.f));
  r[1] = f2bf(fmaxf(fmaf(v.y, scs[oc + 1], shs[oc + 1]), 0.f));
  r[2] = f2bf(fmaxf(fmaf(v.z, scs[oc + 2], shs[oc + 2]), 0.f));
  r[3] = f2bf(fmaxf(fmaf(v.w, scs[oc + 3], shs[oc + 3]), 0.f));
  uint2 pk;
  pk.x = (uint)r[0] | ((uint)r[1] << 16);
  pk.y = (uint)r[2] | ((uint)r[3] << 16);
  *(uint2*)(ybn + i) = pk;
}

// ---------------- 6. deconv: barrier-free register GEMM from global ----------------
// 1024 blocks: b(16) x par(4) x 64-pix tile(16). wave = 64 rows x 32 cols (wid quarter)
__global__ __launch_bounds__(256) void deconv_mfma_kernel(const ushort* __restrict__ ybn,
                                                          const ushort* __restrict__ bq,
                                                          float* __restrict__ O,
                                                          float* __restrict__ st2) {
  int blk = blockIdx.x;
  int pt = blk & 15, par = (blk >> 4) & 3, b = blk >> 6;
  int pu = par >> 1, pv = par & 1;
  int tid = threadIdx.x;
  int wid = tid >> 6, lane = tid & 63, lr = lane & 15, quad = lane >> 4;
  int P0 = pt * 64;
  int hh[4], ww[4];
#pragma unroll
  for (int mi = 0; mi < 4; ++mi) {
    int p = P0 + mi * 16 + lr;
    hh[mi] = p >> 5; ww[mi] = p & 31;
  }

  floatx4 acc[4][2];
#pragma unroll
  for (int mi = 0; mi < 4; ++mi)
#pragma unroll
    for (int ni = 0; ni < 2; ++ni) acc[mi][ni] = (floatx4)0.f;

  const ushort* ybb = ybn + (size_t)b * 1024 * 128;
  // Bq flat index: par*65536 + kstep*4096 + quad*1024 + n*8
  const ushort* bqb = bq + par * 65536 + quad * 1024 + (wid * 32 + lr) * 8;

#pragma unroll
  for (int tap = 0; tap < 4; ++tap) {
    int ty = tap >> 1, tx = tap & 1;
    int ab[4]; bool val[4];
#pragma unroll
    for (int mi = 0; mi < 4; ++mi) {
      int i = hh[mi] + pu - ty, j = ww[mi] + pv - tx;
      val[mi] = (i >= 0) && (i <= 31) && (j >= 0) && (j <= 31);
      int pos = min(max(i, 0), 31) * 32 + min(max(j, 0), 31);
      ab[mi] = pos * 128;
    }
#pragma unroll
    for (int k2 = 0; k2 < 4; ++k2) {
      int kstep = tap * 4 + k2;
      int c0 = k2 * 32 + quad * 8;
      short8 bf[2];
#pragma unroll
      for (int ni = 0; ni < 2; ++ni)
        bf[ni] = *(const short8*)(bqb + kstep * 4096 + ni * 128);
      short8 af[4];
#pragma unroll
      for (int mi = 0; mi < 4; ++mi) {
        short8 a = *(const short8*)(ybb + ab[mi] + c0);
        af[mi] = val[mi] ? a : (short8)0;
      }
#pragma unroll
      for (int mi = 0; mi < 4; ++mi)
#pragma unroll
        for (int ni = 0; ni < 2; ++ni)
          acc[mi][ni] = __builtin_amdgcn_mfma_f32_16x16x32_bf16(af[mi], bf[ni], acc[mi][ni], 0, 0, 0);
    }
  }
  // epilogue: O[b][par][pix][oc]
  size_t obase = (size_t)(b * 4 + par) * 1024 * 128;
#pragma unroll
  for (int mi = 0; mi < 4; ++mi) {
#pragma unroll
    for (int r = 0; r < 4; ++r) {
      int m = mi * 16 + quad * 4 + r;
      float* orow = O + obase + (size_t)(P0 + m) * 128 + wid * 32;
#pragma unroll
      for (int ni = 0; ni < 2; ++ni)
        orow[ni * 16 + lr] = acc[mi][ni][r];
    }
  }
  // BN2 stats: each wave owns distinct cols (wid quarter) -> quad shuffle + atomics
  float sn[2], qn[2];
#pragma unroll
  for (int ni = 0; ni < 2; ++ni) {
    float s = 0.f, q = 0.f;
#pragma unroll
    for (int mi = 0; mi < 4; ++mi)
#pragma unroll
      for (int r = 0; r < 4; ++r) {
        float v = acc[mi][ni][r];
        s += v; q = fmaf(v, v, q);
      }
    sn[ni] = s; qn[ni] = q;
  }
#pragma unroll
  for (int ni = 0; ni < 2; ++ni) {
    sn[ni] += __shfl_xor(sn[ni], 16);
    sn[ni] += __shfl_xor(sn[ni], 32);
    qn[ni] += __shfl_xor(qn[ni], 16);
    qn[ni] += __shfl_xor(qn[ni], 32);
  }
  if (lane < 16) {
    float* dst = st2 + (blk & 15) * 256;
#pragma unroll
    for (int ni = 0; ni < 2; ++ni) {
      atomicAdd(&dst[wid * 32 + ni * 16 + lr], sn[ni]);
      atomicAdd(&dst[128 + wid * 32 + ni * 16 + lr], qn[ni]);
    }
  }
}

// ---------------- 7. bnout: BN2 from 16 striped stats + transpose to NCHW ----------
__global__ __launch_bounds__(256) void bnout_kernel(const float* __restrict__ O,
                                                    const float* __restrict__ st2,
                                                    const float* __restrict__ g2,
                                                    const float* __restrict__ bt2,
                                                    float* __restrict__ out) {
  __shared__ float tile[128 * 33];
  __shared__ float scs[128], shs[128];
  int blk = blockIdx.x;
  int uu = blk & 31, par = (blk >> 5) & 3, b = blk >> 7;
  int pu = par >> 1, pv = par & 1;
  int tid = threadIdx.x;
  if (tid < 128) {
    float s = 0.f, sq = 0.f;
#pragma unroll
    for (int c = 0; c < 16; ++c) {
      s += st2[c * 256 + tid];
      sq += st2[c * 256 + 128 + tid];
    }
    float mean = s / 65536.f;
    float var = sq / 65536.f - mean * mean;
    float sc = g2[tid] * rsqrtf(var + EPSV);
    scs[tid] = sc;
    shs[tid] = fmaf(-mean, sc, bt2[tid]);
  }
  __syncthreads();
#pragma unroll 4
  for (int it = 0; it < 16; ++it) {
    int idx = it * 256 + tid;
    int vv = idx >> 7, oc = idx & 127;
    float v = O[((size_t)(b * 4 + par) * 1024 + uu * 32 + vv) * 128 + oc];
    tile[oc * 33 + vv] = fmaxf(fmaf(v, scs[oc], shs[oc]), 0.f);
  }
  __syncthreads();
#pragma unroll 4
  for (int it = 0; it < 16; ++it) {
    int idx = it * 256 + tid;
    int oc = idx >> 5, vv = idx & 31;
    out[((size_t)b * 128 + oc) * 4096 + (2 * uu + pu) * 64 + 2 * vv + pv] = tile[oc * 33 + vv];
  }
}

extern "C" void kernel_launch(void* const* d_in, const int* in_sizes, int n_in,
                              void* d_out, int out_size, void* d_ws, size_t ws_size,
                              hipStream_t stream) {
  const float* x     = (const float*)d_in[0];
  const float* w_off = (const float*)d_in[1];
  const float* b_off = (const float*)d_in[2];
  const float* w_dcn = (const float*)d_in[3];
  const float* b_dcn = (const float*)d_in[4];
  const float* g1    = (const float*)d_in[5];
  const float* bt1   = (const float*)d_in[6];
  const float* w_up  = (const float*)d_in[7];
  const float* g2    = (const float*)d_in[8];
  const float* bt2   = (const float*)d_in[9];
  float* ws  = (float*)d_ws;
  float* out = (float*)d_out;

  prep_xt_kernel<<<3508, 256, 0, stream>>>(x, w_off, w_dcn, w_up, ws);
  offconv_mfma_kernel<<<512, 256, 0, stream>>>((const __half*)(ws + XT),
                                               (const __half*)(ws + BOFF), b_off, ws + OFFB);
  deform_mfma_kernel<<<512, 256, 0, stream>>>((const __half*)(ws + XT), ws + OFFB,
                                              (const __half*)(ws + BD), ws + YP);
  yred_kernel<<<128, 256, 0, stream>>>(ws + YP, b_dcn, ws + YSUM, ws + ST1);
  ybn_kernel<<<2048, 256, 0, stream>>>(ws + YSUM, ws + ST1, g1, bt1, (ushort*)(ws + YBN));
  deconv_mfma_kernel<<<1024, 256, 0, stream>>>((const ushort*)(ws + YBN),
                                               (const ushort*)(ws + BQ), ws + OB, ws + ST2);
  bnout_kernel<<<2048, 256, 0, stream>>>(ws + OB, ws + ST2, g2, bt2, out);
}

// Round 8
// 209.224 us; speedup vs baseline: 4.0615x; 1.0197x over previous
//
#include <hip/hip_runtime.h>
#include <hip/hip_fp16.h>
#include <math.h>

#define HW 1024
#define EPSV 1e-5f

typedef unsigned int uint;
typedef unsigned short ushort;
typedef __attribute__((ext_vector_type(8))) short short8;
typedef __attribute__((ext_vector_type(8))) _Float16 half8;
typedef __attribute__((ext_vector_type(4))) float floatx4;

// ---------------- ws layout (float offsets), no aliasing ---------------------------
static const size_t BOFF = 0;         // 36864   fp16 Boff[tap][n32][c256]
static const size_t BD   = 36864;     // 147456  fp16 Bd[oc][tap*256+c]
static const size_t BQ   = 184320;    // 131072  bf16 Bq[par][kstep][quad][n][8] (frag order)
static const size_t XT   = 315392;    // 2097152 fp16 xT[b][p][c]
static const size_t OFFB = 2412544;   // 524288  off [b][pix][32] fp32 (atomic-accumulated)
static const size_t ST1  = 2936832;   // 1024: BN1 sum/sq, 4 striped copies of 256
static const size_t ST2  = 2937856;   // 4096: BN2 sum/sq, 16 striped copies of 256
static const size_t YP   = 2941952;   // 8388608 y_part[4][pix][oc]
static const size_t YSUM = 11330560;  // 2097152 ysum[pix][oc] fp32 (bias applied)
static const size_t YBN  = 13427712;  // 1048576 floats = 2M bf16 ybn[pix][oc]
static const size_t OB   = 14476288;  // 8388608 O[b][par][pix][oc] fp32
// total = 22864896 floats = 91.5 MB

__device__ inline ushort f2bf(float f) {
  uint u = __builtin_bit_cast(uint, f);
  uint r = (u + 0x7FFFu + ((u >> 16) & 1u)) >> 16;
  return (ushort)r;
}

// ---------------- 1. prep + xT + zero accumulators & off ---------------------------
__global__ __launch_bounds__(256) void prep_xt_kernel(const float* __restrict__ x,
                                                      const float* __restrict__ w_off,
                                                      const float* __restrict__ w_dcn,
                                                      const float* __restrict__ w_up,
                                                      float* __restrict__ ws) {
  __shared__ float tile[64 * 65];
  int blk = blockIdx.x;
  int tid = threadIdx.x;
  if (blk < 1024) {
    // xT: x[b][c][p] fp32 -> xT[b][p][c] fp16
    int b = blk >> 6, pt = (blk >> 2) & 15, cc = blk & 3;
    int p0 = pt * 64, c0 = cc * 64;
    int pp = tid & 63, ci = tid >> 6;
#pragma unroll
    for (int it = 0; it < 16; ++it) {
      int c = it * 4 + ci;
      tile[c * 65 + pp] = x[((size_t)(b * 256 + c0 + c)) * HW + p0 + pp];
    }
    __syncthreads();
    int cp = tid & 31, pp2 = tid >> 5;
    uint* xtu = (uint*)(ws + XT);
#pragma unroll
    for (int it = 0; it < 8; ++it) {
      int p = it * 8 + pp2;
      __half2 h = __floats2half2_rn(tile[(2 * cp) * 65 + p], tile[(2 * cp + 1) * 65 + p]);
      xtu[(size_t)(b * 1024 + p0 + p) * 128 + cc * 32 + cp] = __builtin_bit_cast(uint, h);
    }
  } else if (blk < 3488) {
    int i = (blk - 1024) * 256 + tid;
    if (i < 73728) {
      // Boff[tap][n][c], zero-padded n>=27
      int c = i & 255; int n = (i >> 8) & 31; int tap = i >> 13;
      float v = (n < 27) ? w_off[((size_t)n * 256 + c) * 9 + tap] : 0.f;
      ((__half*)(ws + BOFF))[i] = __float2half(v);
    } else if (i < 73728 + 294912) {
      int d = i - 73728;            // d = oc*2304 + tap*256 + c
      int oc = d / 2304; int k = d % 2304;
      int tap = k >> 8; int c = k & 255;
      ((__half*)(ws + BD))[d] = __float2half(w_dcn[((size_t)oc * 256 + c) * 9 + tap]);
    } else if (i < 73728 + 294912 + 262144) {
      // Bq[par][kstep][quad][n][8] bf16, fragment-ordered for direct global reads
      int d = i - (73728 + 294912);
      int j = d & 7; int n = (d >> 3) & 127; int quad = (d >> 10) & 3;
      int kstep = (d >> 12) & 15; int par = d >> 16;
      int k = kstep * 32 + quad * 8 + j;
      int t4 = k >> 7; int c = k & 127;
      int ty = t4 >> 1, tx = t4 & 1;
      int pu = par >> 1, pv = par & 1;
      int ky = (1 - pu) + 2 * ty, kx = (1 - pv) + 2 * tx;
      float v = w_up[((size_t)c * 128 + n) * 16 + ky * 4 + kx];
      ((ushort*)(ws + BQ))[d] = f2bf(v);
    }
  } else {
    int i = (blk - 3488) * 256 + tid;
    if (i < 5120) ws[ST1 + i] = 0.f;           // ST1(1024)+ST2(4096)
    else if (i < 5120 + 524288) ws[OFFB + (i - 5120)] = 0.f;  // off accumulator
  }
}

// ---------------- 2. offset conv, K-split x2, atomic raw accumulate ----------------
// 1024 blocks: b(16) x 32-pix tile(32) x cs(2 ch-halves). K=1152 per block.
__global__ __launch_bounds__(256) void offconv_mfma_kernel(const __half* __restrict__ xt,
                                                           const __half* __restrict__ boff,
                                                           float* __restrict__ off) {
  __shared__ short As[32 * 132];
  __shared__ short Bs[32 * 132];
  int blk = blockIdx.x;
  int pt = blk & 31, cs = (blk >> 5) & 1, b = blk >> 6;
  int P0 = pt * 32;
  int tid = threadIdx.x;
  int wid = tid >> 6, lane = tid & 63, lr = lane & 15, quad = lane >> 4;
  int m_w = (wid & 1) * 16, n_w = (wid >> 1) * 16;
  int arow = tid >> 3, aseg = tid & 7;  // 32 rows x 16 halves
  int pix = P0 + arow; int h = pix >> 5, w = pix & 31;

  floatx4 acc = (floatx4)0.f;

  for (int tap = 0; tap < 9; ++tap) {
    int ty = tap / 3, tx = tap % 3;
    int yy = h + ty - 1, xx = w + tx - 1;
    bool valid = (yy >= 0) && (yy < 32) && (xx >= 0) && (xx < 32);
    int pos = min(max(yy, 0), 31) * 32 + min(max(xx, 0), 31);
    const float4* ga = (const float4*)(xt + ((size_t)(b * 1024 + pos)) * 256 + cs * 128 + aseg * 16);
    float4 a0 = ga[0], a1 = ga[1];
    if (!valid) { a0 = make_float4(0.f, 0.f, 0.f, 0.f); a1 = a0; }
    const float4* gb = (const float4*)(boff + ((size_t)(tap * 32 + arow)) * 256 + cs * 128 + aseg * 16);
    float4 b0 = gb[0], b1 = gb[1];
    if (tap) __syncthreads();
    float4* qa = (float4*)(As + arow * 132 + aseg * 16);
    qa[0] = a0; qa[1] = a1;
    float4* qb = (float4*)(Bs + arow * 132 + aseg * 16);
    qb[0] = b0; qb[1] = b1;
    __syncthreads();
#pragma unroll
    for (int k2 = 0; k2 < 4; ++k2) {
      half8 af = *(const half8*)(As + (m_w + lr) * 132 + k2 * 32 + quad * 8);
      half8 bf = *(const half8*)(Bs + (n_w + lr) * 132 + k2 * 32 + quad * 8);
      acc = __builtin_amdgcn_mfma_f32_16x16x32_f16(af, bf, acc, 0, 0, 0);
    }
  }
  int n = n_w + lr;
#pragma unroll
  for (int r = 0; r < 4; ++r) {
    int m = m_w + quad * 4 + r;
    atomicAdd(&off[((size_t)(b * 1024 + P0 + m)) * 32 + n], acc[r]);
  }
}

// ---------------- 3. deformable conv, 64-px tiles (1024 blocks), fused bias+sigmoid
__global__ __launch_bounds__(256) void deform_mfma_kernel(const __half* __restrict__ xt,
                                                          const float* __restrict__ off,
                                                          const float* __restrict__ b_off,
                                                          const __half* __restrict__ bd,
                                                          float* __restrict__ y_part) {
  __shared__ short As[64 * 72];
  __shared__ short Bs[128 * 72];
  int blk = blockIdx.x;
  int ptile = blk & 15, cs = (blk >> 4) & 3, b = blk >> 6;
  int tid = threadIdx.x;
  int wid = tid >> 6, lane = tid & 63, lr = lane & 15, quad = lane >> 4;
  int m_w = (wid & 1) * 32, n_w = (wid >> 1) * 64;
  int P0 = ptile * 64;
  int pix_l = tid >> 2, cseg = tid & 3;   // 64 px x 16-ch segs
  int pix = P0 + pix_l;
  int h = pix >> 5, w = pix & 31;
  const float* offb = off + (size_t)(b * 1024 + pix) * 32;
  const __half* xb = xt + (size_t)b * 1024 * 256 + cs * 64 + cseg * 16;
  int ocb = tid >> 1, seg = tid & 1;      // 128 oc x 32-ch halves
  const __half* bdr = bd + (size_t)ocb * 2304 + cs * 64 + seg * 32;

  floatx4 acc[2][4];
#pragma unroll
  for (int mi = 0; mi < 2; ++mi)
#pragma unroll
    for (int ni = 0; ni < 4; ++ni) acc[mi][ni] = (floatx4)0.f;

  for (int tap = 0; tap < 9; ++tap) {
    float dy = offb[2 * tap] + b_off[2 * tap];
    float dx = offb[2 * tap + 1] + b_off[2 * tap + 1];
    float mraw = offb[18 + tap] + b_off[18 + tap];
    float mm = 1.f / (1.f + __expf(-mraw));
    float py = (float)(h + tap / 3 - 1) + dy;
    float px = (float)(w + tap % 3 - 1) + dx;
    float y0f = floorf(py), x0f = floorf(px);
    float wy = py - y0f, wx = px - x0f;
    int y0 = (int)y0f, x0 = (int)x0f;
    float cw[4] = {(1.f - wy) * (1.f - wx), (1.f - wy) * wx, wy * (1.f - wx), wy * wx};
    uint4 q[4][2];
    __half2 w2[4];
#pragma unroll
    for (int t = 0; t < 4; ++t) {
      int yy = y0 + (t >> 1), xx = x0 + (t & 1);
      bool v = (yy >= 0) && (yy <= 31) && (xx >= 0) && (xx <= 31);
      int yc = min(max(yy, 0), 31), xc = min(max(xx, 0), 31);
      const uint4* xr = (const uint4*)(xb + (size_t)(yc * 32 + xc) * 256);
      q[t][0] = xr[0]; q[t][1] = xr[1];
      w2[t] = __float2half2_rn(v ? cw[t] * mm : 0.f);
    }
    const float4* gb = (const float4*)(bdr + tap * 256);
    float4 b0 = gb[0], b1 = gb[1], b2 = gb[2], b3 = gb[3];

    __half2 hacc[8];
#pragma unroll
    for (int j = 0; j < 8; ++j) hacc[j] = __float2half2_rn(0.f);
#pragma unroll
    for (int t = 0; t < 4; ++t) {
      uint qa[8] = {q[t][0].x, q[t][0].y, q[t][0].z, q[t][0].w,
                    q[t][1].x, q[t][1].y, q[t][1].z, q[t][1].w};
#pragma unroll
      for (int j = 0; j < 8; ++j)
        hacc[j] = __hfma2(w2[t], __builtin_bit_cast(__half2, qa[j]), hacc[j]);
    }
    if (tap) __syncthreads();
    {
      float4 f0, f1;
      f0.x = __builtin_bit_cast(float, hacc[0]);
      f0.y = __builtin_bit_cast(float, hacc[1]);
      f0.z = __builtin_bit_cast(float, hacc[2]);
      f0.w = __builtin_bit_cast(float, hacc[3]);
      f1.x = __builtin_bit_cast(float, hacc[4]);
      f1.y = __builtin_bit_cast(float, hacc[5]);
      f1.z = __builtin_bit_cast(float, hacc[6]);
      f1.w = __builtin_bit_cast(float, hacc[7]);
      float4* qa2 = (float4*)(As + pix_l * 72 + cseg * 16);
      qa2[0] = f0; qa2[1] = f1;
    }
    float4* qb = (float4*)(Bs + ocb * 72 + seg * 32);
    qb[0] = b0; qb[1] = b1; qb[2] = b2; qb[3] = b3;
    __syncthreads();
#pragma unroll
    for (int k2 = 0; k2 < 2; ++k2) {
      half8 af[2], bf[4];
#pragma unroll
      for (int mi = 0; mi < 2; ++mi)
        af[mi] = *(const half8*)(As + (m_w + mi * 16 + lr) * 72 + k2 * 32 + quad * 8);
#pragma unroll
      for (int ni = 0; ni < 4; ++ni)
        bf[ni] = *(const half8*)(Bs + (n_w + ni * 16 + lr) * 72 + k2 * 32 + quad * 8);
#pragma unroll
      for (int mi = 0; mi < 2; ++mi)
#pragma unroll
        for (int ni = 0; ni < 4; ++ni)
          acc[mi][ni] = __builtin_amdgcn_mfma_f32_16x16x32_f16(af[mi], bf[ni], acc[mi][ni], 0, 0, 0);
    }
  }
  float* yp = y_part + (size_t)cs * 2097152 + ((size_t)(b * 1024 + P0)) * 128;
#pragma unroll
  for (int mi = 0; mi < 2; ++mi) {
#pragma unroll
    for (int r = 0; r < 4; ++r) {
      int m = m_w + mi * 16 + quad * 4 + r;
      float* orow = yp + (size_t)m * 128;
#pragma unroll
      for (int ni = 0; ni < 4; ++ni)
        orow[n_w + ni * 16 + lr] = acc[mi][ni][r];
    }
  }
}

// ---------------- 4. yred: 4-partial sum + bias -> ysum; striped BN1 atomics -------
__global__ __launch_bounds__(256) void yred_kernel(const float* __restrict__ yp,
                                                   const float* __restrict__ b_dcn,
                                                   float* __restrict__ ysum,
                                                   float* __restrict__ st1) {
  int blk = blockIdx.x; int tid = threadIdx.x;
  int oc = tid & 127, rh = tid >> 7;
  float bias = b_dcn[oc];
  float s = 0.f, sq = 0.f;
  for (int r = rh; r < 128; r += 2) {
    size_t idx = ((size_t)(blk * 128 + r)) * 128 + oc;
    float v = yp[idx] + yp[2097152 + idx] + yp[4194304 + idx] + yp[6291456 + idx] + bias;
    ysum[idx] = v;
    s += v; sq = fmaf(v, v, sq);
  }
  __shared__ float ls[256], lq[256];
  ls[tid] = s; lq[tid] = sq; __syncthreads();
  if (tid < 128) {
    float* dst = st1 + (blk & 3) * 256;
    atomicAdd(&dst[tid], ls[tid] + ls[tid + 128]);
    atomicAdd(&dst[128 + tid], lq[tid] + lq[tid + 128]);
  }
}

// ---------------- 5. ybn: BN1+ReLU -> bf16 [pix][c] --------------------------------
__global__ __launch_bounds__(256) void ybn_kernel(const float* __restrict__ ysum,
                                                  const float* __restrict__ st1,
                                                  const float* __restrict__ g1,
                                                  const float* __restrict__ bt1,
                                                  ushort* __restrict__ ybn) {
  __shared__ float scs[128], shs[128];
  int tid = threadIdx.x;
  if (tid < 128) {
    float s  = st1[tid] + st1[256 + tid] + st1[512 + tid] + st1[768 + tid];
    float sq = st1[128 + tid] + st1[384 + tid] + st1[640 + tid] + st1[896 + tid];
    float mean = s / 16384.f;
    float var = sq / 16384.f - mean * mean;
    float sc = g1[tid] * rsqrtf(var + EPSV);
    scs[tid] = sc;
    shs[tid] = fmaf(-mean, sc, bt1[tid]);
  }
  __syncthreads();
  int i4 = blockIdx.x * 256 + tid;
  size_t i = (size_t)i4 * 4;
  int oc = (int)(i & 127);
  float4 v = *(const float4*)(ysum + i);
  ushort r[4];
  r[0] = f2bf(fmaxf(fmaf(v.x, scs[oc], shs[oc]), 0.f));
  r[1] = f2bf(fmaxf(fmaf(v.y, scs[oc + 1], shs[oc + 1]), 0.f));
  r[2] = f2bf(fmaxf(fmaf(v.z, scs[oc + 2], shs[oc + 2]), 0.f));
  r[3] = f2bf(fmaxf(fmaf(v.w, scs[oc + 3], shs[oc + 3]), 0.f));
  uint2 pk;
  pk.x = (uint)r[0] | ((uint)r[1] << 16);
  pk.y = (uint)r[2] | ((uint)r[3] << 16);
  *(uint2*)(ybn + i) = pk;
}

// ---------------- 6. deconv: barrier-free register GEMM from global ----------------
__global__ __launch_bounds__(256) void deconv_mfma_kernel(const ushort* __restrict__ ybn,
                                                          const ushort* __restrict__ bq,
                                                          float* __restrict__ O,
                                                          float* __restrict__ st2) {
  int blk = blockIdx.x;
  int pt = blk & 15, par = (blk >> 4) & 3, b = blk >> 6;
  int pu = par >> 1, pv = par & 1;
  int tid = threadIdx.x;
  int wid = tid >> 6, lane = tid & 63, lr = lane & 15, quad = lane >> 4;
  int P0 = pt * 64;
  int hh[4], ww[4];
#pragma unroll
  for (int mi = 0; mi < 4; ++mi) {
    int p = P0 + mi * 16 + lr;
    hh[mi] = p >> 5; ww[mi] = p & 31;
  }

  floatx4 acc[4][2];
#pragma unroll
  for (int mi = 0; mi < 4; ++mi)
#pragma unroll
    for (int ni = 0; ni < 2; ++ni) acc[mi][ni] = (floatx4)0.f;

  const ushort* ybb = ybn + (size_t)b * 1024 * 128;
  const ushort* bqb = bq + par * 65536 + quad * 1024 + (wid * 32 + lr) * 8;

#pragma unroll
  for (int tap = 0; tap < 4; ++tap) {
    int ty = tap >> 1, tx = tap & 1;
    int ab[4]; bool val[4];
#pragma unroll
    for (int mi = 0; mi < 4; ++mi) {
      int i = hh[mi] + pu - ty, j = ww[mi] + pv - tx;
      val[mi] = (i >= 0) && (i <= 31) && (j >= 0) && (j <= 31);
      int pos = min(max(i, 0), 31) * 32 + min(max(j, 0), 31);
      ab[mi] = pos * 128;
    }
#pragma unroll
    for (int k2 = 0; k2 < 4; ++k2) {
      int kstep = tap * 4 + k2;
      int c0 = k2 * 32 + quad * 8;
      short8 bf[2];
#pragma unroll
      for (int ni = 0; ni < 2; ++ni)
        bf[ni] = *(const short8*)(bqb + kstep * 4096 + ni * 128);
      short8 af[4];
#pragma unroll
      for (int mi = 0; mi < 4; ++mi) {
        short8 a = *(const short8*)(ybb + ab[mi] + c0);
        af[mi] = val[mi] ? a : (short8)0;
      }
#pragma unroll
      for (int mi = 0; mi < 4; ++mi)
#pragma unroll
        for (int ni = 0; ni < 2; ++ni)
          acc[mi][ni] = __builtin_amdgcn_mfma_f32_16x16x32_bf16(af[mi], bf[ni], acc[mi][ni], 0, 0, 0);
    }
  }
  size_t obase = (size_t)(b * 4 + par) * 1024 * 128;
#pragma unroll
  for (int mi = 0; mi < 4; ++mi) {
#pragma unroll
    for (int r = 0; r < 4; ++r) {
      int m = mi * 16 + quad * 4 + r;
      float* orow = O + obase + (size_t)(P0 + m) * 128 + wid * 32;
#pragma unroll
      for (int ni = 0; ni < 2; ++ni)
        orow[ni * 16 + lr] = acc[mi][ni][r];
    }
  }
  float sn[2], qn[2];
#pragma unroll
  for (int ni = 0; ni < 2; ++ni) {
    float s = 0.f, q = 0.f;
#pragma unroll
    for (int mi = 0; mi < 4; ++mi)
#pragma unroll
      for (int r = 0; r < 4; ++r) {
        float v = acc[mi][ni][r];
        s += v; q = fmaf(v, v, q);
      }
    sn[ni] = s; qn[ni] = q;
  }
#pragma unroll
  for (int ni = 0; ni < 2; ++ni) {
    sn[ni] += __shfl_xor(sn[ni], 16);
    sn[ni] += __shfl_xor(sn[ni], 32);
    qn[ni] += __shfl_xor(qn[ni], 16);
    qn[ni] += __shfl_xor(qn[ni], 32);
  }
  if (lane < 16) {
    float* dst = st2 + (blk & 15) * 256;
#pragma unroll
    for (int ni = 0; ni < 2; ++ni) {
      atomicAdd(&dst[wid * 32 + ni * 16 + lr], sn[ni]);
      atomicAdd(&dst[128 + wid * 32 + ni * 16 + lr], qn[ni]);
    }
  }
}

// ---------------- 7. bnout: BN2 from 16 striped stats + transpose to NCHW ----------
__global__ __launch_bounds__(256) void bnout_kernel(const float* __restrict__ O,
                                                    const float* __restrict__ st2,
                                                    const float* __restrict__ g2,
                                                    const float* __restrict__ bt2,
                                                    float* __restrict__ out) {
  __shared__ float tile[128 * 33];
  __shared__ float scs[128], shs[128];
  int blk = blockIdx.x;
  int uu = blk & 31, par = (blk >> 5) & 3, b = blk >> 7;
  int pu = par >> 1, pv = par & 1;
  int tid = threadIdx.x;
  if (tid < 128) {
    float s = 0.f, sq = 0.f;
#pragma unroll
    for (int c = 0; c < 16; ++c) {
      s += st2[c * 256 + tid];
      sq += st2[c * 256 + 128 + tid];
    }
    float mean = s / 65536.f;
    float var = sq / 65536.f - mean * mean;
    float sc = g2[tid] * rsqrtf(var + EPSV);
    scs[tid] = sc;
    shs[tid] = fmaf(-mean, sc, bt2[tid]);
  }
  __syncthreads();
#pragma unroll 4
  for (int it = 0; it < 16; ++it) {
    int idx = it * 256 + tid;
    int vv = idx >> 7, oc = idx & 127;
    float v = O[((size_t)(b * 4 + par) * 1024 + uu * 32 + vv) * 128 + oc];
    tile[oc * 33 + vv] = fmaxf(fmaf(v, scs[oc], shs[oc]), 0.f);
  }
  __syncthreads();
#pragma unroll 4
  for (int it = 0; it < 16; ++it) {
    int idx = it * 256 + tid;
    int oc = idx >> 5, vv = idx & 31;
    out[((size_t)b * 128 + oc) * 4096 + (2 * uu + pu) * 64 + 2 * vv + pv] = tile[oc * 33 + vv];
  }
}

extern "C" void kernel_launch(void* const* d_in, const int* in_sizes, int n_in,
                              void* d_out, int out_size, void* d_ws, size_t ws_size,
                              hipStream_t stream) {
  const float* x     = (const float*)d_in[0];
  const float* w_off = (const float*)d_in[1];
  const float* b_off = (const float*)d_in[2];
  const float* w_dcn = (const float*)d_in[3];
  const float* b_dcn = (const float*)d_in[4];
  const float* g1    = (const float*)d_in[5];
  const float* bt1   = (const float*)d_in[6];
  const float* w_up  = (const float*)d_in[7];
  const float* g2    = (const float*)d_in[8];
  const float* bt2   = (const float*)d_in[9];
  float* ws  = (float*)d_ws;
  float* out = (float*)d_out;

  prep_xt_kernel<<<5556, 256, 0, stream>>>(x, w_off, w_dcn, w_up, ws);
  offconv_mfma_kernel<<<1024, 256, 0, stream>>>((const __half*)(ws + XT),
                                                (const __half*)(ws + BOFF), ws + OFFB);
  deform_mfma_kernel<<<1024, 256, 0, stream>>>((const __half*)(ws + XT), ws + OFFB, b_off,
                                               (const __half*)(ws + BD), ws + YP);
  yred_kernel<<<128, 256, 0, stream>>>(ws + YP, b_dcn, ws + YSUM, ws + ST1);
  ybn_kernel<<<2048, 256, 0, stream>>>(ws + YSUM, ws + ST1, g1, bt1, (ushort*)(ws + YBN));
  deconv_mfma_kernel<<<1024, 256, 0, stream>>>((const ushort*)(ws + YBN),
                                               (const ushort*)(ws + BQ), ws + OB, ws + ST2);
  bnout_kernel<<<2048, 256, 0, stream>>>(ws + OB, ws + ST2, g2, bt2, out);
}

// Round 9
// 208.275 us; speedup vs baseline: 4.0800x; 1.0046x over previous
//
#include <hip/hip_runtime.h>
#include <hip/hip_fp16.h>
#include <math.h>

#define HW 1024
#define EPSV 1e-5f

typedef unsigned int uint;
typedef unsigned short ushort;
typedef __attribute__((ext_vector_type(8))) short short8;
typedef __attribute__((ext_vector_type(8))) _Float16 half8;
typedef __attribute__((ext_vector_type(4))) float floatx4;

// ---------------- ws layout (float offsets), no aliasing ---------------------------
static const size_t BOFF = 0;         // 36864   fp16 Boff[tap][n32][c256]
static const size_t BD   = 36864;     // 147456  fp16 Bd[oc][tap*256+c]
static const size_t BQ   = 184320;    // 131072  bf16 Bq[par][kstep][quad][n][8] (frag order)
static const size_t XT   = 315392;    // 2097152 fp16 xT[b][p][c]
static const size_t OFFB = 2412544;   // 524288  off [b][pix][32] fp32 (atomic-accumulated)
static const size_t ST1  = 2936832;   // 1024: BN1 sum/sq, 4 striped copies of 256
static const size_t ST2  = 2937856;   // 4096: BN2 sum/sq, 16 striped copies of 256
static const size_t YP   = 2941952;   // 4194304 floats = bf16 y_part[4][pix][oc]
static const size_t YSUM = 7136256;   // 1048576 floats = bf16 ysum[pix][oc]
static const size_t YBN  = 8184832;   // 1048576 floats = bf16 ybn[pix][oc]
static const size_t OB   = 9233408;   // 4194304 floats = bf16 O[b][par][pix][oc]
// total = 13427712 floats = 53.7 MB

__device__ inline ushort f2bf(float f) {
  uint u = __builtin_bit_cast(uint, f);
  uint r = (u + 0x7FFFu + ((u >> 16) & 1u)) >> 16;
  return (ushort)r;
}
__device__ inline float b2f(ushort u) {
  return __builtin_bit_cast(float, ((uint)u) << 16);
}

// ---------------- 1. prep + xT + zero accumulators & off ---------------------------
__global__ __launch_bounds__(256) void prep_xt_kernel(const float* __restrict__ x,
                                                      const float* __restrict__ w_off,
                                                      const float* __restrict__ w_dcn,
                                                      const float* __restrict__ w_up,
                                                      float* __restrict__ ws) {
  __shared__ float tile[64 * 65];
  int blk = blockIdx.x;
  int tid = threadIdx.x;
  if (blk < 1024) {
    // xT: x[b][c][p] fp32 -> xT[b][p][c] fp16
    int b = blk >> 6, pt = (blk >> 2) & 15, cc = blk & 3;
    int p0 = pt * 64, c0 = cc * 64;
    int pp = tid & 63, ci = tid >> 6;
#pragma unroll
    for (int it = 0; it < 16; ++it) {
      int c = it * 4 + ci;
      tile[c * 65 + pp] = x[((size_t)(b * 256 + c0 + c)) * HW + p0 + pp];
    }
    __syncthreads();
    int cp = tid & 31, pp2 = tid >> 5;
    uint* xtu = (uint*)(ws + XT);
#pragma unroll
    for (int it = 0; it < 8; ++it) {
      int p = it * 8 + pp2;
      __half2 h = __floats2half2_rn(tile[(2 * cp) * 65 + p], tile[(2 * cp + 1) * 65 + p]);
      xtu[(size_t)(b * 1024 + p0 + p) * 128 + cc * 32 + cp] = __builtin_bit_cast(uint, h);
    }
  } else if (blk < 3488) {
    int i = (blk - 1024) * 256 + tid;
    if (i < 73728) {
      // Boff[tap][n][c], zero-padded n>=27
      int c = i & 255; int n = (i >> 8) & 31; int tap = i >> 13;
      float v = (n < 27) ? w_off[((size_t)n * 256 + c) * 9 + tap] : 0.f;
      ((__half*)(ws + BOFF))[i] = __float2half(v);
    } else if (i < 73728 + 294912) {
      int d = i - 73728;            // d = oc*2304 + tap*256 + c
      int oc = d / 2304; int k = d % 2304;
      int tap = k >> 8; int c = k & 255;
      ((__half*)(ws + BD))[d] = __float2half(w_dcn[((size_t)oc * 256 + c) * 9 + tap]);
    } else if (i < 73728 + 294912 + 262144) {
      // Bq[par][kstep][quad][n][8] bf16, fragment-ordered for direct global reads
      int d = i - (73728 + 294912);
      int j = d & 7; int n = (d >> 3) & 127; int quad = (d >> 10) & 3;
      int kstep = (d >> 12) & 15; int par = d >> 16;
      int k = kstep * 32 + quad * 8 + j;
      int t4 = k >> 7; int c = k & 127;
      int ty = t4 >> 1, tx = t4 & 1;
      int pu = par >> 1, pv = par & 1;
      int ky = (1 - pu) + 2 * ty, kx = (1 - pv) + 2 * tx;
      float v = w_up[((size_t)c * 128 + n) * 16 + ky * 4 + kx];
      ((ushort*)(ws + BQ))[d] = f2bf(v);
    }
  } else {
    int i = (blk - 3488) * 256 + tid;
    if (i < 5120) ws[ST1 + i] = 0.f;           // ST1(1024)+ST2(4096)
    else if (i < 5120 + 524288) ws[OFFB + (i - 5120)] = 0.f;  // off accumulator
  }
}

// ---------------- 2. offset conv, K-split x2, atomic raw accumulate ----------------
__global__ __launch_bounds__(256) void offconv_mfma_kernel(const __half* __restrict__ xt,
                                                           const __half* __restrict__ boff,
                                                           float* __restrict__ off) {
  __shared__ short As[32 * 132];
  __shared__ short Bs[32 * 132];
  int blk = blockIdx.x;
  int pt = blk & 31, cs = (blk >> 5) & 1, b = blk >> 6;
  int P0 = pt * 32;
  int tid = threadIdx.x;
  int wid = tid >> 6, lane = tid & 63, lr = lane & 15, quad = lane >> 4;
  int m_w = (wid & 1) * 16, n_w = (wid >> 1) * 16;
  int arow = tid >> 3, aseg = tid & 7;  // 32 rows x 16 halves
  int pix = P0 + arow; int h = pix >> 5, w = pix & 31;

  floatx4 acc = (floatx4)0.f;

  for (int tap = 0; tap < 9; ++tap) {
    int ty = tap / 3, tx = tap % 3;
    int yy = h + ty - 1, xx = w + tx - 1;
    bool valid = (yy >= 0) && (yy < 32) && (xx >= 0) && (xx < 32);
    int pos = min(max(yy, 0), 31) * 32 + min(max(xx, 0), 31);
    const float4* ga = (const float4*)(xt + ((size_t)(b * 1024 + pos)) * 256 + cs * 128 + aseg * 16);
    float4 a0 = ga[0], a1 = ga[1];
    if (!valid) { a0 = make_float4(0.f, 0.f, 0.f, 0.f); a1 = a0; }
    const float4* gb = (const float4*)(boff + ((size_t)(tap * 32 + arow)) * 256 + cs * 128 + aseg * 16);
    float4 b0 = gb[0], b1 = gb[1];
    if (tap) __syncthreads();
    float4* qa = (float4*)(As + arow * 132 + aseg * 16);
    qa[0] = a0; qa[1] = a1;
    float4* qb = (float4*)(Bs + arow * 132 + aseg * 16);
    qb[0] = b0; qb[1] = b1;
    __syncthreads();
#pragma unroll
    for (int k2 = 0; k2 < 4; ++k2) {
      half8 af = *(const half8*)(As + (m_w + lr) * 132 + k2 * 32 + quad * 8);
      half8 bf = *(const half8*)(Bs + (n_w + lr) * 132 + k2 * 32 + quad * 8);
      acc = __builtin_amdgcn_mfma_f32_16x16x32_f16(af, bf, acc, 0, 0, 0);
    }
  }
  int n = n_w + lr;
#pragma unroll
  for (int r = 0; r < 4; ++r) {
    int m = m_w + quad * 4 + r;
    atomicAdd(&off[((size_t)(b * 1024 + P0 + m)) * 32 + n], acc[r]);
  }
}

// ---------------- 3. deformable conv, 64-px tiles, bf16 partial output -------------
__global__ __launch_bounds__(256) void deform_mfma_kernel(const __half* __restrict__ xt,
                                                          const float* __restrict__ off,
                                                          const float* __restrict__ b_off,
                                                          const __half* __restrict__ bd,
                                                          ushort* __restrict__ y_part) {
  __shared__ short As[64 * 72];
  __shared__ short Bs[128 * 72];
  int blk = blockIdx.x;
  int ptile = blk & 15, cs = (blk >> 4) & 3, b = blk >> 6;
  int tid = threadIdx.x;
  int wid = tid >> 6, lane = tid & 63, lr = lane & 15, quad = lane >> 4;
  int m_w = (wid & 1) * 32, n_w = (wid >> 1) * 64;
  int P0 = ptile * 64;
  int pix_l = tid >> 2, cseg = tid & 3;   // 64 px x 16-ch segs
  int pix = P0 + pix_l;
  int h = pix >> 5, w = pix & 31;
  const float* offb = off + (size_t)(b * 1024 + pix) * 32;
  const __half* xb = xt + (size_t)b * 1024 * 256 + cs * 64 + cseg * 16;
  int ocb = tid >> 1, seg = tid & 1;      // 128 oc x 32-ch halves
  const __half* bdr = bd + (size_t)ocb * 2304 + cs * 64 + seg * 32;

  floatx4 acc[2][4];
#pragma unroll
  for (int mi = 0; mi < 2; ++mi)
#pragma unroll
    for (int ni = 0; ni < 4; ++ni) acc[mi][ni] = (floatx4)0.f;

  for (int tap = 0; tap < 9; ++tap) {
    float dy = offb[2 * tap] + b_off[2 * tap];
    float dx = offb[2 * tap + 1] + b_off[2 * tap + 1];
    float mraw = offb[18 + tap] + b_off[18 + tap];
    float mm = 1.f / (1.f + __expf(-mraw));
    float py = (float)(h + tap / 3 - 1) + dy;
    float px = (float)(w + tap % 3 - 1) + dx;
    float y0f = floorf(py), x0f = floorf(px);
    float wy = py - y0f, wx = px - x0f;
    int y0 = (int)y0f, x0 = (int)x0f;
    float cw[4] = {(1.f - wy) * (1.f - wx), (1.f - wy) * wx, wy * (1.f - wx), wy * wx};
    uint4 q[4][2];
    __half2 w2[4];
#pragma unroll
    for (int t = 0; t < 4; ++t) {
      int yy = y0 + (t >> 1), xx = x0 + (t & 1);
      bool v = (yy >= 0) && (yy <= 31) && (xx >= 0) && (xx <= 31);
      int yc = min(max(yy, 0), 31), xc = min(max(xx, 0), 31);
      const uint4* xr = (const uint4*)(xb + (size_t)(yc * 32 + xc) * 256);
      q[t][0] = xr[0]; q[t][1] = xr[1];
      w2[t] = __float2half2_rn(v ? cw[t] * mm : 0.f);
    }
    const float4* gb = (const float4*)(bdr + tap * 256);
    float4 b0 = gb[0], b1 = gb[1], b2 = gb[2], b3 = gb[3];

    __half2 hacc[8];
#pragma unroll
    for (int j = 0; j < 8; ++j) hacc[j] = __float2half2_rn(0.f);
#pragma unroll
    for (int t = 0; t < 4; ++t) {
      uint qa[8] = {q[t][0].x, q[t][0].y, q[t][0].z, q[t][0].w,
                    q[t][1].x, q[t][1].y, q[t][1].z, q[t][1].w};
#pragma unroll
      for (int j = 0; j < 8; ++j)
        hacc[j] = __hfma2(w2[t], __builtin_bit_cast(__half2, qa[j]), hacc[j]);
    }
    if (tap) __syncthreads();
    {
      float4 f0, f1;
      f0.x = __builtin_bit_cast(float, hacc[0]);
      f0.y = __builtin_bit_cast(float, hacc[1]);
      f0.z = __builtin_bit_cast(float, hacc[2]);
      f0.w = __builtin_bit_cast(float, hacc[3]);
      f1.x = __builtin_bit_cast(float, hacc[4]);
      f1.y = __builtin_bit_cast(float, hacc[5]);
      f1.z = __builtin_bit_cast(float, hacc[6]);
      f1.w = __builtin_bit_cast(float, hacc[7]);
      float4* qa2 = (float4*)(As + pix_l * 72 + cseg * 16);
      qa2[0] = f0; qa2[1] = f1;
    }
    float4* qb = (float4*)(Bs + ocb * 72 + seg * 32);
    qb[0] = b0; qb[1] = b1; qb[2] = b2; qb[3] = b3;
    __syncthreads();
#pragma unroll
    for (int k2 = 0; k2 < 2; ++k2) {
      half8 af[2], bf[4];
#pragma unroll
      for (int mi = 0; mi < 2; ++mi)
        af[mi] = *(const half8*)(As + (m_w + mi * 16 + lr) * 72 + k2 * 32 + quad * 8);
#pragma unroll
      for (int ni = 0; ni < 4; ++ni)
        bf[ni] = *(const half8*)(Bs + (n_w + ni * 16 + lr) * 72 + k2 * 32 + quad * 8);
#pragma unroll
      for (int mi = 0; mi < 2; ++mi)
#pragma unroll
        for (int ni = 0; ni < 4; ++ni)
          acc[mi][ni] = __builtin_amdgcn_mfma_f32_16x16x32_f16(af[mi], bf[ni], acc[mi][ni], 0, 0, 0);
    }
  }
  ushort* yp = y_part + (size_t)cs * 2097152 + ((size_t)(b * 1024 + P0)) * 128;
#pragma unroll
  for (int mi = 0; mi < 2; ++mi) {
#pragma unroll
    for (int r = 0; r < 4; ++r) {
      int m = m_w + mi * 16 + quad * 4 + r;
      ushort* orow = yp + (size_t)m * 128;
#pragma unroll
      for (int ni = 0; ni < 4; ++ni)
        orow[n_w + ni * 16 + lr] = f2bf(acc[mi][ni][r]);
    }
  }
}

// ---------------- 4. yred: 4 bf16 partials + bias -> bf16 ysum; striped BN1 atomics
__global__ __launch_bounds__(256) void yred_kernel(const ushort* __restrict__ yp,
                                                   const float* __restrict__ b_dcn,
                                                   ushort* __restrict__ ysum,
                                                   float* __restrict__ st1) {
  int blk = blockIdx.x; int tid = threadIdx.x;
  int oc = tid & 127, rh = tid >> 7;
  float bias = b_dcn[oc];
  float s = 0.f, sq = 0.f;
  for (int r = rh; r < 128; r += 2) {
    size_t idx = ((size_t)(blk * 128 + r)) * 128 + oc;
    float v = b2f(yp[idx]) + b2f(yp[2097152 + idx]) + b2f(yp[4194304 + idx])
            + b2f(yp[6291456 + idx]) + bias;
    ysum[idx] = f2bf(v);
    s += v; sq = fmaf(v, v, sq);
  }
  __shared__ float ls[256], lq[256];
  ls[tid] = s; lq[tid] = sq; __syncthreads();
  if (tid < 128) {
    float* dst = st1 + (blk & 3) * 256;
    atomicAdd(&dst[tid], ls[tid] + ls[tid + 128]);
    atomicAdd(&dst[128 + tid], lq[tid] + lq[tid + 128]);
  }
}

// ---------------- 5. ybn: BN1+ReLU on bf16 ysum -> bf16 ybn ------------------------
__global__ __launch_bounds__(256) void ybn_kernel(const ushort* __restrict__ ysum,
                                                  const float* __restrict__ st1,
                                                  const float* __restrict__ g1,
                                                  const float* __restrict__ bt1,
                                                  ushort* __restrict__ ybn) {
  __shared__ float scs[128], shs[128];
  int tid = threadIdx.x;
  if (tid < 128) {
    float s  = st1[tid] + st1[256 + tid] + st1[512 + tid] + st1[768 + tid];
    float sq = st1[128 + tid] + st1[384 + tid] + st1[640 + tid] + st1[896 + tid];
    float mean = s / 16384.f;
    float var = sq / 16384.f - mean * mean;
    float sc = g1[tid] * rsqrtf(var + EPSV);
    scs[tid] = sc;
    shs[tid] = fmaf(-mean, sc, bt1[tid]);
  }
  __syncthreads();
  int i8 = blockIdx.x * 256 + tid;
  size_t i = (size_t)i8 * 8;
  int oc = (int)(i & 127);
  uint4 pv = *(const uint4*)(ysum + i);
  uint words[4] = {pv.x, pv.y, pv.z, pv.w};
  uint owords[4];
#pragma unroll
  for (int j = 0; j < 4; ++j) {
    ushort u0 = (ushort)(words[j] & 0xFFFFu);
    ushort u1 = (ushort)(words[j] >> 16);
    int c0 = oc + 2 * j, c1 = oc + 2 * j + 1;
    float v0 = fmaxf(fmaf(b2f(u0), scs[c0], shs[c0]), 0.f);
    float v1 = fmaxf(fmaf(b2f(u1), scs[c1], shs[c1]), 0.f);
    owords[j] = (uint)f2bf(v0) | ((uint)f2bf(v1) << 16);
  }
  *(uint4*)(ybn + i) = make_uint4(owords[0], owords[1], owords[2], owords[3]);
}

// ---------------- 6. deconv: barrier-free register GEMM, bf16 O output -------------
__global__ __launch_bounds__(256) void deconv_mfma_kernel(const ushort* __restrict__ ybn,
                                                          const ushort* __restrict__ bq,
                                                          ushort* __restrict__ O,
                                                          float* __restrict__ st2) {
  int blk = blockIdx.x;
  int pt = blk & 15, par = (blk >> 4) & 3, b = blk >> 6;
  int pu = par >> 1, pv = par & 1;
  int tid = threadIdx.x;
  int wid = tid >> 6, lane = tid & 63, lr = lane & 15, quad = lane >> 4;
  int P0 = pt * 64;
  int hh[4], ww[4];
#pragma unroll
  for (int mi = 0; mi < 4; ++mi) {
    int p = P0 + mi * 16 + lr;
    hh[mi] = p >> 5; ww[mi] = p & 31;
  }

  floatx4 acc[4][2];
#pragma unroll
  for (int mi = 0; mi < 4; ++mi)
#pragma unroll
    for (int ni = 0; ni < 2; ++ni) acc[mi][ni] = (floatx4)0.f;

  const ushort* ybb = ybn + (size_t)b * 1024 * 128;
  const ushort* bqb = bq + par * 65536 + quad * 1024 + (wid * 32 + lr) * 8;

#pragma unroll
  for (int tap = 0; tap < 4; ++tap) {
    int ty = tap >> 1, tx = tap & 1;
    int ab[4]; bool val[4];
#pragma unroll
    for (int mi = 0; mi < 4; ++mi) {
      int i = hh[mi] + pu - ty, j = ww[mi] + pv - tx;
      val[mi] = (i >= 0) && (i <= 31) && (j >= 0) && (j <= 31);
      int pos = min(max(i, 0), 31) * 32 + min(max(j, 0), 31);
      ab[mi] = pos * 128;
    }
#pragma unroll
    for (int k2 = 0; k2 < 4; ++k2) {
      int kstep = tap * 4 + k2;
      int c0 = k2 * 32 + quad * 8;
      short8 bf[2];
#pragma unroll
      for (int ni = 0; ni < 2; ++ni)
        bf[ni] = *(const short8*)(bqb + kstep * 4096 + ni * 128);
      short8 af[4];
#pragma unroll
      for (int mi = 0; mi < 4; ++mi) {
        short8 a = *(const short8*)(ybb + ab[mi] + c0);
        af[mi] = val[mi] ? a : (short8)0;
      }
#pragma unroll
      for (int mi = 0; mi < 4; ++mi)
#pragma unroll
        for (int ni = 0; ni < 2; ++ni)
          acc[mi][ni] = __builtin_amdgcn_mfma_f32_16x16x32_bf16(af[mi], bf[ni], acc[mi][ni], 0, 0, 0);
    }
  }
  size_t obase = (size_t)(b * 4 + par) * 1024 * 128;
#pragma unroll
  for (int mi = 0; mi < 4; ++mi) {
#pragma unroll
    for (int r = 0; r < 4; ++r) {
      int m = mi * 16 + quad * 4 + r;
      ushort* orow = O + obase + (size_t)(P0 + m) * 128 + wid * 32;
#pragma unroll
      for (int ni = 0; ni < 2; ++ni)
        orow[ni * 16 + lr] = f2bf(acc[mi][ni][r]);
    }
  }
  float sn[2], qn[2];
#pragma unroll
  for (int ni = 0; ni < 2; ++ni) {
    float s = 0.f, q = 0.f;
#pragma unroll
    for (int mi = 0; mi < 4; ++mi)
#pragma unroll
      for (int r = 0; r < 4; ++r) {
        float v = acc[mi][ni][r];
        s += v; q = fmaf(v, v, q);
      }
    sn[ni] = s; qn[ni] = q;
  }
#pragma unroll
  for (int ni = 0; ni < 2; ++ni) {
    sn[ni] += __shfl_xor(sn[ni], 16);
    sn[ni] += __shfl_xor(sn[ni], 32);
    qn[ni] += __shfl_xor(qn[ni], 16);
    qn[ni] += __shfl_xor(qn[ni], 32);
  }
  if (lane < 16) {
    float* dst = st2 + (blk & 15) * 256;
#pragma unroll
    for (int ni = 0; ni < 2; ++ni) {
      atomicAdd(&dst[wid * 32 + ni * 16 + lr], sn[ni]);
      atomicAdd(&dst[128 + wid * 32 + ni * 16 + lr], qn[ni]);
    }
  }
}

// ---------------- 7. bnout: BN2 from 16 striped stats + transpose to NCHW ----------
__global__ __launch_bounds__(256) void bnout_kernel(const ushort* __restrict__ O,
                                                    const float* __restrict__ st2,
                                                    const float* __restrict__ g2,
                                                    const float* __restrict__ bt2,
                                                    float* __restrict__ out) {
  __shared__ float tile[128 * 33];
  __shared__ float scs[128], shs[128];
  int blk = blockIdx.x;
  int uu = blk & 31, par = (blk >> 5) & 3, b = blk >> 7;
  int pu = par >> 1, pv = par & 1;
  int tid = threadIdx.x;
  if (tid < 128) {
    float s = 0.f, sq = 0.f;
#pragma unroll
    for (int c = 0; c < 16; ++c) {
      s += st2[c * 256 + tid];
      sq += st2[c * 256 + 128 + tid];
    }
    float mean = s / 65536.f;
    float var = sq / 65536.f - mean * mean;
    float sc = g2[tid] * rsqrtf(var + EPSV);
    scs[tid] = sc;
    shs[tid] = fmaf(-mean, sc, bt2[tid]);
  }
  __syncthreads();
#pragma unroll 4
  for (int it = 0; it < 16; ++it) {
    int idx = it * 256 + tid;
    int vv = idx >> 7, oc = idx & 127;
    float v = b2f(O[((size_t)(b * 4 + par) * 1024 + uu * 32 + vv) * 128 + oc]);
    tile[oc * 33 + vv] = fmaxf(fmaf(v, scs[oc], shs[oc]), 0.f);
  }
  __syncthreads();
#pragma unroll 4
  for (int it = 0; it < 16; ++it) {
    int idx = it * 256 + tid;
    int oc = idx >> 5, vv = idx & 31;
    out[((size_t)b * 128 + oc) * 4096 + (2 * uu + pu) * 64 + 2 * vv + pv] = tile[oc * 33 + vv];
  }
}

extern "C" void kernel_launch(void* const* d_in, const int* in_sizes, int n_in,
                              void* d_out, int out_size, void* d_ws, size_t ws_size,
                              hipStream_t stream) {
  const float* x     = (const float*)d_in[0];
  const float* w_off = (const float*)d_in[1];
  const float* b_off = (const float*)d_in[2];
  const float* w_dcn = (const float*)d_in[3];
  const float* b_dcn = (const float*)d_in[4];
  const float* g1    = (const float*)d_in[5];
  const float* bt1   = (const float*)d_in[6];
  const float* w_up  = (const float*)d_in[7];
  const float* g2    = (const float*)d_in[8];
  const float* bt2   = (const float*)d_in[9];
  float* ws  = (float*)d_ws;
  float* out = (float*)d_out;

  prep_xt_kernel<<<5556, 256, 0, stream>>>(x, w_off, w_dcn, w_up, ws);
  offconv_mfma_kernel<<<1024, 256, 0, stream>>>((const __half*)(ws + XT),
                                                (const __half*)(ws + BOFF), ws + OFFB);
  deform_mfma_kernel<<<1024, 256, 0, stream>>>((const __half*)(ws + XT), ws + OFFB, b_off,
                                               (const __half*)(ws + BD), (ushort*)(ws + YP));
  yred_kernel<<<128, 256, 0, stream>>>((const ushort*)(ws + YP), b_dcn,
                                       (ushort*)(ws + YSUM), ws + ST1);
  ybn_kernel<<<1024, 256, 0, stream>>>((const ushort*)(ws + YSUM), ws + ST1, g1, bt1,
                                       (ushort*)(ws + YBN));
  deconv_mfma_kernel<<<1024, 256, 0, stream>>>((const ushort*)(ws + YBN),
                                               (const ushort*)(ws + BQ),
                                               (ushort*)(ws + OB), ws + ST2);
  bnout_kernel<<<2048, 256, 0, stream>>>((const ushort*)(ws + OB), ws + ST2, g2, bt2, out);
}